// Round 7
// baseline (1869.457 us; speedup 1.0000x reference)
//
#include <hip/hip_runtime.h>
#include <hip/hip_bf16.h>

#define BB 32
#define NN 520
#define MM 520
#define EE 128
#define HH 8
#define DKK 16
#define FFH_ 512
#define NL_ 6
#define DEPOT_ 20
#define LL 40

typedef short short8 __attribute__((ext_vector_type(8)));
typedef short bshort4 __attribute__((ext_vector_type(4)));
typedef float floatx4 __attribute__((ext_vector_type(4)));

// Manual RTNE float->bf16 (4 VALU ops). NOTE: do NOT use __float2bfloat16 here --
// r6 measured it as the legacy TRUNCATING conversion on this ROCm (absmax 4.9e-4
// -> 2.0e-3) and it regressed all GEMMs ~30% (worse codegen, VGPR +40).
__device__ __forceinline__ unsigned short f2b(float x) {
    unsigned int u = __float_as_uint(x);
    return (unsigned short)((u + 0x7fffu + ((u >> 16) & 1u)) >> 16);
}
__device__ __forceinline__ float b2f_(unsigned short h) {
    return __uint_as_float(((unsigned int)h) << 16);
}

// ---------------- embedding: depot/customer linear ----------------
__global__ __launch_bounds__(256) void embed_k(
    const float* __restrict__ dep, const float* __restrict__ cus,
    const float* __restrict__ Wd, const float* __restrict__ bd,
    const float* __restrict__ Wc3, const float* __restrict__ bc,
    float* __restrict__ x)
{
    int idx = blockIdx.x * 256 + threadIdx.x;   // < B*N*E = 2129920
    int e = idx & 127;
    int bn = idx >> 7;
    int n = bn % NN;
    int b = bn / NN;
    float a;
    if (n < DEPOT_) {
        a = bd[e];
        const float* f = dep + ((size_t)(b * DEPOT_ + n)) * 4;
        #pragma unroll
        for (int j = 0; j < 4; j++) a += f[j] * Wd[e * 4 + j];
    } else {
        a = bc[e];
        const float* f = cus + ((size_t)(b * 500 + (n - DEPOT_))) * 3;
        #pragma unroll
        for (int j = 0; j < 3; j++) a += f[j] * Wc3[e * 3 + j];
    }
    x[idx] = a;
}

// ---------------- weight pre-conversion: fp32 -> hi/lo bf16 planes ----------------
#define WLS 196608
#define WDEC 1179648
#define WTOT 1277952
__global__ __launch_bounds__(256) void wconv_k(
    const float* __restrict__ Wq, const float* __restrict__ Wk, const float* __restrict__ Wv,
    const float* __restrict__ Wc, const float* __restrict__ fW1, const float* __restrict__ fW2,
    const float* __restrict__ dWk, const float* __restrict__ dWv, const float* __restrict__ dWc,
    const float* __restrict__ Wql, const float* __restrict__ Wqr,
    unsigned short* __restrict__ WH, unsigned short* __restrict__ WL)
{
    int idx = blockIdx.x * 256 + threadIdx.x;
    if (idx >= WTOT) return;
    const float* src;
    if (idx < WDEC) {
        int i = idx / WLS, r = idx % WLS;
        if (r < 49152) {
            int row = r >> 7, col = r & 127;
            const float* w = row < 128 ? Wq : (row < 256 ? Wk : Wv);
            src = w + (size_t)i * 16384 + (size_t)(row & 127) * 128 + col;
        } else if (r < 65536) {
            src = Wc + (size_t)i * 16384 + (r - 49152);
        } else if (r < 131072) {
            src = fW1 + (size_t)i * 65536 + (r - 65536);
        } else {
            src = fW2 + (size_t)i * 65536 + (r - 131072);
        }
    } else {
        int r = idx - WDEC;
        if (r < 32768) {
            int row = r >> 7, col = r & 127;
            src = (row < 128 ? dWk : dWv) + (size_t)(row & 127) * 128 + col;
        } else if (r < 49152) {
            src = dWc + (r - 32768);
        } else {
            int rr = r - 49152;
            int row = rr >> 7, col = rr & 127;
            if (row < 128)      src = Wqr + (size_t)row * 257 + col;
            else if (row < 256) src = Wql + (size_t)(row - 128) * 256 + col;
            else                src = Wql + (size_t)(row - 256) * 256 + 128 + col;
        }
    }
    float v = *src;
    unsigned short h = f2b(v);
    WH[idx] = h;
    WL[idx] = f2b(v - b2f_(h));
}

// ---------------- bf16x3 MFMA GEMM with pre-converted weights ----------------
#define AP 40
__global__ __launch_bounds__(256) void gemm_pc_k(
    const float* __restrict__ A, int lda,
    const unsigned short* __restrict__ WH, const unsigned short* __restrict__ WL, int ldw,
    const float* __restrict__ bias,
    float* __restrict__ C, int ldc,
    int K, int relu)
{
    __shared__ __align__(16) unsigned short Ah[128][AP];
    __shared__ __align__(16) unsigned short Al[128][AP];
    __shared__ __align__(16) unsigned short Bh[64][AP];
    __shared__ __align__(16) unsigned short Bl[64][AP];

    int t = threadIdx.x;
    int w = t >> 6, lane = t & 63;
    int frow = lane & 15, fq = lane >> 4;
    int n0 = blockIdx.x * 64, m0 = blockIdx.y * 128;

    int arow = t & 127, ahalf = (t >> 7) * 16;
    int brow = t & 63,  bq    = (t >> 6) * 8;

    floatx4 acc[2][4];
    #pragma unroll
    for (int i = 0; i < 2; i++)
        #pragma unroll
        for (int j = 0; j < 4; j++)
            acc[i][j] = (floatx4){0.0f, 0.0f, 0.0f, 0.0f};

    for (int k0 = 0; k0 < K; k0 += 32) {
        {
            const float* Ap = A + (size_t)(m0 + arow) * lda + k0 + ahalf;
            float vr[16];
            #pragma unroll
            for (int j = 0; j < 4; j++) {
                float4 v = ((const float4*)Ap)[j];
                vr[j * 4 + 0] = v.x; vr[j * 4 + 1] = v.y;
                vr[j * 4 + 2] = v.z; vr[j * 4 + 3] = v.w;
            }
            short8 hv0, hv1, lv0, lv1;
            #pragma unroll
            for (int j = 0; j < 8; j++) {
                unsigned short h = f2b(vr[j]);
                hv0[j] = (short)h;
                lv0[j] = (short)f2b(vr[j] - b2f_(h));
            }
            #pragma unroll
            for (int j = 0; j < 8; j++) {
                unsigned short h = f2b(vr[8 + j]);
                hv1[j] = (short)h;
                lv1[j] = (short)f2b(vr[8 + j] - b2f_(h));
            }
            *((short8*)&Ah[arow][ahalf])     = hv0;
            *((short8*)&Ah[arow][ahalf + 8]) = hv1;
            *((short8*)&Al[arow][ahalf])     = lv0;
            *((short8*)&Al[arow][ahalf + 8]) = lv1;
        }
        {
            size_t wo = (size_t)(n0 + brow) * ldw + k0 + bq;
            *((short8*)&Bh[brow][bq]) = *((const short8*)(WH + wo));
            *((short8*)&Bl[brow][bq]) = *((const short8*)(WL + wo));
        }
        __syncthreads();

        short8 ah0 = *((const short8*)&Ah[w * 32 + frow][fq * 8]);
        short8 ah1 = *((const short8*)&Ah[w * 32 + 16 + frow][fq * 8]);
        short8 al0 = *((const short8*)&Al[w * 32 + frow][fq * 8]);
        short8 al1 = *((const short8*)&Al[w * 32 + 16 + frow][fq * 8]);
        #pragma unroll
        for (int nt = 0; nt < 4; nt++) {
            short8 bh = *((const short8*)&Bh[nt * 16 + frow][fq * 8]);
            short8 bl = *((const short8*)&Bl[nt * 16 + frow][fq * 8]);
            acc[0][nt] = __builtin_amdgcn_mfma_f32_16x16x32_bf16(ah0, bh, acc[0][nt], 0, 0, 0);
            acc[1][nt] = __builtin_amdgcn_mfma_f32_16x16x32_bf16(ah1, bh, acc[1][nt], 0, 0, 0);
            acc[0][nt] = __builtin_amdgcn_mfma_f32_16x16x32_bf16(ah0, bl, acc[0][nt], 0, 0, 0);
            acc[1][nt] = __builtin_amdgcn_mfma_f32_16x16x32_bf16(ah1, bl, acc[1][nt], 0, 0, 0);
            acc[0][nt] = __builtin_amdgcn_mfma_f32_16x16x32_bf16(al0, bh, acc[0][nt], 0, 0, 0);
            acc[1][nt] = __builtin_amdgcn_mfma_f32_16x16x32_bf16(al1, bh, acc[1][nt], 0, 0, 0);
        }
        __syncthreads();
    }

    #pragma unroll
    for (int nt = 0; nt < 4; nt++) {
        int col = n0 + nt * 16 + frow;
        float bv = bias ? bias[col] : 0.0f;
        #pragma unroll
        for (int mt = 0; mt < 2; mt++) {
            int rbase = m0 + w * 32 + mt * 16 + fq * 4;
            #pragma unroll
            for (int r = 0; r < 4; r++) {
                float v = acc[mt][nt][r] + bv;
                if (relu) v = fmaxf(v, 0.0f);
                C[(size_t)(rbase + r) * ldc + col] = v;
            }
        }
    }
}

// ---------------- fused 3-way GEMM (QKV / dec-KV / R+L1) ----------------
// pack=1: outputs written head-major [B*H][N][16] (for fmha); pack=0: standard [B*N][E].
__global__ __launch_bounds__(256) void gemm_qkv3_k(
    const float* __restrict__ A, int lda,
    const unsigned short* __restrict__ WH, const unsigned short* __restrict__ WL, int ldw,
    float* __restrict__ C0, float* __restrict__ C1, float* __restrict__ C2,
    int ldc, int K, int pack)
{
    __shared__ __align__(16) unsigned short Ah[128][AP];
    __shared__ __align__(16) unsigned short Al[128][AP];
    __shared__ __align__(16) unsigned short Bh[64][AP];
    __shared__ __align__(16) unsigned short Bl[64][AP];

    int t = threadIdx.x;
    int w = t >> 6, lane = t & 63;
    int frow = lane & 15, fq = lane >> 4;
    int nb = blockIdx.x;
    int which = nb >> 1;
    float* C = which == 0 ? C0 : (which == 1 ? C1 : C2);
    int n0w = nb * 64;            // row in stacked weight plane
    int n0c = (nb & 1) * 64;      // col in the selected C
    int m0 = blockIdx.y * 128;

    int arow = t & 127, ahalf = (t >> 7) * 16;
    int brow = t & 63,  bq    = (t >> 6) * 8;

    floatx4 acc[2][4];
    #pragma unroll
    for (int i = 0; i < 2; i++)
        #pragma unroll
        for (int j = 0; j < 4; j++)
            acc[i][j] = (floatx4){0.0f, 0.0f, 0.0f, 0.0f};

    for (int k0 = 0; k0 < K; k0 += 32) {
        {
            const float* Ap = A + (size_t)(m0 + arow) * lda + k0 + ahalf;
            float vr[16];
            #pragma unroll
            for (int j = 0; j < 4; j++) {
                float4 v = ((const float4*)Ap)[j];
                vr[j * 4 + 0] = v.x; vr[j * 4 + 1] = v.y;
                vr[j * 4 + 2] = v.z; vr[j * 4 + 3] = v.w;
            }
            short8 hv0, hv1, lv0, lv1;
            #pragma unroll
            for (int j = 0; j < 8; j++) {
                unsigned short h = f2b(vr[j]);
                hv0[j] = (short)h;
                lv0[j] = (short)f2b(vr[j] - b2f_(h));
            }
            #pragma unroll
            for (int j = 0; j < 8; j++) {
                unsigned short h = f2b(vr[8 + j]);
                hv1[j] = (short)h;
                lv1[j] = (short)f2b(vr[8 + j] - b2f_(h));
            }
            *((short8*)&Ah[arow][ahalf])     = hv0;
            *((short8*)&Ah[arow][ahalf + 8]) = hv1;
            *((short8*)&Al[arow][ahalf])     = lv0;
            *((short8*)&Al[arow][ahalf + 8]) = lv1;
        }
        {
            size_t wo = (size_t)(n0w + brow) * ldw + k0 + bq;
            *((short8*)&Bh[brow][bq]) = *((const short8*)(WH + wo));
            *((short8*)&Bl[brow][bq]) = *((const short8*)(WL + wo));
        }
        __syncthreads();

        short8 ah0 = *((const short8*)&Ah[w * 32 + frow][fq * 8]);
        short8 ah1 = *((const short8*)&Ah[w * 32 + 16 + frow][fq * 8]);
        short8 al0 = *((const short8*)&Al[w * 32 + frow][fq * 8]);
        short8 al1 = *((const short8*)&Al[w * 32 + 16 + frow][fq * 8]);
        #pragma unroll
        for (int nt = 0; nt < 4; nt++) {
            short8 bh = *((const short8*)&Bh[nt * 16 + frow][fq * 8]);
            short8 bl = *((const short8*)&Bl[nt * 16 + frow][fq * 8]);
            acc[0][nt] = __builtin_amdgcn_mfma_f32_16x16x32_bf16(ah0, bh, acc[0][nt], 0, 0, 0);
            acc[1][nt] = __builtin_amdgcn_mfma_f32_16x16x32_bf16(ah1, bh, acc[1][nt], 0, 0, 0);
            acc[0][nt] = __builtin_amdgcn_mfma_f32_16x16x32_bf16(ah0, bl, acc[0][nt], 0, 0, 0);
            acc[1][nt] = __builtin_amdgcn_mfma_f32_16x16x32_bf16(ah1, bl, acc[1][nt], 0, 0, 0);
            acc[0][nt] = __builtin_amdgcn_mfma_f32_16x16x32_bf16(al0, bh, acc[0][nt], 0, 0, 0);
            acc[1][nt] = __builtin_amdgcn_mfma_f32_16x16x32_bf16(al1, bh, acc[1][nt], 0, 0, 0);
        }
        __syncthreads();
    }

    #pragma unroll
    for (int nt = 0; nt < 4; nt++) {
        int col = n0c + nt * 16 + frow;
        int hh = col >> 4, dd = col & 15;
        #pragma unroll
        for (int mt = 0; mt < 2; mt++) {
            int rbase = m0 + w * 32 + mt * 16 + fq * 4;
            #pragma unroll
            for (int r = 0; r < 4; r++) {
                int row = rbase + r;
                if (pack) {
                    int b2 = row / NN, n2 = row - b2 * NN;
                    C[((size_t)(b2 * HH + hh) * NN + n2) * 16 + dd] = acc[mt][nt][r];
                } else {
                    C[(size_t)row * ldc + col] = acc[mt][nt][r];
                }
            }
        }
    }
}

// ---------------- score GEMM (NT) with tanh epilogue (fp32) ----------------
#define GT 64
#define GK 32
#define GP 36
__global__ __launch_bounds__(256) void sgemm_k(
    const float* __restrict__ A,    // score [B*520][128]
    const float* __restrict__ Enc,  // [B*520][128]
    float* __restrict__ C)          // [B][520][520]
{
    __shared__ float As[GT][GP];
    __shared__ float Ws[GT][GP];
    int t = threadIdx.x;
    int tx = t & 15, ty = t >> 4;
    int b = blockIdx.z;
    int m0 = blockIdx.y * GT, n0 = blockIdx.x * GT;
    int lr = t >> 2, lc = (t & 3) * 8;
    int mr = m0 + lr; if (mr >= NN) mr = NN - 1;
    int nr = n0 + lr; if (nr >= NN) nr = NN - 1;
    float acc[4][4];
    #pragma unroll
    for (int i = 0; i < 4; i++)
        #pragma unroll
        for (int j = 0; j < 4; j++) acc[i][j] = 0.0f;

    for (int k0 = 0; k0 < EE; k0 += GK) {
        const float* Ap = A + ((size_t)(b * NN + mr)) * EE + k0 + lc;
        const float* Wp = Enc + ((size_t)(b * NN + nr)) * EE + k0 + lc;
        float4 av0 = *((const float4*)Ap), av1 = *((const float4*)(Ap + 4));
        float4 wv0 = *((const float4*)Wp), wv1 = *((const float4*)(Wp + 4));
        *((float4*)&As[lr][lc]) = av0; *((float4*)&As[lr][lc + 4]) = av1;
        *((float4*)&Ws[lr][lc]) = wv0; *((float4*)&Ws[lr][lc + 4]) = wv1;
        __syncthreads();
        #pragma unroll
        for (int kk = 0; kk < GK; kk += 2) {
            float2 a0 = *((const float2*)&As[ty][kk]);
            float2 a1 = *((const float2*)&As[ty + 16][kk]);
            float2 a2 = *((const float2*)&As[ty + 32][kk]);
            float2 a3 = *((const float2*)&As[ty + 48][kk]);
            float2 w0 = *((const float2*)&Ws[tx][kk]);
            float2 w1 = *((const float2*)&Ws[tx + 16][kk]);
            float2 w2 = *((const float2*)&Ws[tx + 32][kk]);
            float2 w3 = *((const float2*)&Ws[tx + 48][kk]);
            acc[0][0] += a0.x * w0.x + a0.y * w0.y;
            acc[0][1] += a0.x * w1.x + a0.y * w1.y;
            acc[0][2] += a0.x * w2.x + a0.y * w2.y;
            acc[0][3] += a0.x * w3.x + a0.y * w3.y;
            acc[1][0] += a1.x * w0.x + a1.y * w0.y;
            acc[1][1] += a1.x * w1.x + a1.y * w1.y;
            acc[1][2] += a1.x * w2.x + a1.y * w2.y;
            acc[1][3] += a1.x * w3.x + a1.y * w3.y;
            acc[2][0] += a2.x * w0.x + a2.y * w0.y;
            acc[2][1] += a2.x * w1.x + a2.y * w1.y;
            acc[2][2] += a2.x * w2.x + a2.y * w2.y;
            acc[2][3] += a2.x * w3.x + a2.y * w3.y;
            acc[3][0] += a3.x * w0.x + a3.y * w0.y;
            acc[3][1] += a3.x * w1.x + a3.y * w1.y;
            acc[3][2] += a3.x * w2.x + a3.y * w2.y;
            acc[3][3] += a3.x * w3.x + a3.y * w3.y;
        }
        __syncthreads();
    }
    #pragma unroll
    for (int i = 0; i < 4; i++) {
        int m = m0 + ty + 16 * i;
        if (m >= NN) continue;
        #pragma unroll
        for (int j = 0; j < 4; j++) {
            int n = n0 + tx + 16 * j;
            if (n >= NN) continue;
            float v = 10.0f * tanhf(acc[i][j] * 0.088388347648318447f);
            C[((size_t)(b * NN + m)) * NN + n] = v;
        }
    }
}

// ---------------- row softmax: out = softmax(logits + mask) ----------------
__global__ __launch_bounds__(64) void smax_k(
    const float* __restrict__ L, const float* __restrict__ mask,
    float* __restrict__ out)
{
    int bm = blockIdx.x;
    int t = threadIdx.x;
    const float* Lr = L + (size_t)bm * NN;
    const float* Mr = mask + (size_t)bm * NN;
    float v[9];
    float mx = -1e30f;
    #pragma unroll
    for (int i = 0; i < 9; i++) {
        int idx = t + i * 64;
        if (idx < NN) { v[i] = Lr[idx] + Mr[idx]; mx = fmaxf(mx, v[i]); }
        else v[i] = -1e30f;
    }
    #pragma unroll
    for (int o = 32; o > 0; o >>= 1) mx = fmaxf(mx, __shfl_xor(mx, o));
    float s = 0.0f;
    #pragma unroll
    for (int i = 0; i < 9; i++) {
        int idx = t + i * 64;
        float e = (idx < NN) ? expf(v[i] - mx) : 0.0f;
        v[i] = e; s += e;
    }
    #pragma unroll
    for (int o = 32; o > 0; o >>= 1) s += __shfl_xor(s, o);
    float inv = 1.0f / s;
    #pragma unroll
    for (int i = 0; i < 9; i++) {
        int idx = t + i * 64;
        if (idx < NN) out[(size_t)bm * NN + idx] = v[i] * inv;
    }
}

// ---------------- persistent-KV MFMA flash attention v3.1 (bf16x3, fp32-equivalent) ----------------
// Grid (b=32, h=8, z=4), 256 threads (4 waves). id%8 = b%8: all 32 blocks of a
// batch share one XCD -> mask + K/V L2-resident (r5: FETCH 194->37MB).
// QK^T: two mfma_16x16x32 with [Kh|Kl] x {[Qh|Ql],[Ql|Qh]} = exact 4-term product.
// T13 defer-max: skip O/l rescale + shfl broadcasts while the running max hasn't
// grown by >8 (P bounded by e^8; fp32 accum fine). Dbuf LDS, 1 barrier/iter.
#define ATK 64
#define NFRG 3
__global__ __launch_bounds__(256) void fmha_pers_k(
    const float* __restrict__ Qp, const float* __restrict__ Kp,
    const float* __restrict__ Vp, const float* __restrict__ mask,
    float* __restrict__ O, int Nq, int Nk)
{
    __shared__ __align__(16) unsigned short Khl[2][ATK][40];  // [kc][0:16 hi-dk | 16:32 lo-dk]
    __shared__ __align__(16) unsigned short Vhi[2][16][72];
    __shared__ __align__(16) unsigned short Vlo[2][16][72];

    int b = blockIdx.x, h = blockIdx.y, z = blockIdx.z;
    int bh = b * HH + h;
    int t = threadIdx.x;
    int w = t >> 6, lane = t & 63;
    int r16 = lane & 15, g = lane >> 4;

    // ---- per-wave q fragments: fi = f*16 + z*4 + w covers rows [fi*16, fi*16+16) ----
    short8 qf[NFRG], qs[NFRG];      // [Qh|Ql] and swapped [Ql|Qh] 32-k operands
    floatx4 o_acc[NFRG];
    float m_i[NFRG], l_i[NFRG];
    const float* mrowf[NFRG];
    const float* QpB = Qp + (size_t)bh * Nq * 16;
    #pragma unroll
    for (int f = 0; f < NFRG; f++) {
        int fi = f * 16 + z * 4 + w;
        int qg = fi * 16 + r16;
        int qc = qg < Nq ? qg : Nq - 1;
        const float* qp = QpB + (size_t)qc * 16 + 8 * (g & 1);
        float4 qv0 = *((const float4*)qp);
        float4 qv1 = *((const float4*)(qp + 4));
        float qa[8] = {qv0.x, qv0.y, qv0.z, qv0.w, qv1.x, qv1.y, qv1.z, qv1.w};
        #pragma unroll
        for (int j = 0; j < 8; j++) {
            unsigned short hh = f2b(qa[j]);
            unsigned short ll = f2b(qa[j] - b2f_(hh));
            qf[f][j] = (short)(g < 2 ? hh : ll);
            qs[f][j] = (short)(g < 2 ? ll : hh);
        }
        o_acc[f] = (floatx4){0.0f, 0.0f, 0.0f, 0.0f};
        m_i[f] = -1e30f; l_i[f] = 0.0f;
        mrowf[f] = mask ? (mask + ((size_t)(b * Nq + qc)) * Nk) : nullptr;
    }

    // ---- staging: 256 threads, float4/thread per array ----
    int srow = t >> 2, sc = (t & 3) * 4;
    const float* KpB = Kp + ((size_t)bh * Nk) * 16 + sc;
    const float* VpB = Vp + ((size_t)bh * Nk) * 16 + sc;

    {
        int krc = srow < Nk ? srow : Nk - 1;
        float4 kv = *((const float4*)(KpB + (size_t)krc * 16));
        float4 vv = *((const float4*)(VpB + (size_t)krc * 16));
        float ka[4] = {kv.x, kv.y, kv.z, kv.w};
        float va[4] = {vv.x, vv.y, vv.z, vv.w};
        bshort4 khv, klv;
        #pragma unroll
        for (int j = 0; j < 4; j++) {
            unsigned short hh = f2b(ka[j]);
            khv[j] = (short)hh;
            klv[j] = (short)f2b(ka[j] - b2f_(hh));
        }
        *((bshort4*)&Khl[0][srow][sc])      = khv;
        *((bshort4*)&Khl[0][srow][16 + sc]) = klv;
        #pragma unroll
        for (int j = 0; j < 4; j++) {
            unsigned short hh = f2b(va[j]);
            Vhi[0][sc + j][srow] = hh;
            Vlo[0][sc + j][srow] = (unsigned short)f2b(va[j] - b2f_(hh));
        }
    }
    __syncthreads();

    int nkt = (Nk + ATK - 1) / ATK;
    for (int kt = 0; kt < nkt; kt++) {
        int cur = kt & 1;
        int k0 = kt * ATK;

        // ---- prefetch next K/V tile to regs (HBM/L2 latency hides under compute) ----
        float4 nkv, nvv;
        bool pf = (kt + 1 < nkt);
        if (pf) {
            int kr = k0 + ATK + srow;
            int krc = kr < Nk ? kr : Nk - 1;
            nkv = *((const float4*)(KpB + (size_t)krc * 16));
            nvv = *((const float4*)(VpB + (size_t)krc * 16));
        }

        // ---- hoisted mask loads for this tile (issue under the QK MFMAs) ----
        float mvv[NFRG][4][4];
        if (mask) {
            #pragma unroll
            for (int f = 0; f < NFRG; f++) {
                #pragma unroll
                for (int s = 0; s < 4; s++) {
                    int c0 = k0 + s * 16 + 4 * g;
                    if (c0 + 3 < Nk) {
                        float4 m4 = *((const float4*)(mrowf[f] + c0));
                        mvv[f][s][0] = m4.x; mvv[f][s][1] = m4.y;
                        mvv[f][s][2] = m4.z; mvv[f][s][3] = m4.w;
                    } else {
                        #pragma unroll
                        for (int r = 0; r < 4; r++)
                            mvv[f][s][r] = (c0 + r < Nk) ? mrowf[f][c0 + r] : 0.0f;
                    }
                }
            }
        }

        // ---- K/V fragments for this tile (shared by all frags of the wave) ----
        short8 kfr[4];
        bshort4 vhf[4], vlf[4];
        #pragma unroll
        for (int s = 0; s < 4; s++) {
            kfr[s] = *((const short8*)&Khl[cur][s * 16 + r16][8 * g]);
            vhf[s] = *((const bshort4*)&Vhi[cur][r16][s * 16 + 4 * g]);
            vlf[s] = *((const bshort4*)&Vlo[cur][r16][s * 16 + 4 * g]);
        }

        #pragma unroll
        for (int f = 0; f < NFRG; f++) {
            int fi = f * 16 + z * 4 + w;
            if (fi * 16 >= Nq) continue;   // wave-uniform

            // ---- S^T: 4 sub-tiles x 2 passes of 16x16x32 (exact 4-term product) ----
            float p[4][4];
            #pragma unroll
            for (int s = 0; s < 4; s++) {
                floatx4 a = (floatx4){0.0f, 0.0f, 0.0f, 0.0f};
                a = __builtin_amdgcn_mfma_f32_16x16x32_bf16(kfr[s], qf[f], a, 0, 0, 0);
                a = __builtin_amdgcn_mfma_f32_16x16x32_bf16(kfr[s], qs[f], a, 0, 0, 0);
                #pragma unroll
                for (int r = 0; r < 4; r++) p[s][r] = a[r];
            }

            // ---- scale + mask + bounds ----
            #pragma unroll
            for (int s = 0; s < 4; s++) {
                int c0 = k0 + s * 16 + 4 * g;
                #pragma unroll
                for (int r = 0; r < 4; r++) {
                    float mv = mask ? mvv[f][s][r] : 0.0f;
                    p[s][r] = (c0 + r < Nk) ? (p[s][r] * 0.25f + mv) : -1e30f;
                }
            }

            // ---- online softmax with T13 defer-max (per q = lane&15) ----
            float tmax = -1e30f;
            #pragma unroll
            for (int s = 0; s < 4; s++)
                #pragma unroll
                for (int r = 0; r < 4; r++) tmax = fmaxf(tmax, p[s][r]);
            tmax = fmaxf(tmax, __shfl_xor(tmax, 16));
            tmax = fmaxf(tmax, __shfl_xor(tmax, 32));
            float m_cur = m_i[f];
            if (!__all(tmax <= m_cur + 8.0f)) {
                float m_new = fmaxf(m_cur, tmax);
                float alpha = __expf(m_cur - m_new);
                l_i[f] *= alpha;
                #pragma unroll
                for (int r = 0; r < 4; r++) {
                    float ar = __shfl(alpha, 4 * g + r);
                    o_acc[f][r] *= ar;
                }
                m_i[f] = m_new;
                m_cur = m_new;
            }
            float lloc = 0.0f;
            #pragma unroll
            for (int s = 0; s < 4; s++) {
                #pragma unroll
                for (int r = 0; r < 4; r++) {
                    float e = __expf(p[s][r] - m_cur);
                    p[s][r] = e; lloc += e;
                }
            }
            lloc += __shfl_xor(lloc, 16);
            lloc += __shfl_xor(lloc, 32);
            l_i[f] += lloc;

            // ---- PV: p is already the x16 A-frag (kc = 4g+r) ----
            #pragma unroll
            for (int s = 0; s < 4; s++) {
                bshort4 ph, pl;
                #pragma unroll
                for (int r = 0; r < 4; r++) {
                    unsigned short hh = f2b(p[s][r]);
                    ph[r] = (short)hh;
                    pl[r] = (short)f2b(p[s][r] - b2f_(hh));
                }
                o_acc[f] = __builtin_amdgcn_mfma_f32_16x16x16bf16_1k(ph, vhf[s], o_acc[f], 0, 0, 0);
                o_acc[f] = __builtin_amdgcn_mfma_f32_16x16x16bf16_1k(ph, vlf[s], o_acc[f], 0, 0, 0);
                o_acc[f] = __builtin_amdgcn_mfma_f32_16x16x16bf16_1k(pl, vhf[s], o_acc[f], 0, 0, 0);
            }
        }

        // ---- write next tile into the other buffer; one barrier per iteration ----
        if (pf) {
            int nb = cur ^ 1;
            float ka[4] = {nkv.x, nkv.y, nkv.z, nkv.w};
            float va[4] = {nvv.x, nvv.y, nvv.z, nvv.w};
            bshort4 khv, klv;
            #pragma unroll
            for (int j = 0; j < 4; j++) {
                unsigned short hh = f2b(ka[j]);
                khv[j] = (short)hh;
                klv[j] = (short)f2b(ka[j] - b2f_(hh));
            }
            *((bshort4*)&Khl[nb][srow][sc])      = khv;
            *((bshort4*)&Khl[nb][srow][16 + sc]) = klv;
            #pragma unroll
            for (int j = 0; j < 4; j++) {
                unsigned short hh = f2b(va[j]);
                Vhi[nb][sc + j][srow] = hh;
                Vlo[nb][sc + j][srow] = (unsigned short)f2b(va[j] - b2f_(hh));
            }
        }
        __syncthreads();
    }

    // ---- epilogue: O reg r is (q-row 4g+r, d = r16); l lives at lane q ----
    #pragma unroll
    for (int f = 0; f < NFRG; f++) {
        int fi = f * 16 + z * 4 + w;
        if (fi * 16 >= Nq) continue;
        #pragma unroll
        for (int r = 0; r < 4; r++) {
            float lr = __shfl(l_i[f], 4 * g + r);
            int qrow = fi * 16 + 4 * g + r;
            if (qrow < Nq)
                O[((size_t)(b * Nq + qrow)) * EE + h * 16 + r16] = o_acc[f][r] / lr;
        }
    }
}

// ---------------- InstanceNorm over node axis ----------------
__global__ __launch_bounds__(64) void inorm_k(
    const float* __restrict__ X, const float* __restrict__ Y,
    const float* __restrict__ g, const float* __restrict__ bb,
    float* __restrict__ Out)
{
    int be = blockIdx.x;
    int b = be >> 7, e = be & 127;
    int t = threadIdx.x;
    float vals[9];
    float s = 0.0f, s2 = 0.0f;
    int c = 0;
    for (int n = t; n < NN; n += 64) {
        size_t off = ((size_t)(b * NN + n)) * EE + e;
        float v = X[off] + Y[off];
        vals[c++] = v; s += v; s2 += v * v;
    }
    #pragma unroll
    for (int o = 32; o > 0; o >>= 1) { s += __shfl_down(s, o); s2 += __shfl_down(s2, o); }
    s = __shfl(s, 0); s2 = __shfl(s2, 0);
    float mu = s * (1.0f / NN);
    float var = s2 * (1.0f / NN) - mu * mu;
    float inv = rsqrtf(var + 1e-5f);
    float gg = g[e], bv = bb[e];
    c = 0;
    for (int n = t; n < NN; n += 64) {
        size_t off = ((size_t)(b * NN + n)) * EE + e;
        Out[off] = (vals[c++] - mu) * inv * gg + bv;
    }
}

__global__ void zero_k(float* p, int n) {
    int i = blockIdx.x * 256 + threadIdx.x;
    if (i < n) p[i] = 0.0f;
}

__global__ __launch_bounds__(128) void encsum_k(const float* __restrict__ enc, float* __restrict__ esum) {
    int b = blockIdx.x, ch = blockIdx.y, t = threadIdx.x;
    float a = 0.0f;
    for (int i = 0; i < 65; i++) {
        int n = ch * 65 + i;
        a += enc[((size_t)(b * NN + n)) * EE + t];
    }
    atomicAdd(&esum[b * EE + t], a);
}

// mt[b,e] = sum_f (esum[b,f]/N) * Wr[e, 128+f]
__global__ __launch_bounds__(128) void meanterm_k(
    const float* __restrict__ esum, const float* __restrict__ Wr, float* __restrict__ mt)
{
    int b = blockIdx.x, t = threadIdx.x;
    __shared__ float em[128];
    em[t] = esum[b * EE + t] * (1.0f / NN);
    __syncthreads();
    const float* w = Wr + (size_t)t * 257 + 128;
    float a = 0.0f;
    for (int f = 0; f < 128; f++) a += em[f] * w[f];
    mt[b * EE + t] = a;
}

__global__ __launch_bounds__(128) void subtour_k(
    const float* __restrict__ enc, const int* __restrict__ subn,
    const int* __restrict__ subl, float* __restrict__ subm)
{
    int bm = blockIdx.x;
    int b = bm / MM;
    int t = threadIdx.x;
    int len = subl[bm];
    float acc = 0.0f; int cnt = 0;
    for (int l = 0; l < LL; l++) {
        int node = subn[(size_t)bm * LL + l];
        if (l < len && node >= DEPOT_) {
            acc += enc[((size_t)(b * NN + node)) * EE + t];
            cnt++;
        }
    }
    float cf = (float)(cnt < 1 ? 1 : cnt);
    subm[(size_t)bm * EE + t] = acc / cf;
}

// ---------------- decoder q: gather/blend, writes head-packed final_q ----------------
__global__ __launch_bounds__(128) void decq_gather_k(
    const float* __restrict__ R, const float* __restrict__ L1, const float* __restrict__ SM2,
    const float* __restrict__ mterm, const int* __restrict__ cur,
    const float* __restrict__ loadv, const int* __restrict__ sel,
    const float* __restrict__ Wqr, float* __restrict__ out)
{
    int bm = blockIdx.x;
    int b = bm / MM;
    int m = bm - b * MM;
    int t = threadIdx.x;
    int cn = cur[bm];
    int s2v = sel[(size_t)bm * 4 + 2];
    bool flag = (s2v >= DEPOT_) && (cn < DEPOT_);
    size_t eo = ((size_t)(b * NN + cn)) * EE + t;
    float q;
    if (flag) q = L1[eo] + SM2[(size_t)bm * EE + t];
    else      q = R[eo] + mterm[b * EE + t] + loadv[bm] * Wqr[(size_t)t * 257 + 256];
    out[((size_t)(b * HH + (t >> 4)) * MM + m) * 16 + (t & 15)] = q;
}

extern "C" void kernel_launch(void* const* d_in, const int* in_sizes, int n_in,
                              void* d_out, int out_size, void* d_ws, size_t ws_size,
                              hipStream_t stream)
{
    const float* depot = (const float*)d_in[0];
    const float* cust  = (const float*)d_in[1];
    const float* mask  = (const float*)d_in[2];
    const float* loadv = (const float*)d_in[3];
    const int*  cur   = (const int*)d_in[4];
    const int*  subn  = (const int*)d_in[5];
    const int*  subl  = (const int*)d_in[6];
    const int*  sel   = (const int*)d_in[7];
    const float* Wdep  = (const float*)d_in[8];
    const float* bdep  = (const float*)d_in[9];
    const float* Wcus  = (const float*)d_in[10];
    const float* bcus  = (const float*)d_in[11];
    const float* Wq    = (const float*)d_in[12];
    const float* Wk    = (const float*)d_in[13];
    const float* Wv    = (const float*)d_in[14];
    const float* Wc    = (const float*)d_in[15];
    const float* Wcb   = (const float*)d_in[16];
    const float* n1g   = (const float*)d_in[17];
    const float* n1b   = (const float*)d_in[18];
    const float* fW1   = (const float*)d_in[19];
    const float* fb1   = (const float*)d_in[20];
    const float* fW2   = (const float*)d_in[21];
    const float* fb2   = (const float*)d_in[22];
    const float* n2g   = (const float*)d_in[23];
    const float* n2b   = (const float*)d_in[24];
    const float* Wql   = (const float*)d_in[25];
    const float* Wqr   = (const float*)d_in[26];
    const float* dWk   = (const float*)d_in[27];
    const float* dWv   = (const float*)d_in[28];
    const float* dWc   = (const float*)d_in[29];
    const float* dWcb  = (const float*)d_in[30];

    const size_t SZ = (size_t)BB * NN * EE;           // 2,129,920
    float* f0 = (float*)d_ws;       // x / encoded
    float* f1 = f0 + SZ;            // q / k_d (packed) / logits (spans f1..f5)
    float* f2 = f1 + SZ;            // k / v_d (packed)
    float* f3 = f2 + SZ;            // v (packed) / encsum + meanterm
    float* f4 = f3 + SZ;            // mh,ff2 out / sub_mean, dec attn
    float* f5 = f4 + SZ;            // x1 / final_q (packed)
    float* big = f5 + SZ;           // ffh (B*N*FFH) / R,L1,SM2 / dec score
    unsigned short* WHp = (unsigned short*)(big + (size_t)BB * NN * FFH_);
    unsigned short* WLp = WHp + WTOT;

    dim3 g4(EE / 64, (BB * NN) / 128);     // (2, 130)
    dim3 g16(FFH_ / 64, (BB * NN) / 128);  // (8, 130)
    dim3 gq3(6, (BB * NN) / 128);          // fused QKV
    dim3 gq2(4, (BB * NN) / 128);          // fused 2-way
    dim3 gmha(BB, HH, 4);                  // (32, 8, 4): id%8==b%8 -> per-batch L2 on one XCD
    dim3 gsc((NN + GT - 1) / GT, (NN + GT - 1) / GT, BB);  // (9, 9, 32)

    wconv_k<<<(WTOT + 255) / 256, 256, 0, stream>>>(Wq, Wk, Wv, Wc, fW1, fW2,
                                                    dWk, dWv, dWc, Wql, Wqr, WHp, WLp);
    embed_k<<<(BB * NN * EE) / 256, 256, 0, stream>>>(depot, cust, Wdep, bdep, Wcus, bcus, f0);

    for (int i = 0; i < NL_; i++) {
        const unsigned short* lH = WHp + (size_t)i * WLS;
        const unsigned short* lL = WLp + (size_t)i * WLS;
        gemm_qkv3_k<<<gq3, 256, 0, stream>>>(f0, EE, lH, lL, EE, f1, f2, f3, EE, EE, 1);
        fmha_pers_k<<<gmha, 256, 0, stream>>>(f1, f2, f3, nullptr, f4, NN, NN);
        gemm_pc_k<<<g4, 256, 0, stream>>>(f4, EE, lH + 49152, lL + 49152, EE, Wcb + i * EE, f1, EE, EE, 0);
        inorm_k<<<BB * EE, 64, 0, stream>>>(f0, f1, n1g + i * EE, n1b + i * EE, f5);
        gemm_pc_k<<<g16, 256, 0, stream>>>(f5, EE, lH + 65536, lL + 65536, EE, fb1 + i * FFH_, big, FFH_, EE, 1);
        gemm_pc_k<<<g4, 256, 0, stream>>>(big, FFH_, lH + 131072, lL + 131072, FFH_, fb2 + i * EE, f1, EE, FFH_, 0);
        inorm_k<<<BB * EE, 64, 0, stream>>>(f5, f1, n2g + i * EE, n2b + i * EE, f0);
    }

    // ---- decoder ----
    const unsigned short* dH = WHp + WDEC;
    const unsigned short* dL = WLp + WDEC;
    gemm_qkv3_k<<<gq2, 256, 0, stream>>>(f0, EE, dH, dL, EE, f1, f2, f2, EE, EE, 1);  // k_d, v_d packed

    zero_k<<<(BB * EE + 255) / 256, 256, 0, stream>>>(f3, BB * EE);
    encsum_k<<<dim3(BB, 8), 128, 0, stream>>>(f0, f3);
    meanterm_k<<<BB, 128, 0, stream>>>(f3, Wqr, f3 + BB * EE);
    subtour_k<<<BB * MM, 128, 0, stream>>>(f0, subn, subl, f4);

    // R (big), L1 (big+SZ) from encoded; SM2 (big+2SZ) from subm  (standard layout)
    gemm_qkv3_k<<<gq2, 256, 0, stream>>>(f0, EE, dH + 49152, dL + 49152, EE, big, big + SZ, big + SZ, EE, EE, 0);
    gemm_pc_k<<<g4, 256, 0, stream>>>(f4, EE, dH + 49152 + 32768, dL + 49152 + 32768, EE, nullptr, big + 2 * SZ, EE, EE, 0);
    decq_gather_k<<<BB * MM, 128, 0, stream>>>(big, big + SZ, big + 2 * SZ, f3 + BB * EE, cur, loadv, sel, Wqr, f5);

    fmha_pers_k<<<gmha, 256, 0, stream>>>(f5, f1, f2, mask, f4, MM, NN);
    gemm_pc_k<<<g4, 256, 0, stream>>>(f4, EE, dH + 32768, dL + 32768, EE, dWcb, big, EE, EE, 0);

    // logits (B x 520 x 520) at f1 (spans f1..f5; all dead now)
    sgemm_k<<<gsc, 256, 0, stream>>>(big, f0, f1);
    smax_k<<<BB * MM, 64, 0, stream>>>(f1, mask, (float*)d_out);
}

// Round 8
// 1548.737 us; speedup vs baseline: 1.2071x; 1.2071x over previous
//
#include <hip/hip_runtime.h>
#include <hip/hip_bf16.h>

#define BB 32
#define NN 520
#define MM 520
#define EE 128
#define HH 8
#define DKK 16
#define FFH_ 512
#define NL_ 6
#define DEPOT_ 20
#define LL 40

typedef short short8 __attribute__((ext_vector_type(8)));
typedef short bshort4 __attribute__((ext_vector_type(4)));
typedef float floatx4 __attribute__((ext_vector_type(4)));

// Manual RTNE float->bf16 (4 VALU ops). NOTE: do NOT use __float2bfloat16 here --
// r6 measured it as the legacy TRUNCATING conversion on this ROCm (absmax 4.9e-4
// -> 2.0e-3). r7 showed the RTNE cost is only visible in fmha (~6us), GEMMs are
// barrier-bound and insensitive. Accuracy wins: keep RTNE.
__device__ __forceinline__ unsigned short f2b(float x) {
    unsigned int u = __float_as_uint(x);
    return (unsigned short)((u + 0x7fffu + ((u >> 16) & 1u)) >> 16);
}
__device__ __forceinline__ float b2f_(unsigned short h) {
    return __uint_as_float(((unsigned int)h) << 16);
}

// ---------------- embedding: depot/customer linear ----------------
__global__ __launch_bounds__(256) void embed_k(
    const float* __restrict__ dep, const float* __restrict__ cus,
    const float* __restrict__ Wd, const float* __restrict__ bd,
    const float* __restrict__ Wc3, const float* __restrict__ bc,
    float* __restrict__ x)
{
    int idx = blockIdx.x * 256 + threadIdx.x;   // < B*N*E = 2129920
    int e = idx & 127;
    int bn = idx >> 7;
    int n = bn % NN;
    int b = bn / NN;
    float a;
    if (n < DEPOT_) {
        a = bd[e];
        const float* f = dep + ((size_t)(b * DEPOT_ + n)) * 4;
        #pragma unroll
        for (int j = 0; j < 4; j++) a += f[j] * Wd[e * 4 + j];
    } else {
        a = bc[e];
        const float* f = cus + ((size_t)(b * 500 + (n - DEPOT_))) * 3;
        #pragma unroll
        for (int j = 0; j < 3; j++) a += f[j] * Wc3[e * 3 + j];
    }
    x[idx] = a;
}

// ---------------- weight pre-conversion: fp32 -> hi/lo bf16 planes ----------------
#define WLS 196608
#define WDEC 1179648
#define WTOT 1277952
__global__ __launch_bounds__(256) void wconv_k(
    const float* __restrict__ Wq, const float* __restrict__ Wk, const float* __restrict__ Wv,
    const float* __restrict__ Wc, const float* __restrict__ fW1, const float* __restrict__ fW2,
    const float* __restrict__ dWk, const float* __restrict__ dWv, const float* __restrict__ dWc,
    const float* __restrict__ Wql, const float* __restrict__ Wqr,
    unsigned short* __restrict__ WH, unsigned short* __restrict__ WL)
{
    int idx = blockIdx.x * 256 + threadIdx.x;
    if (idx >= WTOT) return;
    const float* src;
    if (idx < WDEC) {
        int i = idx / WLS, r = idx % WLS;
        if (r < 49152) {
            int row = r >> 7, col = r & 127;
            const float* w = row < 128 ? Wq : (row < 256 ? Wk : Wv);
            src = w + (size_t)i * 16384 + (size_t)(row & 127) * 128 + col;
        } else if (r < 65536) {
            src = Wc + (size_t)i * 16384 + (r - 49152);
        } else if (r < 131072) {
            src = fW1 + (size_t)i * 65536 + (r - 65536);
        } else {
            src = fW2 + (size_t)i * 65536 + (r - 131072);
        }
    } else {
        int r = idx - WDEC;
        if (r < 32768) {
            int row = r >> 7, col = r & 127;
            src = (row < 128 ? dWk : dWv) + (size_t)(row & 127) * 128 + col;
        } else if (r < 49152) {
            src = dWc + (r - 32768);
        } else {
            int rr = r - 49152;
            int row = rr >> 7, col = rr & 127;
            if (row < 128)      src = Wqr + (size_t)row * 257 + col;
            else if (row < 256) src = Wql + (size_t)(row - 128) * 256 + col;
            else                src = Wql + (size_t)(row - 256) * 256 + 128 + col;
        }
    }
    float v = *src;
    unsigned short h = f2b(v);
    WH[idx] = h;
    WL[idx] = f2b(v - b2f_(h));
}

// ---------------- bf16x3 MFMA GEMM with pre-converted weights ----------------
#define AP 40
__global__ __launch_bounds__(256) void gemm_pc_k(
    const float* __restrict__ A, int lda,
    const unsigned short* __restrict__ WH, const unsigned short* __restrict__ WL, int ldw,
    const float* __restrict__ bias,
    float* __restrict__ C, int ldc,
    int K, int relu)
{
    __shared__ __align__(16) unsigned short Ah[128][AP];
    __shared__ __align__(16) unsigned short Al[128][AP];
    __shared__ __align__(16) unsigned short Bh[64][AP];
    __shared__ __align__(16) unsigned short Bl[64][AP];

    int t = threadIdx.x;
    int w = t >> 6, lane = t & 63;
    int frow = lane & 15, fq = lane >> 4;
    int n0 = blockIdx.x * 64, m0 = blockIdx.y * 128;

    int arow = t & 127, ahalf = (t >> 7) * 16;
    int brow = t & 63,  bq    = (t >> 6) * 8;

    floatx4 acc[2][4];
    #pragma unroll
    for (int i = 0; i < 2; i++)
        #pragma unroll
        for (int j = 0; j < 4; j++)
            acc[i][j] = (floatx4){0.0f, 0.0f, 0.0f, 0.0f};

    for (int k0 = 0; k0 < K; k0 += 32) {
        {
            const float* Ap = A + (size_t)(m0 + arow) * lda + k0 + ahalf;
            float vr[16];
            #pragma unroll
            for (int j = 0; j < 4; j++) {
                float4 v = ((const float4*)Ap)[j];
                vr[j * 4 + 0] = v.x; vr[j * 4 + 1] = v.y;
                vr[j * 4 + 2] = v.z; vr[j * 4 + 3] = v.w;
            }
            short8 hv0, hv1, lv0, lv1;
            #pragma unroll
            for (int j = 0; j < 8; j++) {
                unsigned short h = f2b(vr[j]);
                hv0[j] = (short)h;
                lv0[j] = (short)f2b(vr[j] - b2f_(h));
            }
            #pragma unroll
            for (int j = 0; j < 8; j++) {
                unsigned short h = f2b(vr[8 + j]);
                hv1[j] = (short)h;
                lv1[j] = (short)f2b(vr[8 + j] - b2f_(h));
            }
            *((short8*)&Ah[arow][ahalf])     = hv0;
            *((short8*)&Ah[arow][ahalf + 8]) = hv1;
            *((short8*)&Al[arow][ahalf])     = lv0;
            *((short8*)&Al[arow][ahalf + 8]) = lv1;
        }
        {
            size_t wo = (size_t)(n0 + brow) * ldw + k0 + bq;
            *((short8*)&Bh[brow][bq]) = *((const short8*)(WH + wo));
            *((short8*)&Bl[brow][bq]) = *((const short8*)(WL + wo));
        }
        __syncthreads();

        short8 ah0 = *((const short8*)&Ah[w * 32 + frow][fq * 8]);
        short8 ah1 = *((const short8*)&Ah[w * 32 + 16 + frow][fq * 8]);
        short8 al0 = *((const short8*)&Al[w * 32 + frow][fq * 8]);
        short8 al1 = *((const short8*)&Al[w * 32 + 16 + frow][fq * 8]);
        #pragma unroll
        for (int nt = 0; nt < 4; nt++) {
            short8 bh = *((const short8*)&Bh[nt * 16 + frow][fq * 8]);
            short8 bl = *((const short8*)&Bl[nt * 16 + frow][fq * 8]);
            acc[0][nt] = __builtin_amdgcn_mfma_f32_16x16x32_bf16(ah0, bh, acc[0][nt], 0, 0, 0);
            acc[1][nt] = __builtin_amdgcn_mfma_f32_16x16x32_bf16(ah1, bh, acc[1][nt], 0, 0, 0);
            acc[0][nt] = __builtin_amdgcn_mfma_f32_16x16x32_bf16(ah0, bl, acc[0][nt], 0, 0, 0);
            acc[1][nt] = __builtin_amdgcn_mfma_f32_16x16x32_bf16(ah1, bl, acc[1][nt], 0, 0, 0);
            acc[0][nt] = __builtin_amdgcn_mfma_f32_16x16x32_bf16(al0, bh, acc[0][nt], 0, 0, 0);
            acc[1][nt] = __builtin_amdgcn_mfma_f32_16x16x32_bf16(al1, bh, acc[1][nt], 0, 0, 0);
        }
        __syncthreads();
    }

    #pragma unroll
    for (int nt = 0; nt < 4; nt++) {
        int col = n0 + nt * 16 + frow;
        float bv = bias ? bias[col] : 0.0f;
        #pragma unroll
        for (int mt = 0; mt < 2; mt++) {
            int rbase = m0 + w * 32 + mt * 16 + fq * 4;
            #pragma unroll
            for (int r = 0; r < 4; r++) {
                float v = acc[mt][nt][r] + bv;
                if (relu) v = fmaxf(v, 0.0f);
                C[(size_t)(rbase + r) * ldc + col] = v;
            }
        }
    }
}

// ---------------- fused 3-way GEMM (QKV / dec-KV / R+L1) ----------------
// pack=1: outputs written head-major [B*H][N][16] (for fmha); pack=0: standard [B*N][E].
__global__ __launch_bounds__(256) void gemm_qkv3_k(
    const float* __restrict__ A, int lda,
    const unsigned short* __restrict__ WH, const unsigned short* __restrict__ WL, int ldw,
    float* __restrict__ C0, float* __restrict__ C1, float* __restrict__ C2,
    int ldc, int K, int pack)
{
    __shared__ __align__(16) unsigned short Ah[128][AP];
    __shared__ __align__(16) unsigned short Al[128][AP];
    __shared__ __align__(16) unsigned short Bh[64][AP];
    __shared__ __align__(16) unsigned short Bl[64][AP];

    int t = threadIdx.x;
    int w = t >> 6, lane = t & 63;
    int frow = lane & 15, fq = lane >> 4;
    int nb = blockIdx.x;
    int which = nb >> 1;
    float* C = which == 0 ? C0 : (which == 1 ? C1 : C2);
    int n0w = nb * 64;            // row in stacked weight plane
    int n0c = (nb & 1) * 64;      // col in the selected C
    int m0 = blockIdx.y * 128;

    int arow = t & 127, ahalf = (t >> 7) * 16;
    int brow = t & 63,  bq    = (t >> 6) * 8;

    floatx4 acc[2][4];
    #pragma unroll
    for (int i = 0; i < 2; i++)
        #pragma unroll
        for (int j = 0; j < 4; j++)
            acc[i][j] = (floatx4){0.0f, 0.0f, 0.0f, 0.0f};

    for (int k0 = 0; k0 < K; k0 += 32) {
        {
            const float* Ap = A + (size_t)(m0 + arow) * lda + k0 + ahalf;
            float vr[16];
            #pragma unroll
            for (int j = 0; j < 4; j++) {
                float4 v = ((const float4*)Ap)[j];
                vr[j * 4 + 0] = v.x; vr[j * 4 + 1] = v.y;
                vr[j * 4 + 2] = v.z; vr[j * 4 + 3] = v.w;
            }
            short8 hv0, hv1, lv0, lv1;
            #pragma unroll
            for (int j = 0; j < 8; j++) {
                unsigned short h = f2b(vr[j]);
                hv0[j] = (short)h;
                lv0[j] = (short)f2b(vr[j] - b2f_(h));
            }
            #pragma unroll
            for (int j = 0; j < 8; j++) {
                unsigned short h = f2b(vr[8 + j]);
                hv1[j] = (short)h;
                lv1[j] = (short)f2b(vr[8 + j] - b2f_(h));
            }
            *((short8*)&Ah[arow][ahalf])     = hv0;
            *((short8*)&Ah[arow][ahalf + 8]) = hv1;
            *((short8*)&Al[arow][ahalf])     = lv0;
            *((short8*)&Al[arow][ahalf + 8]) = lv1;
        }
        {
            size_t wo = (size_t)(n0w + brow) * ldw + k0 + bq;
            *((short8*)&Bh[brow][bq]) = *((const short8*)(WH + wo));
            *((short8*)&Bl[brow][bq]) = *((const short8*)(WL + wo));
        }
        __syncthreads();

        short8 ah0 = *((const short8*)&Ah[w * 32 + frow][fq * 8]);
        short8 ah1 = *((const short8*)&Ah[w * 32 + 16 + frow][fq * 8]);
        short8 al0 = *((const short8*)&Al[w * 32 + frow][fq * 8]);
        short8 al1 = *((const short8*)&Al[w * 32 + 16 + frow][fq * 8]);
        #pragma unroll
        for (int nt = 0; nt < 4; nt++) {
            short8 bh = *((const short8*)&Bh[nt * 16 + frow][fq * 8]);
            short8 bl = *((const short8*)&Bl[nt * 16 + frow][fq * 8]);
            acc[0][nt] = __builtin_amdgcn_mfma_f32_16x16x32_bf16(ah0, bh, acc[0][nt], 0, 0, 0);
            acc[1][nt] = __builtin_amdgcn_mfma_f32_16x16x32_bf16(ah1, bh, acc[1][nt], 0, 0, 0);
            acc[0][nt] = __builtin_amdgcn_mfma_f32_16x16x32_bf16(ah0, bl, acc[0][nt], 0, 0, 0);
            acc[1][nt] = __builtin_amdgcn_mfma_f32_16x16x32_bf16(ah1, bl, acc[1][nt], 0, 0, 0);
            acc[0][nt] = __builtin_amdgcn_mfma_f32_16x16x32_bf16(al0, bh, acc[0][nt], 0, 0, 0);
            acc[1][nt] = __builtin_amdgcn_mfma_f32_16x16x32_bf16(al1, bh, acc[1][nt], 0, 0, 0);
        }
        __syncthreads();
    }

    #pragma unroll
    for (int nt = 0; nt < 4; nt++) {
        int col = n0c + nt * 16 + frow;
        int hh = col >> 4, dd = col & 15;
        #pragma unroll
        for (int mt = 0; mt < 2; mt++) {
            int rbase = m0 + w * 32 + mt * 16 + fq * 4;
            #pragma unroll
            for (int r = 0; r < 4; r++) {
                int row = rbase + r;
                if (pack) {
                    int b2 = row / NN, n2 = row - b2 * NN;
                    C[((size_t)(b2 * HH + hh) * NN + n2) * 16 + dd] = acc[mt][nt][r];
                } else {
                    C[(size_t)row * ldc + col] = acc[mt][nt][r];
                }
            }
        }
    }
}

// ---------------- score GEMM (NT) with tanh epilogue (fp32) ----------------
#define GT 64
#define GK 32
#define GP 36
__global__ __launch_bounds__(256) void sgemm_k(
    const float* __restrict__ A,    // score [B*520][128]
    const float* __restrict__ Enc,  // [B*520][128]
    float* __restrict__ C)          // [B][520][520]
{
    __shared__ float As[GT][GP];
    __shared__ float Ws[GT][GP];
    int t = threadIdx.x;
    int tx = t & 15, ty = t >> 4;
    int b = blockIdx.z;
    int m0 = blockIdx.y * GT, n0 = blockIdx.x * GT;
    int lr = t >> 2, lc = (t & 3) * 8;
    int mr = m0 + lr; if (mr >= NN) mr = NN - 1;
    int nr = n0 + lr; if (nr >= NN) nr = NN - 1;
    float acc[4][4];
    #pragma unroll
    for (int i = 0; i < 4; i++)
        #pragma unroll
        for (int j = 0; j < 4; j++) acc[i][j] = 0.0f;

    for (int k0 = 0; k0 < EE; k0 += GK) {
        const float* Ap = A + ((size_t)(b * NN + mr)) * EE + k0 + lc;
        const float* Wp = Enc + ((size_t)(b * NN + nr)) * EE + k0 + lc;
        float4 av0 = *((const float4*)Ap), av1 = *((const float4*)(Ap + 4));
        float4 wv0 = *((const float4*)Wp), wv1 = *((const float4*)(Wp + 4));
        *((float4*)&As[lr][lc]) = av0; *((float4*)&As[lr][lc + 4]) = av1;
        *((float4*)&Ws[lr][lc]) = wv0; *((float4*)&Ws[lr][lc + 4]) = wv1;
        __syncthreads();
        #pragma unroll
        for (int kk = 0; kk < GK; kk += 2) {
            float2 a0 = *((const float2*)&As[ty][kk]);
            float2 a1 = *((const float2*)&As[ty + 16][kk]);
            float2 a2 = *((const float2*)&As[ty + 32][kk]);
            float2 a3 = *((const float2*)&As[ty + 48][kk]);
            float2 w0 = *((const float2*)&Ws[tx][kk]);
            float2 w1 = *((const float2*)&Ws[tx + 16][kk]);
            float2 w2 = *((const float2*)&Ws[tx + 32][kk]);
            float2 w3 = *((const float2*)&Ws[tx + 48][kk]);
            acc[0][0] += a0.x * w0.x + a0.y * w0.y;
            acc[0][1] += a0.x * w1.x + a0.y * w1.y;
            acc[0][2] += a0.x * w2.x + a0.y * w2.y;
            acc[0][3] += a0.x * w3.x + a0.y * w3.y;
            acc[1][0] += a1.x * w0.x + a1.y * w0.y;
            acc[1][1] += a1.x * w1.x + a1.y * w1.y;
            acc[1][2] += a1.x * w2.x + a1.y * w2.y;
            acc[1][3] += a1.x * w3.x + a1.y * w3.y;
            acc[2][0] += a2.x * w0.x + a2.y * w0.y;
            acc[2][1] += a2.x * w1.x + a2.y * w1.y;
            acc[2][2] += a2.x * w2.x + a2.y * w2.y;
            acc[2][3] += a2.x * w3.x + a2.y * w3.y;
            acc[3][0] += a3.x * w0.x + a3.y * w0.y;
            acc[3][1] += a3.x * w1.x + a3.y * w1.y;
            acc[3][2] += a3.x * w2.x + a3.y * w2.y;
            acc[3][3] += a3.x * w3.x + a3.y * w3.y;
        }
        __syncthreads();
    }
    #pragma unroll
    for (int i = 0; i < 4; i++) {
        int m = m0 + ty + 16 * i;
        if (m >= NN) continue;
        #pragma unroll
        for (int j = 0; j < 4; j++) {
            int n = n0 + tx + 16 * j;
            if (n >= NN) continue;
            float v = 10.0f * tanhf(acc[i][j] * 0.088388347648318447f);
            C[((size_t)(b * NN + m)) * NN + n] = v;
        }
    }
}

// ---------------- row softmax: out = softmax(logits + mask) ----------------
__global__ __launch_bounds__(64) void smax_k(
    const float* __restrict__ L, const float* __restrict__ mask,
    float* __restrict__ out)
{
    int bm = blockIdx.x;
    int t = threadIdx.x;
    const float* Lr = L + (size_t)bm * NN;
    const float* Mr = mask + (size_t)bm * NN;
    float v[9];
    float mx = -1e30f;
    #pragma unroll
    for (int i = 0; i < 9; i++) {
        int idx = t + i * 64;
        if (idx < NN) { v[i] = Lr[idx] + Mr[idx]; mx = fmaxf(mx, v[i]); }
        else v[i] = -1e30f;
    }
    #pragma unroll
    for (int o = 32; o > 0; o >>= 1) mx = fmaxf(mx, __shfl_xor(mx, o));
    float s = 0.0f;
    #pragma unroll
    for (int i = 0; i < 9; i++) {
        int idx = t + i * 64;
        float e = (idx < NN) ? expf(v[i] - mx) : 0.0f;
        v[i] = e; s += e;
    }
    #pragma unroll
    for (int o = 32; o > 0; o >>= 1) s += __shfl_xor(s, o);
    float inv = 1.0f / s;
    #pragma unroll
    for (int i = 0; i < 9; i++) {
        int idx = t + i * 64;
        if (idx < NN) out[(size_t)bm * NN + idx] = v[i] * inv;
    }
}

// ---------------- persistent-KV MFMA flash attention v3.2 (bf16x3, fp32-equivalent) ----------------
// Grid (b=32, h=8, z=4), 256 threads (4 waves). id%8 = b%8: all 32 blocks of a
// batch share one XCD -> mask + K/V L2-resident (r5: FETCH 194->37MB).
// QK^T: two mfma_16x16x32 with [Kh|Kl] x {[Qh|Ql],[Ql|Qh]} = exact 4-term product.
// T13 defer-max REMOVED (r7: +6.5us/dispatch -- the per-frag ballot+branch costs
// more than the rescale it skips at NFRG=3). Dbuf LDS, 1 barrier/iter.
#define ATK 64
#define NFRG 3
__global__ __launch_bounds__(256) void fmha_pers_k(
    const float* __restrict__ Qp, const float* __restrict__ Kp,
    const float* __restrict__ Vp, const float* __restrict__ mask,
    float* __restrict__ O, int Nq, int Nk)
{
    __shared__ __align__(16) unsigned short Khl[2][ATK][40];  // [kc][0:16 hi-dk | 16:32 lo-dk]
    __shared__ __align__(16) unsigned short Vhi[2][16][72];
    __shared__ __align__(16) unsigned short Vlo[2][16][72];

    int b = blockIdx.x, h = blockIdx.y, z = blockIdx.z;
    int bh = b * HH + h;
    int t = threadIdx.x;
    int w = t >> 6, lane = t & 63;
    int r16 = lane & 15, g = lane >> 4;

    // ---- per-wave q fragments: fi = f*16 + z*4 + w covers rows [fi*16, fi*16+16) ----
    short8 qf[NFRG], qs[NFRG];      // [Qh|Ql] and swapped [Ql|Qh] 32-k operands
    floatx4 o_acc[NFRG];
    float m_i[NFRG], l_i[NFRG];
    const float* mrowf[NFRG];
    const float* QpB = Qp + (size_t)bh * Nq * 16;
    #pragma unroll
    for (int f = 0; f < NFRG; f++) {
        int fi = f * 16 + z * 4 + w;
        int qg = fi * 16 + r16;
        int qc = qg < Nq ? qg : Nq - 1;
        const float* qp = QpB + (size_t)qc * 16 + 8 * (g & 1);
        float4 qv0 = *((const float4*)qp);
        float4 qv1 = *((const float4*)(qp + 4));
        float qa[8] = {qv0.x, qv0.y, qv0.z, qv0.w, qv1.x, qv1.y, qv1.z, qv1.w};
        #pragma unroll
        for (int j = 0; j < 8; j++) {
            unsigned short hh = f2b(qa[j]);
            unsigned short ll = f2b(qa[j] - b2f_(hh));
            qf[f][j] = (short)(g < 2 ? hh : ll);
            qs[f][j] = (short)(g < 2 ? ll : hh);
        }
        o_acc[f] = (floatx4){0.0f, 0.0f, 0.0f, 0.0f};
        m_i[f] = -1e30f; l_i[f] = 0.0f;
        mrowf[f] = mask ? (mask + ((size_t)(b * Nq + qc)) * Nk) : nullptr;
    }

    // ---- staging: 256 threads, float4/thread per array ----
    int srow = t >> 2, sc = (t & 3) * 4;
    const float* KpB = Kp + ((size_t)bh * Nk) * 16 + sc;
    const float* VpB = Vp + ((size_t)bh * Nk) * 16 + sc;

    {
        int krc = srow < Nk ? srow : Nk - 1;
        float4 kv = *((const float4*)(KpB + (size_t)krc * 16));
        float4 vv = *((const float4*)(VpB + (size_t)krc * 16));
        float ka[4] = {kv.x, kv.y, kv.z, kv.w};
        float va[4] = {vv.x, vv.y, vv.z, vv.w};
        bshort4 khv, klv;
        #pragma unroll
        for (int j = 0; j < 4; j++) {
            unsigned short hh = f2b(ka[j]);
            khv[j] = (short)hh;
            klv[j] = (short)f2b(ka[j] - b2f_(hh));
        }
        *((bshort4*)&Khl[0][srow][sc])      = khv;
        *((bshort4*)&Khl[0][srow][16 + sc]) = klv;
        #pragma unroll
        for (int j = 0; j < 4; j++) {
            unsigned short hh = f2b(va[j]);
            Vhi[0][sc + j][srow] = hh;
            Vlo[0][sc + j][srow] = (unsigned short)f2b(va[j] - b2f_(hh));
        }
    }
    __syncthreads();

    int nkt = (Nk + ATK - 1) / ATK;
    for (int kt = 0; kt < nkt; kt++) {
        int cur = kt & 1;
        int k0 = kt * ATK;

        // ---- prefetch next K/V tile to regs (HBM/L2 latency hides under compute) ----
        float4 nkv, nvv;
        bool pf = (kt + 1 < nkt);
        if (pf) {
            int kr = k0 + ATK + srow;
            int krc = kr < Nk ? kr : Nk - 1;
            nkv = *((const float4*)(KpB + (size_t)krc * 16));
            nvv = *((const float4*)(VpB + (size_t)krc * 16));
        }

        // ---- hoisted mask loads for this tile (issue under the QK MFMAs) ----
        float mvv[NFRG][4][4];
        if (mask) {
            #pragma unroll
            for (int f = 0; f < NFRG; f++) {
                #pragma unroll
                for (int s = 0; s < 4; s++) {
                    int c0 = k0 + s * 16 + 4 * g;
                    if (c0 + 3 < Nk) {
                        float4 m4 = *((const float4*)(mrowf[f] + c0));
                        mvv[f][s][0] = m4.x; mvv[f][s][1] = m4.y;
                        mvv[f][s][2] = m4.z; mvv[f][s][3] = m4.w;
                    } else {
                        #pragma unroll
                        for (int r = 0; r < 4; r++)
                            mvv[f][s][r] = (c0 + r < Nk) ? mrowf[f][c0 + r] : 0.0f;
                    }
                }
            }
        }

        // ---- K/V fragments for this tile (shared by all frags of the wave) ----
        short8 kfr[4];
        bshort4 vhf[4], vlf[4];
        #pragma unroll
        for (int s = 0; s < 4; s++) {
            kfr[s] = *((const short8*)&Khl[cur][s * 16 + r16][8 * g]);
            vhf[s] = *((const bshort4*)&Vhi[cur][r16][s * 16 + 4 * g]);
            vlf[s] = *((const bshort4*)&Vlo[cur][r16][s * 16 + 4 * g]);
        }

        #pragma unroll
        for (int f = 0; f < NFRG; f++) {
            int fi = f * 16 + z * 4 + w;
            if (fi * 16 >= Nq) continue;   // wave-uniform

            // ---- S^T: 4 sub-tiles x 2 passes of 16x16x32 (exact 4-term product) ----
            float p[4][4];
            #pragma unroll
            for (int s = 0; s < 4; s++) {
                floatx4 a = (floatx4){0.0f, 0.0f, 0.0f, 0.0f};
                a = __builtin_amdgcn_mfma_f32_16x16x32_bf16(kfr[s], qf[f], a, 0, 0, 0);
                a = __builtin_amdgcn_mfma_f32_16x16x32_bf16(kfr[s], qs[f], a, 0, 0, 0);
                #pragma unroll
                for (int r = 0; r < 4; r++) p[s][r] = a[r];
            }

            // ---- scale + mask + bounds ----
            #pragma unroll
            for (int s = 0; s < 4; s++) {
                int c0 = k0 + s * 16 + 4 * g;
                #pragma unroll
                for (int r = 0; r < 4; r++) {
                    float mv = mask ? mvv[f][s][r] : 0.0f;
                    p[s][r] = (c0 + r < Nk) ? (p[s][r] * 0.25f + mv) : -1e30f;
                }
            }

            // ---- online softmax (per q = lane&15) ----
            float tmax = -1e30f;
            #pragma unroll
            for (int s = 0; s < 4; s++)
                #pragma unroll
                for (int r = 0; r < 4; r++) tmax = fmaxf(tmax, p[s][r]);
            tmax = fmaxf(tmax, __shfl_xor(tmax, 16));
            tmax = fmaxf(tmax, __shfl_xor(tmax, 32));
            float m_new = fmaxf(m_i[f], tmax);
            float alpha = __expf(m_i[f] - m_new);
            float lloc = 0.0f;
            #pragma unroll
            for (int s = 0; s < 4; s++) {
                #pragma unroll
                for (int r = 0; r < 4; r++) {
                    float e = __expf(p[s][r] - m_new);
                    p[s][r] = e; lloc += e;
                }
            }
            lloc += __shfl_xor(lloc, 16);
            lloc += __shfl_xor(lloc, 32);
            l_i[f] = l_i[f] * alpha + lloc;
            m_i[f] = m_new;
            #pragma unroll
            for (int r = 0; r < 4; r++) {
                float ar = __shfl(alpha, 4 * g + r);
                o_acc[f][r] *= ar;
            }

            // ---- PV: p is already the x16 A-frag (kc = 4g+r) ----
            #pragma unroll
            for (int s = 0; s < 4; s++) {
                bshort4 ph, pl;
                #pragma unroll
                for (int r = 0; r < 4; r++) {
                    unsigned short hh = f2b(p[s][r]);
                    ph[r] = (short)hh;
                    pl[r] = (short)f2b(p[s][r] - b2f_(hh));
                }
                o_acc[f] = __builtin_amdgcn_mfma_f32_16x16x16bf16_1k(ph, vhf[s], o_acc[f], 0, 0, 0);
                o_acc[f] = __builtin_amdgcn_mfma_f32_16x16x16bf16_1k(ph, vlf[s], o_acc[f], 0, 0, 0);
                o_acc[f] = __builtin_amdgcn_mfma_f32_16x16x16bf16_1k(pl, vhf[s], o_acc[f], 0, 0, 0);
            }
        }

        // ---- write next tile into the other buffer; one barrier per iteration ----
        if (pf) {
            int nb = cur ^ 1;
            float ka[4] = {nkv.x, nkv.y, nkv.z, nkv.w};
            float va[4] = {nvv.x, nvv.y, nvv.z, nvv.w};
            bshort4 khv, klv;
            #pragma unroll
            for (int j = 0; j < 4; j++) {
                unsigned short hh = f2b(ka[j]);
                khv[j] = (short)hh;
                klv[j] = (short)f2b(ka[j] - b2f_(hh));
            }
            *((bshort4*)&Khl[nb][srow][sc])      = khv;
            *((bshort4*)&Khl[nb][srow][16 + sc]) = klv;
            #pragma unroll
            for (int j = 0; j < 4; j++) {
                unsigned short hh = f2b(va[j]);
                Vhi[nb][sc + j][srow] = hh;
                Vlo[nb][sc + j][srow] = (unsigned short)f2b(va[j] - b2f_(hh));
            }
        }
        __syncthreads();
    }

    // ---- epilogue: O reg r is (q-row 4g+r, d = r16); l lives at lane q ----
    #pragma unroll
    for (int f = 0; f < NFRG; f++) {
        int fi = f * 16 + z * 4 + w;
        if (fi * 16 >= Nq) continue;
        #pragma unroll
        for (int r = 0; r < 4; r++) {
            float lr = __shfl(l_i[f], 4 * g + r);
            int qrow = fi * 16 + 4 * g + r;
            if (qrow < Nq)
                O[((size_t)(b * Nq + qrow)) * EE + h * 16 + r16] = o_acc[f][r] / lr;
        }
    }
}

// ---------------- InstanceNorm over node axis (coalesced) ----------------
// Old layout had e FIXED per block -> per-lane stride 512B, 64 lines per load.
// New: grid (b, eg of 16 e's), 256 threads: tx = e offset (coalesced across
// lanes), tn = n stride. Per-e partial sums combined via a 16x16 LDS tile.
__global__ __launch_bounds__(256) void inorm_k(
    const float* __restrict__ X, const float* __restrict__ Y,
    const float* __restrict__ g, const float* __restrict__ bb,
    float* __restrict__ Out)
{
    int b = blockIdx.x, eg = blockIdx.y;
    int t = threadIdx.x;
    int tx = t & 15, tn = t >> 4;
    int e = eg * 16 + tx;
    const float* Xb = X + ((size_t)b * NN) * EE + e;
    const float* Yb = Y + ((size_t)b * NN) * EE + e;
    float s = 0.0f, s2 = 0.0f;
    for (int n = tn; n < NN; n += 16) {
        float v = Xb[(size_t)n * EE] + Yb[(size_t)n * EE];
        s += v; s2 += v * v;
    }
    __shared__ float rs[16][17], rs2[16][17];
    rs[tn][tx] = s; rs2[tn][tx] = s2;
    __syncthreads();
    float st = 0.0f, st2 = 0.0f;
    #pragma unroll
    for (int j = 0; j < 16; j++) { st += rs[j][tx]; st2 += rs2[j][tx]; }
    float mu = st * (1.0f / NN);
    float var = st2 * (1.0f / NN) - mu * mu;
    float inv = rsqrtf(var + 1e-5f);
    float gg = g[e], bv = bb[e];
    float* Ob = Out + ((size_t)b * NN) * EE + e;
    for (int n = tn; n < NN; n += 16) {
        float v = Xb[(size_t)n * EE] + Yb[(size_t)n * EE];
        Ob[(size_t)n * EE] = (v - mu) * inv * gg + bv;
    }
}

__global__ void zero_k(float* p, int n) {
    int i = blockIdx.x * 256 + threadIdx.x;
    if (i < n) p[i] = 0.0f;
}

__global__ __launch_bounds__(128) void encsum_k(const float* __restrict__ enc, float* __restrict__ esum) {
    int b = blockIdx.x, ch = blockIdx.y, t = threadIdx.x;
    float a = 0.0f;
    for (int i = 0; i < 65; i++) {
        int n = ch * 65 + i;
        a += enc[((size_t)(b * NN + n)) * EE + t];
    }
    atomicAdd(&esum[b * EE + t], a);
}

// mt[b,e] = sum_f (esum[b,f]/N) * Wr[e, 128+f]
__global__ __launch_bounds__(128) void meanterm_k(
    const float* __restrict__ esum, const float* __restrict__ Wr, float* __restrict__ mt)
{
    int b = blockIdx.x, t = threadIdx.x;
    __shared__ float em[128];
    em[t] = esum[b * EE + t] * (1.0f / NN);
    __syncthreads();
    const float* w = Wr + (size_t)t * 257 + 128;
    float a = 0.0f;
    for (int f = 0; f < 128; f++) a += em[f] * w[f];
    mt[b * EE + t] = a;
}

__global__ __launch_bounds__(128) void subtour_k(
    const float* __restrict__ enc, const int* __restrict__ subn,
    const int* __restrict__ subl, float* __restrict__ subm)
{
    int bm = blockIdx.x;
    int b = bm / MM;
    int t = threadIdx.x;
    int len = subl[bm];
    float acc = 0.0f; int cnt = 0;
    for (int l = 0; l < LL; l++) {
        int node = subn[(size_t)bm * LL + l];
        if (l < len && node >= DEPOT_) {
            acc += enc[((size_t)(b * NN + node)) * EE + t];
            cnt++;
        }
    }
    float cf = (float)(cnt < 1 ? 1 : cnt);
    subm[(size_t)bm * EE + t] = acc / cf;
}

// ---------------- decoder q: gather/blend, writes head-packed final_q ----------------
__global__ __launch_bounds__(128) void decq_gather_k(
    const float* __restrict__ R, const float* __restrict__ L1, const float* __restrict__ SM2,
    const float* __restrict__ mterm, const int* __restrict__ cur,
    const float* __restrict__ loadv, const int* __restrict__ sel,
    const float* __restrict__ Wqr, float* __restrict__ out)
{
    int bm = blockIdx.x;
    int b = bm / MM;
    int m = bm - b * MM;
    int t = threadIdx.x;
    int cn = cur[bm];
    int s2v = sel[(size_t)bm * 4 + 2];
    bool flag = (s2v >= DEPOT_) && (cn < DEPOT_);
    size_t eo = ((size_t)(b * NN + cn)) * EE + t;
    float q;
    if (flag) q = L1[eo] + SM2[(size_t)bm * EE + t];
    else      q = R[eo] + mterm[b * EE + t] + loadv[bm] * Wqr[(size_t)t * 257 + 256];
    out[((size_t)(b * HH + (t >> 4)) * MM + m) * 16 + (t & 15)] = q;
}

extern "C" void kernel_launch(void* const* d_in, const int* in_sizes, int n_in,
                              void* d_out, int out_size, void* d_ws, size_t ws_size,
                              hipStream_t stream)
{
    const float* depot = (const float*)d_in[0];
    const float* cust  = (const float*)d_in[1];
    const float* mask  = (const float*)d_in[2];
    const float* loadv = (const float*)d_in[3];
    const int*  cur   = (const int*)d_in[4];
    const int*  subn  = (const int*)d_in[5];
    const int*  subl  = (const int*)d_in[6];
    const int*  sel   = (const int*)d_in[7];
    const float* Wdep  = (const float*)d_in[8];
    const float* bdep  = (const float*)d_in[9];
    const float* Wcus  = (const float*)d_in[10];
    const float* bcus  = (const float*)d_in[11];
    const float* Wq    = (const float*)d_in[12];
    const float* Wk    = (const float*)d_in[13];
    const float* Wv    = (const float*)d_in[14];
    const float* Wc    = (const float*)d_in[15];
    const float* Wcb   = (const float*)d_in[16];
    const float* n1g   = (const float*)d_in[17];
    const float* n1b   = (const float*)d_in[18];
    const float* fW1   = (const float*)d_in[19];
    const float* fb1   = (const float*)d_in[20];
    const float* fW2   = (const float*)d_in[21];
    const float* fb2   = (const float*)d_in[22];
    const float* n2g   = (const float*)d_in[23];
    const float* n2b   = (const float*)d_in[24];
    const float* Wql   = (const float*)d_in[25];
    const float* Wqr   = (const float*)d_in[26];
    const float* dWk   = (const float*)d_in[27];
    const float* dWv   = (const float*)d_in[28];
    const float* dWc   = (const float*)d_in[29];
    const float* dWcb  = (const float*)d_in[30];

    const size_t SZ = (size_t)BB * NN * EE;           // 2,129,920
    float* f0 = (float*)d_ws;       // x / encoded
    float* f1 = f0 + SZ;            // q / k_d (packed) / logits (spans f1..f5)
    float* f2 = f1 + SZ;            // k / v_d (packed)
    float* f3 = f2 + SZ;            // v (packed) / encsum + meanterm
    float* f4 = f3 + SZ;            // mh,ff2 out / sub_mean, dec attn
    float* f5 = f4 + SZ;            // x1 / final_q (packed)
    float* big = f5 + SZ;           // ffh (B*N*FFH) / R,L1,SM2 / dec score
    unsigned short* WHp = (unsigned short*)(big + (size_t)BB * NN * FFH_);
    unsigned short* WLp = WHp + WTOT;

    dim3 g4(EE / 64, (BB * NN) / 128);     // (2, 130)
    dim3 g16(FFH_ / 64, (BB * NN) / 128);  // (8, 130)
    dim3 gq3(6, (BB * NN) / 128);          // fused QKV
    dim3 gq2(4, (BB * NN) / 128);          // fused 2-way
    dim3 gmha(BB, HH, 4);                  // (32, 8, 4): id%8==b%8 -> per-batch L2 on one XCD
    dim3 gin(BB, 8);                       // coalesced inorm: (b, e-group)
    dim3 gsc((NN + GT - 1) / GT, (NN + GT - 1) / GT, BB);  // (9, 9, 32)

    wconv_k<<<(WTOT + 255) / 256, 256, 0, stream>>>(Wq, Wk, Wv, Wc, fW1, fW2,
                                                    dWk, dWv, dWc, Wql, Wqr, WHp, WLp);
    embed_k<<<(BB * NN * EE) / 256, 256, 0, stream>>>(depot, cust, Wdep, bdep, Wcus, bcus, f0);

    for (int i = 0; i < NL_; i++) {
        const unsigned short* lH = WHp + (size_t)i * WLS;
        const unsigned short* lL = WLp + (size_t)i * WLS;
        gemm_qkv3_k<<<gq3, 256, 0, stream>>>(f0, EE, lH, lL, EE, f1, f2, f3, EE, EE, 1);
        fmha_pers_k<<<gmha, 256, 0, stream>>>(f1, f2, f3, nullptr, f4, NN, NN);
        gemm_pc_k<<<g4, 256, 0, stream>>>(f4, EE, lH + 49152, lL + 49152, EE, Wcb + i * EE, f1, EE, EE, 0);
        inorm_k<<<gin, 256, 0, stream>>>(f0, f1, n1g + i * EE, n1b + i * EE, f5);
        gemm_pc_k<<<g16, 256, 0, stream>>>(f5, EE, lH + 65536, lL + 65536, EE, fb1 + i * FFH_, big, FFH_, EE, 1);
        gemm_pc_k<<<g4, 256, 0, stream>>>(big, FFH_, lH + 131072, lL + 131072, FFH_, fb2 + i * EE, f1, EE, FFH_, 0);
        inorm_k<<<gin, 256, 0, stream>>>(f5, f1, n2g + i * EE, n2b + i * EE, f0);
    }

    // ---- decoder ----
    const unsigned short* dH = WHp + WDEC;
    const unsigned short* dL = WLp + WDEC;
    gemm_qkv3_k<<<gq2, 256, 0, stream>>>(f0, EE, dH, dL, EE, f1, f2, f2, EE, EE, 1);  // k_d, v_d packed

    zero_k<<<(BB * EE + 255) / 256, 256, 0, stream>>>(f3, BB * EE);
    encsum_k<<<dim3(BB, 8), 128, 0, stream>>>(f0, f3);
    meanterm_k<<<BB, 128, 0, stream>>>(f3, Wqr, f3 + BB * EE);
    subtour_k<<<BB * MM, 128, 0, stream>>>(f0, subn, subl, f4);

    // R (big), L1 (big+SZ) from encoded; SM2 (big+2SZ) from subm  (standard layout)
    gemm_qkv3_k<<<gq2, 256, 0, stream>>>(f0, EE, dH + 49152, dL + 49152, EE, big, big + SZ, big + SZ, EE, EE, 0);
    gemm_pc_k<<<g4, 256, 0, stream>>>(f4, EE, dH + 49152 + 32768, dL + 49152 + 32768, EE, nullptr, big + 2 * SZ, EE, EE, 0);
    decq_gather_k<<<BB * MM, 128, 0, stream>>>(big, big + SZ, big + 2 * SZ, f3 + BB * EE, cur, loadv, sel, Wqr, f5);

    fmha_pers_k<<<gmha, 256, 0, stream>>>(f5, f1, f2, mask, f4, MM, NN);
    gemm_pc_k<<<g4, 256, 0, stream>>>(f4, EE, dH + 32768, dL + 32768, EE, dWcb, big, EE, EE, 0);

    // logits (B x 520 x 520) at f1 (spans f1..f5; all dead now)
    sgemm_k<<<gsc, 256, 0, stream>>>(big, f0, f1);
    smax_k<<<BB * MM, 64, 0, stream>>>(f1, mask, (float*)d_out);
}

// Round 9
// 1484.812 us; speedup vs baseline: 1.2591x; 1.0431x over previous
//
#include <hip/hip_runtime.h>
#include <hip/hip_bf16.h>

#define BB 32
#define NN 520
#define MM 520
#define EE 128
#define HH 8
#define DKK 16
#define FFH_ 512
#define NL_ 6
#define DEPOT_ 20
#define LL 40

typedef short short8 __attribute__((ext_vector_type(8)));
typedef short bshort4 __attribute__((ext_vector_type(4)));
typedef float floatx4 __attribute__((ext_vector_type(4)));

// Manual RTNE float->bf16 (4 VALU ops) -- used where a value is converted once.
__device__ __forceinline__ unsigned short f2b(float x) {
    unsigned int u = __float_as_uint(x);
    return (unsigned short)((u + 0x7fffu + ((u >> 16) & 1u)) >> 16);
}
// Truncating float->bf16 (1 VALU op) -- ONLY for hi/lo SPLIT PAIRS, where the lo
// part captures the hi rounding residual exactly (rounding mode only affects the
// dropped 3rd-order term, ~2^-16 rel). r8 post-mortem: RTNE in fmha's P-split was
// the r7 fmha regression (432 VALU ops/tile); trunc restores r6's 81us.
__device__ __forceinline__ unsigned short f2b_t(float x) {
    return (unsigned short)(__float_as_uint(x) >> 16);
}
__device__ __forceinline__ float b2f_(unsigned short h) {
    return __uint_as_float(((unsigned int)h) << 16);
}

// ---------------- embedding: depot/customer linear ----------------
__global__ __launch_bounds__(256) void embed_k(
    const float* __restrict__ dep, const float* __restrict__ cus,
    const float* __restrict__ Wd, const float* __restrict__ bd,
    const float* __restrict__ Wc3, const float* __restrict__ bc,
    float* __restrict__ x)
{
    int idx = blockIdx.x * 256 + threadIdx.x;   // < B*N*E = 2129920
    int e = idx & 127;
    int bn = idx >> 7;
    int n = bn % NN;
    int b = bn / NN;
    float a;
    if (n < DEPOT_) {
        a = bd[e];
        const float* f = dep + ((size_t)(b * DEPOT_ + n)) * 4;
        #pragma unroll
        for (int j = 0; j < 4; j++) a += f[j] * Wd[e * 4 + j];
    } else {
        a = bc[e];
        const float* f = cus + ((size_t)(b * 500 + (n - DEPOT_))) * 3;
        #pragma unroll
        for (int j = 0; j < 3; j++) a += f[j] * Wc3[e * 3 + j];
    }
    x[idx] = a;
}

// ---------------- weight pre-conversion: fp32 -> hi/lo bf16 planes ----------------
#define WLS 196608
#define WDEC 1179648
#define WTOT 1277952
__global__ __launch_bounds__(256) void wconv_k(
    const float* __restrict__ Wq, const float* __restrict__ Wk, const float* __restrict__ Wv,
    const float* __restrict__ Wc, const float* __restrict__ fW1, const float* __restrict__ fW2,
    const float* __restrict__ dWk, const float* __restrict__ dWv, const float* __restrict__ dWc,
    const float* __restrict__ Wql, const float* __restrict__ Wqr,
    unsigned short* __restrict__ WH, unsigned short* __restrict__ WL)
{
    int idx = blockIdx.x * 256 + threadIdx.x;
    if (idx >= WTOT) return;
    const float* src;
    if (idx < WDEC) {
        int i = idx / WLS, r = idx % WLS;
        if (r < 49152) {
            int row = r >> 7, col = r & 127;
            const float* w = row < 128 ? Wq : (row < 256 ? Wk : Wv);
            src = w + (size_t)i * 16384 + (size_t)(row & 127) * 128 + col;
        } else if (r < 65536) {
            src = Wc + (size_t)i * 16384 + (r - 49152);
        } else if (r < 131072) {
            src = fW1 + (size_t)i * 65536 + (r - 65536);
        } else {
            src = fW2 + (size_t)i * 65536 + (r - 131072);
        }
    } else {
        int r = idx - WDEC;
        if (r < 32768) {
            int row = r >> 7, col = r & 127;
            src = (row < 128 ? dWk : dWv) + (size_t)(row & 127) * 128 + col;
        } else if (r < 49152) {
            src = dWc + (r - 32768);
        } else {
            int rr = r - 49152;
            int row = rr >> 7, col = rr & 127;
            if (row < 128)      src = Wqr + (size_t)row * 257 + col;
            else if (row < 256) src = Wql + (size_t)(row - 128) * 256 + col;
            else                src = Wql + (size_t)(row - 256) * 256 + 128 + col;
        }
    }
    float v = *src;
    unsigned short h = f2b(v);
    WH[idx] = h;
    WL[idx] = f2b(v - b2f_(h));
}

// ---------------- bf16x3 MFMA GEMM, double-buffered LDS (1 barrier/iter) ----------------
// r8 post-mortem: GEMMs are barrier-drain bound (2 full drains per 32-K step at
// ~1 block/CU). fmha's proven pattern applied: prefetch next chunk to regs BEFORE
// the MFMAs, convert+write to the OTHER LDS buffer after (disjoint memory -> no
// extra barrier), single __syncthreads per iter.
#define AP 40
__global__ __launch_bounds__(256) void gemm_pc_k(
    const float* __restrict__ A, int lda,
    const unsigned short* __restrict__ WH, const unsigned short* __restrict__ WL, int ldw,
    const float* __restrict__ bias,
    float* __restrict__ C, int ldc,
    int K, int relu)
{
    __shared__ __align__(16) unsigned short Ah[2][128][AP];
    __shared__ __align__(16) unsigned short Al[2][128][AP];
    __shared__ __align__(16) unsigned short Bh[2][64][AP];
    __shared__ __align__(16) unsigned short Bl[2][64][AP];

    int t = threadIdx.x;
    int w = t >> 6, lane = t & 63;
    int frow = lane & 15, fq = lane >> 4;
    int n0 = blockIdx.x * 64, m0 = blockIdx.y * 128;

    int arow = t & 127, ahalf = (t >> 7) * 16;
    int brow = t & 63,  bq    = (t >> 6) * 8;

    const float* Abase = A + (size_t)(m0 + arow) * lda + ahalf;
    const unsigned short* WHb = WH + (size_t)(n0 + brow) * ldw + bq;
    const unsigned short* WLb = WL + (size_t)(n0 + brow) * ldw + bq;

    floatx4 acc[2][4];
    #pragma unroll
    for (int i = 0; i < 2; i++)
        #pragma unroll
        for (int j = 0; j < 4; j++)
            acc[i][j] = (floatx4){0.0f, 0.0f, 0.0f, 0.0f};

    // ---- prologue: stage chunk 0 into buffer 0 ----
    {
        float vr[16];
        #pragma unroll
        for (int j = 0; j < 4; j++) {
            float4 v = ((const float4*)Abase)[j];
            vr[j * 4 + 0] = v.x; vr[j * 4 + 1] = v.y;
            vr[j * 4 + 2] = v.z; vr[j * 4 + 3] = v.w;
        }
        short8 hv0, hv1, lv0, lv1;
        #pragma unroll
        for (int j = 0; j < 8; j++) {
            unsigned short h = f2b(vr[j]);
            hv0[j] = (short)h;
            lv0[j] = (short)f2b(vr[j] - b2f_(h));
        }
        #pragma unroll
        for (int j = 0; j < 8; j++) {
            unsigned short h = f2b(vr[8 + j]);
            hv1[j] = (short)h;
            lv1[j] = (short)f2b(vr[8 + j] - b2f_(h));
        }
        *((short8*)&Ah[0][arow][ahalf])     = hv0;
        *((short8*)&Ah[0][arow][ahalf + 8]) = hv1;
        *((short8*)&Al[0][arow][ahalf])     = lv0;
        *((short8*)&Al[0][arow][ahalf + 8]) = lv1;
        *((short8*)&Bh[0][brow][bq]) = *((const short8*)WHb);
        *((short8*)&Bl[0][brow][bq]) = *((const short8*)WLb);
    }
    __syncthreads();

    int nkt = K >> 5;
    for (int kt = 0; kt < nkt; kt++) {
        int cur = kt & 1;
        bool pf = (kt + 1 < nkt);

        // ---- issue next chunk's global loads (hide under MFMA) ----
        float4 av[4];
        short8 nbh, nbl;
        if (pf) {
            const float* Ap = Abase + (kt + 1) * 32;
            #pragma unroll
            for (int j = 0; j < 4; j++) av[j] = ((const float4*)Ap)[j];
            nbh = *((const short8*)(WHb + (kt + 1) * 32));
            nbl = *((const short8*)(WLb + (kt + 1) * 32));
        }

        short8 ah0 = *((const short8*)&Ah[cur][w * 32 + frow][fq * 8]);
        short8 ah1 = *((const short8*)&Ah[cur][w * 32 + 16 + frow][fq * 8]);
        short8 al0 = *((const short8*)&Al[cur][w * 32 + frow][fq * 8]);
        short8 al1 = *((const short8*)&Al[cur][w * 32 + 16 + frow][fq * 8]);
        #pragma unroll
        for (int nt = 0; nt < 4; nt++) {
            short8 bh = *((const short8*)&Bh[cur][nt * 16 + frow][fq * 8]);
            short8 bl = *((const short8*)&Bl[cur][nt * 16 + frow][fq * 8]);
            acc[0][nt] = __builtin_amdgcn_mfma_f32_16x16x32_bf16(ah0, bh, acc[0][nt], 0, 0, 0);
            acc[1][nt] = __builtin_amdgcn_mfma_f32_16x16x32_bf16(ah1, bh, acc[1][nt], 0, 0, 0);
            acc[0][nt] = __builtin_amdgcn_mfma_f32_16x16x32_bf16(ah0, bl, acc[0][nt], 0, 0, 0);
            acc[1][nt] = __builtin_amdgcn_mfma_f32_16x16x32_bf16(ah1, bl, acc[1][nt], 0, 0, 0);
            acc[0][nt] = __builtin_amdgcn_mfma_f32_16x16x32_bf16(al0, bh, acc[0][nt], 0, 0, 0);
            acc[1][nt] = __builtin_amdgcn_mfma_f32_16x16x32_bf16(al1, bh, acc[1][nt], 0, 0, 0);
        }

        // ---- convert + write next chunk into the OTHER buffer ----
        if (pf) {
            int nb2 = cur ^ 1;
            float vr[16];
            #pragma unroll
            for (int j = 0; j < 4; j++) {
                vr[j * 4 + 0] = av[j].x; vr[j * 4 + 1] = av[j].y;
                vr[j * 4 + 2] = av[j].z; vr[j * 4 + 3] = av[j].w;
            }
            short8 hv0, hv1, lv0, lv1;
            #pragma unroll
            for (int j = 0; j < 8; j++) {
                unsigned short h = f2b(vr[j]);
                hv0[j] = (short)h;
                lv0[j] = (short)f2b(vr[j] - b2f_(h));
            }
            #pragma unroll
            for (int j = 0; j < 8; j++) {
                unsigned short h = f2b(vr[8 + j]);
                hv1[j] = (short)h;
                lv1[j] = (short)f2b(vr[8 + j] - b2f_(h));
            }
            *((short8*)&Ah[nb2][arow][ahalf])     = hv0;
            *((short8*)&Ah[nb2][arow][ahalf + 8]) = hv1;
            *((short8*)&Al[nb2][arow][ahalf])     = lv0;
            *((short8*)&Al[nb2][arow][ahalf + 8]) = lv1;
            *((short8*)&Bh[nb2][brow][bq]) = nbh;
            *((short8*)&Bl[nb2][brow][bq]) = nbl;
        }
        __syncthreads();
    }

    #pragma unroll
    for (int nt = 0; nt < 4; nt++) {
        int col = n0 + nt * 16 + frow;
        float bv = bias ? bias[col] : 0.0f;
        #pragma unroll
        for (int mt = 0; mt < 2; mt++) {
            int rbase = m0 + w * 32 + mt * 16 + fq * 4;
            #pragma unroll
            for (int r = 0; r < 4; r++) {
                float v = acc[mt][nt][r] + bv;
                if (relu) v = fmaxf(v, 0.0f);
                C[(size_t)(rbase + r) * ldc + col] = v;
            }
        }
    }
}

// ---------------- fused 3-way GEMM (QKV / dec-KV / R+L1), dbuf, K=128 ----------------
// pack=1: outputs written head-major [B*H][N][16] (for fmha); pack=0: standard [B*N][E].
__global__ __launch_bounds__(256) void gemm_qkv3_k(
    const float* __restrict__ A, int lda,
    const unsigned short* __restrict__ WH, const unsigned short* __restrict__ WL, int ldw,
    float* __restrict__ C0, float* __restrict__ C1, float* __restrict__ C2,
    int ldc, int K, int pack)
{
    __shared__ __align__(16) unsigned short Ah[2][128][AP];
    __shared__ __align__(16) unsigned short Al[2][128][AP];
    __shared__ __align__(16) unsigned short Bh[2][64][AP];
    __shared__ __align__(16) unsigned short Bl[2][64][AP];

    int t = threadIdx.x;
    int w = t >> 6, lane = t & 63;
    int frow = lane & 15, fq = lane >> 4;
    int nb = blockIdx.x;
    int which = nb >> 1;
    float* C = which == 0 ? C0 : (which == 1 ? C1 : C2);
    int n0w = nb * 64;            // row in stacked weight plane
    int n0c = (nb & 1) * 64;      // col in the selected C
    int m0 = blockIdx.y * 128;

    int arow = t & 127, ahalf = (t >> 7) * 16;
    int brow = t & 63,  bq    = (t >> 6) * 8;

    const float* Abase = A + (size_t)(m0 + arow) * lda + ahalf;
    const unsigned short* WHb = WH + (size_t)(n0w + brow) * ldw + bq;
    const unsigned short* WLb = WL + (size_t)(n0w + brow) * ldw + bq;

    floatx4 acc[2][4];
    #pragma unroll
    for (int i = 0; i < 2; i++)
        #pragma unroll
        for (int j = 0; j < 4; j++)
            acc[i][j] = (floatx4){0.0f, 0.0f, 0.0f, 0.0f};

    {
        float vr[16];
        #pragma unroll
        for (int j = 0; j < 4; j++) {
            float4 v = ((const float4*)Abase)[j];
            vr[j * 4 + 0] = v.x; vr[j * 4 + 1] = v.y;
            vr[j * 4 + 2] = v.z; vr[j * 4 + 3] = v.w;
        }
        short8 hv0, hv1, lv0, lv1;
        #pragma unroll
        for (int j = 0; j < 8; j++) {
            unsigned short h = f2b(vr[j]);
            hv0[j] = (short)h;
            lv0[j] = (short)f2b(vr[j] - b2f_(h));
        }
        #pragma unroll
        for (int j = 0; j < 8; j++) {
            unsigned short h = f2b(vr[8 + j]);
            hv1[j] = (short)h;
            lv1[j] = (short)f2b(vr[8 + j] - b2f_(h));
        }
        *((short8*)&Ah[0][arow][ahalf])     = hv0;
        *((short8*)&Ah[0][arow][ahalf + 8]) = hv1;
        *((short8*)&Al[0][arow][ahalf])     = lv0;
        *((short8*)&Al[0][arow][ahalf + 8]) = lv1;
        *((short8*)&Bh[0][brow][bq]) = *((const short8*)WHb);
        *((short8*)&Bl[0][brow][bq]) = *((const short8*)WLb);
    }
    __syncthreads();

    int nkt = K >> 5;
    for (int kt = 0; kt < nkt; kt++) {
        int cur = kt & 1;
        bool pf = (kt + 1 < nkt);

        float4 av[4];
        short8 nbh, nbl;
        if (pf) {
            const float* Ap = Abase + (kt + 1) * 32;
            #pragma unroll
            for (int j = 0; j < 4; j++) av[j] = ((const float4*)Ap)[j];
            nbh = *((const short8*)(WHb + (kt + 1) * 32));
            nbl = *((const short8*)(WLb + (kt + 1) * 32));
        }

        short8 ah0 = *((const short8*)&Ah[cur][w * 32 + frow][fq * 8]);
        short8 ah1 = *((const short8*)&Ah[cur][w * 32 + 16 + frow][fq * 8]);
        short8 al0 = *((const short8*)&Al[cur][w * 32 + frow][fq * 8]);
        short8 al1 = *((const short8*)&Al[cur][w * 32 + 16 + frow][fq * 8]);
        #pragma unroll
        for (int nt = 0; nt < 4; nt++) {
            short8 bh = *((const short8*)&Bh[cur][nt * 16 + frow][fq * 8]);
            short8 bl = *((const short8*)&Bl[cur][nt * 16 + frow][fq * 8]);
            acc[0][nt] = __builtin_amdgcn_mfma_f32_16x16x32_bf16(ah0, bh, acc[0][nt], 0, 0, 0);
            acc[1][nt] = __builtin_amdgcn_mfma_f32_16x16x32_bf16(ah1, bh, acc[1][nt], 0, 0, 0);
            acc[0][nt] = __builtin_amdgcn_mfma_f32_16x16x32_bf16(ah0, bl, acc[0][nt], 0, 0, 0);
            acc[1][nt] = __builtin_amdgcn_mfma_f32_16x16x32_bf16(ah1, bl, acc[1][nt], 0, 0, 0);
            acc[0][nt] = __builtin_amdgcn_mfma_f32_16x16x32_bf16(al0, bh, acc[0][nt], 0, 0, 0);
            acc[1][nt] = __builtin_amdgcn_mfma_f32_16x16x32_bf16(al1, bh, acc[1][nt], 0, 0, 0);
        }

        if (pf) {
            int nb2 = cur ^ 1;
            float vr[16];
            #pragma unroll
            for (int j = 0; j < 4; j++) {
                vr[j * 4 + 0] = av[j].x; vr[j * 4 + 1] = av[j].y;
                vr[j * 4 + 2] = av[j].z; vr[j * 4 + 3] = av[j].w;
            }
            short8 hv0, hv1, lv0, lv1;
            #pragma unroll
            for (int j = 0; j < 8; j++) {
                unsigned short h = f2b(vr[j]);
                hv0[j] = (short)h;
                lv0[j] = (short)f2b(vr[j] - b2f_(h));
            }
            #pragma unroll
            for (int j = 0; j < 8; j++) {
                unsigned short h = f2b(vr[8 + j]);
                hv1[j] = (short)h;
                lv1[j] = (short)f2b(vr[8 + j] - b2f_(h));
            }
            *((short8*)&Ah[nb2][arow][ahalf])     = hv0;
            *((short8*)&Ah[nb2][arow][ahalf + 8]) = hv1;
            *((short8*)&Al[nb2][arow][ahalf])     = lv0;
            *((short8*)&Al[nb2][arow][ahalf + 8]) = lv1;
            *((short8*)&Bh[nb2][brow][bq]) = nbh;
            *((short8*)&Bl[nb2][brow][bq]) = nbl;
        }
        __syncthreads();
    }

    #pragma unroll
    for (int nt = 0; nt < 4; nt++) {
        int col = n0c + nt * 16 + frow;
        int hh = col >> 4, dd = col & 15;
        #pragma unroll
        for (int mt = 0; mt < 2; mt++) {
            int rbase = m0 + w * 32 + mt * 16 + fq * 4;
            #pragma unroll
            for (int r = 0; r < 4; r++) {
                int row = rbase + r;
                if (pack) {
                    int b2 = row / NN, n2 = row - b2 * NN;
                    C[((size_t)(b2 * HH + hh) * NN + n2) * 16 + dd] = acc[mt][nt][r];
                } else {
                    C[(size_t)row * ldc + col] = acc[mt][nt][r];
                }
            }
        }
    }
}

// ---------------- score GEMM (NT) with tanh epilogue (fp32) ----------------
#define GT 64
#define GK 32
#define GP 36
__global__ __launch_bounds__(256) void sgemm_k(
    const float* __restrict__ A,    // score [B*520][128]
    const float* __restrict__ Enc,  // [B*520][128]
    float* __restrict__ C)          // [B][520][520]
{
    __shared__ float As[GT][GP];
    __shared__ float Ws[GT][GP];
    int t = threadIdx.x;
    int tx = t & 15, ty = t >> 4;
    int b = blockIdx.z;
    int m0 = blockIdx.y * GT, n0 = blockIdx.x * GT;
    int lr = t >> 2, lc = (t & 3) * 8;
    int mr = m0 + lr; if (mr >= NN) mr = NN - 1;
    int nr = n0 + lr; if (nr >= NN) nr = NN - 1;
    float acc[4][4];
    #pragma unroll
    for (int i = 0; i < 4; i++)
        #pragma unroll
        for (int j = 0; j < 4; j++) acc[i][j] = 0.0f;

    for (int k0 = 0; k0 < EE; k0 += GK) {
        const float* Ap = A + ((size_t)(b * NN + mr)) * EE + k0 + lc;
        const float* Wp = Enc + ((size_t)(b * NN + nr)) * EE + k0 + lc;
        float4 av0 = *((const float4*)Ap), av1 = *((const float4*)(Ap + 4));
        float4 wv0 = *((const float4*)Wp), wv1 = *((const float4*)(Wp + 4));
        *((float4*)&As[lr][lc]) = av0; *((float4*)&As[lr][lc + 4]) = av1;
        *((float4*)&Ws[lr][lc]) = wv0; *((float4*)&Ws[lr][lc + 4]) = wv1;
        __syncthreads();
        #pragma unroll
        for (int kk = 0; kk < GK; kk += 2) {
            float2 a0 = *((const float2*)&As[ty][kk]);
            float2 a1 = *((const float2*)&As[ty + 16][kk]);
            float2 a2 = *((const float2*)&As[ty + 32][kk]);
            float2 a3 = *((const float2*)&As[ty + 48][kk]);
            float2 w0 = *((const float2*)&Ws[tx][kk]);
            float2 w1 = *((const float2*)&Ws[tx + 16][kk]);
            float2 w2 = *((const float2*)&Ws[tx + 32][kk]);
            float2 w3 = *((const float2*)&Ws[tx + 48][kk]);
            acc[0][0] += a0.x * w0.x + a0.y * w0.y;
            acc[0][1] += a0.x * w1.x + a0.y * w1.y;
            acc[0][2] += a0.x * w2.x + a0.y * w2.y;
            acc[0][3] += a0.x * w3.x + a0.y * w3.y;
            acc[1][0] += a1.x * w0.x + a1.y * w0.y;
            acc[1][1] += a1.x * w1.x + a1.y * w1.y;
            acc[1][2] += a1.x * w2.x + a1.y * w2.y;
            acc[1][3] += a1.x * w3.x + a1.y * w3.y;
            acc[2][0] += a2.x * w0.x + a2.y * w0.y;
            acc[2][1] += a2.x * w1.x + a2.y * w1.y;
            acc[2][2] += a2.x * w2.x + a2.y * w2.y;
            acc[2][3] += a2.x * w3.x + a2.y * w3.y;
            acc[3][0] += a3.x * w0.x + a3.y * w0.y;
            acc[3][1] += a3.x * w1.x + a3.y * w1.y;
            acc[3][2] += a3.x * w2.x + a3.y * w2.y;
            acc[3][3] += a3.x * w3.x + a3.y * w3.y;
        }
        __syncthreads();
    }
    #pragma unroll
    for (int i = 0; i < 4; i++) {
        int m = m0 + ty + 16 * i;
        if (m >= NN) continue;
        #pragma unroll
        for (int j = 0; j < 4; j++) {
            int n = n0 + tx + 16 * j;
            if (n >= NN) continue;
            float v = 10.0f * tanhf(acc[i][j] * 0.088388347648318447f);
            C[((size_t)(b * NN + m)) * NN + n] = v;
        }
    }
}

// ---------------- row softmax: out = softmax(logits + mask) ----------------
__global__ __launch_bounds__(64) void smax_k(
    const float* __restrict__ L, const float* __restrict__ mask,
    float* __restrict__ out)
{
    int bm = blockIdx.x;
    int t = threadIdx.x;
    const float* Lr = L + (size_t)bm * NN;
    const float* Mr = mask + (size_t)bm * NN;
    float v[9];
    float mx = -1e30f;
    #pragma unroll
    for (int i = 0; i < 9; i++) {
        int idx = t + i * 64;
        if (idx < NN) { v[i] = Lr[idx] + Mr[idx]; mx = fmaxf(mx, v[i]); }
        else v[i] = -1e30f;
    }
    #pragma unroll
    for (int o = 32; o > 0; o >>= 1) mx = fmaxf(mx, __shfl_xor(mx, o));
    float s = 0.0f;
    #pragma unroll
    for (int i = 0; i < 9; i++) {
        int idx = t + i * 64;
        float e = (idx < NN) ? expf(v[i] - mx) : 0.0f;
        v[i] = e; s += e;
    }
    #pragma unroll
    for (int o = 32; o > 0; o >>= 1) s += __shfl_xor(s, o);
    float inv = 1.0f / s;
    #pragma unroll
    for (int i = 0; i < 9; i++) {
        int idx = t + i * 64;
        if (idx < NN) out[(size_t)bm * NN + idx] = v[i] * inv;
    }
}

// ---------------- persistent-KV MFMA flash attention v3.3 (bf16x3, fp32-equivalent) ----------------
// Grid (b=32, h=8, z=4), 256 threads (4 waves). id%8 = b%8: all 32 blocks of a
// batch share one XCD -> mask + K/V L2-resident. QK^T: two mfma_16x16x32 with
// [Kh|Kl] x {[Qh|Ql],[Ql|Qh]} = exact 4-term product. All hi/lo splits use the
// 1-op TRUNCATING f2b_t (residual captured by lo; r8 post-mortem: RTNE here cost
// ~7us/dispatch of pure VALU). Dbuf LDS, 1 barrier/iter.
#define ATK 64
#define NFRG 3
__global__ __launch_bounds__(256) void fmha_pers_k(
    const float* __restrict__ Qp, const float* __restrict__ Kp,
    const float* __restrict__ Vp, const float* __restrict__ mask,
    float* __restrict__ O, int Nq, int Nk)
{
    __shared__ __align__(16) unsigned short Khl[2][ATK][40];  // [kc][0:16 hi-dk | 16:32 lo-dk]
    __shared__ __align__(16) unsigned short Vhi[2][16][72];
    __shared__ __align__(16) unsigned short Vlo[2][16][72];

    int b = blockIdx.x, h = blockIdx.y, z = blockIdx.z;
    int bh = b * HH + h;
    int t = threadIdx.x;
    int w = t >> 6, lane = t & 63;
    int r16 = lane & 15, g = lane >> 4;

    // ---- per-wave q fragments: fi = f*16 + z*4 + w covers rows [fi*16, fi*16+16) ----
    short8 qf[NFRG], qs[NFRG];      // [Qh|Ql] and swapped [Ql|Qh] 32-k operands
    floatx4 o_acc[NFRG];
    float m_i[NFRG], l_i[NFRG];
    const float* mrowf[NFRG];
    const float* QpB = Qp + (size_t)bh * Nq * 16;
    #pragma unroll
    for (int f = 0; f < NFRG; f++) {
        int fi = f * 16 + z * 4 + w;
        int qg = fi * 16 + r16;
        int qc = qg < Nq ? qg : Nq - 1;
        const float* qp = QpB + (size_t)qc * 16 + 8 * (g & 1);
        float4 qv0 = *((const float4*)qp);
        float4 qv1 = *((const float4*)(qp + 4));
        float qa[8] = {qv0.x, qv0.y, qv0.z, qv0.w, qv1.x, qv1.y, qv1.z, qv1.w};
        #pragma unroll
        for (int j = 0; j < 8; j++) {
            unsigned short hh = f2b_t(qa[j]);
            unsigned short ll = f2b_t(qa[j] - b2f_(hh));
            qf[f][j] = (short)(g < 2 ? hh : ll);
            qs[f][j] = (short)(g < 2 ? ll : hh);
        }
        o_acc[f] = (floatx4){0.0f, 0.0f, 0.0f, 0.0f};
        m_i[f] = -1e30f; l_i[f] = 0.0f;
        mrowf[f] = mask ? (mask + ((size_t)(b * Nq + qc)) * Nk) : nullptr;
    }

    // ---- staging: 256 threads, float4/thread per array ----
    int srow = t >> 2, sc = (t & 3) * 4;
    const float* KpB = Kp + ((size_t)bh * Nk) * 16 + sc;
    const float* VpB = Vp + ((size_t)bh * Nk) * 16 + sc;

    {
        int krc = srow < Nk ? srow : Nk - 1;
        float4 kv = *((const float4*)(KpB + (size_t)krc * 16));
        float4 vv = *((const float4*)(VpB + (size_t)krc * 16));
        float ka[4] = {kv.x, kv.y, kv.z, kv.w};
        float va[4] = {vv.x, vv.y, vv.z, vv.w};
        bshort4 khv, klv;
        #pragma unroll
        for (int j = 0; j < 4; j++) {
            unsigned short hh = f2b_t(ka[j]);
            khv[j] = (short)hh;
            klv[j] = (short)f2b_t(ka[j] - b2f_(hh));
        }
        *((bshort4*)&Khl[0][srow][sc])      = khv;
        *((bshort4*)&Khl[0][srow][16 + sc]) = klv;
        #pragma unroll
        for (int j = 0; j < 4; j++) {
            unsigned short hh = f2b_t(va[j]);
            Vhi[0][sc + j][srow] = hh;
            Vlo[0][sc + j][srow] = f2b_t(va[j] - b2f_(hh));
        }
    }
    __syncthreads();

    int nkt = (Nk + ATK - 1) / ATK;
    for (int kt = 0; kt < nkt; kt++) {
        int cur = kt & 1;
        int k0 = kt * ATK;

        // ---- prefetch next K/V tile to regs (HBM/L2 latency hides under compute) ----
        float4 nkv, nvv;
        bool pf = (kt + 1 < nkt);
        if (pf) {
            int kr = k0 + ATK + srow;
            int krc = kr < Nk ? kr : Nk - 1;
            nkv = *((const float4*)(KpB + (size_t)krc * 16));
            nvv = *((const float4*)(VpB + (size_t)krc * 16));
        }

        // ---- hoisted mask loads for this tile (issue under the QK MFMAs) ----
        float mvv[NFRG][4][4];
        if (mask) {
            #pragma unroll
            for (int f = 0; f < NFRG; f++) {
                #pragma unroll
                for (int s = 0; s < 4; s++) {
                    int c0 = k0 + s * 16 + 4 * g;
                    if (c0 + 3 < Nk) {
                        float4 m4 = *((const float4*)(mrowf[f] + c0));
                        mvv[f][s][0] = m4.x; mvv[f][s][1] = m4.y;
                        mvv[f][s][2] = m4.z; mvv[f][s][3] = m4.w;
                    } else {
                        #pragma unroll
                        for (int r = 0; r < 4; r++)
                            mvv[f][s][r] = (c0 + r < Nk) ? mrowf[f][c0 + r] : 0.0f;
                    }
                }
            }
        }

        // ---- K/V fragments for this tile (shared by all frags of the wave) ----
        short8 kfr[4];
        bshort4 vhf[4], vlf[4];
        #pragma unroll
        for (int s = 0; s < 4; s++) {
            kfr[s] = *((const short8*)&Khl[cur][s * 16 + r16][8 * g]);
            vhf[s] = *((const bshort4*)&Vhi[cur][r16][s * 16 + 4 * g]);
            vlf[s] = *((const bshort4*)&Vlo[cur][r16][s * 16 + 4 * g]);
        }

        #pragma unroll
        for (int f = 0; f < NFRG; f++) {
            int fi = f * 16 + z * 4 + w;
            if (fi * 16 >= Nq) continue;   // wave-uniform

            // ---- S^T: 4 sub-tiles x 2 passes of 16x16x32 (exact 4-term product) ----
            float p[4][4];
            #pragma unroll
            for (int s = 0; s < 4; s++) {
                floatx4 a = (floatx4){0.0f, 0.0f, 0.0f, 0.0f};
                a = __builtin_amdgcn_mfma_f32_16x16x32_bf16(kfr[s], qf[f], a, 0, 0, 0);
                a = __builtin_amdgcn_mfma_f32_16x16x32_bf16(kfr[s], qs[f], a, 0, 0, 0);
                #pragma unroll
                for (int r = 0; r < 4; r++) p[s][r] = a[r];
            }

            // ---- scale + mask + bounds ----
            #pragma unroll
            for (int s = 0; s < 4; s++) {
                int c0 = k0 + s * 16 + 4 * g;
                #pragma unroll
                for (int r = 0; r < 4; r++) {
                    float mv = mask ? mvv[f][s][r] : 0.0f;
                    p[s][r] = (c0 + r < Nk) ? (p[s][r] * 0.25f + mv) : -1e30f;
                }
            }

            // ---- online softmax (per q = lane&15) ----
            float tmax = -1e30f;
            #pragma unroll
            for (int s = 0; s < 4; s++)
                #pragma unroll
                for (int r = 0; r < 4; r++) tmax = fmaxf(tmax, p[s][r]);
            tmax = fmaxf(tmax, __shfl_xor(tmax, 16));
            tmax = fmaxf(tmax, __shfl_xor(tmax, 32));
            float m_new = fmaxf(m_i[f], tmax);
            float alpha = __expf(m_i[f] - m_new);
            float lloc = 0.0f;
            #pragma unroll
            for (int s = 0; s < 4; s++) {
                #pragma unroll
                for (int r = 0; r < 4; r++) {
                    float e = __expf(p[s][r] - m_new);
                    p[s][r] = e; lloc += e;
                }
            }
            lloc += __shfl_xor(lloc, 16);
            lloc += __shfl_xor(lloc, 32);
            l_i[f] = l_i[f] * alpha + lloc;
            m_i[f] = m_new;
            #pragma unroll
            for (int r = 0; r < 4; r++) {
                float ar = __shfl(alpha, 4 * g + r);
                o_acc[f][r] *= ar;
            }

            // ---- PV: p is already the x16 A-frag (kc = 4g+r); trunc split ----
            #pragma unroll
            for (int s = 0; s < 4; s++) {
                bshort4 ph, pl;
                #pragma unroll
                for (int r = 0; r < 4; r++) {
                    unsigned short hh = f2b_t(p[s][r]);
                    ph[r] = (short)hh;
                    pl[r] = (short)f2b_t(p[s][r] - b2f_(hh));
                }
                o_acc[f] = __builtin_amdgcn_mfma_f32_16x16x16bf16_1k(ph, vhf[s], o_acc[f], 0, 0, 0);
                o_acc[f] = __builtin_amdgcn_mfma_f32_16x16x16bf16_1k(ph, vlf[s], o_acc[f], 0, 0, 0);
                o_acc[f] = __builtin_amdgcn_mfma_f32_16x16x16bf16_1k(pl, vhf[s], o_acc[f], 0, 0, 0);
            }
        }

        // ---- write next tile into the other buffer; one barrier per iteration ----
        if (pf) {
            int nb2 = cur ^ 1;
            float ka[4] = {nkv.x, nkv.y, nkv.z, nkv.w};
            float va[4] = {nvv.x, nvv.y, nvv.z, nvv.w};
            bshort4 khv, klv;
            #pragma unroll
            for (int j = 0; j < 4; j++) {
                unsigned short hh = f2b_t(ka[j]);
                khv[j] = (short)hh;
                klv[j] = (short)f2b_t(ka[j] - b2f_(hh));
            }
            *((bshort4*)&Khl[nb2][srow][sc])      = khv;
            *((bshort4*)&Khl[nb2][srow][16 + sc]) = klv;
            #pragma unroll
            for (int j = 0; j < 4; j++) {
                unsigned short hh = f2b_t(va[j]);
                Vhi[nb2][sc + j][srow] = hh;
                Vlo[nb2][sc + j][srow] = f2b_t(va[j] - b2f_(hh));
            }
        }
        __syncthreads();
    }

    // ---- epilogue: O reg r is (q-row 4g+r, d = r16); l lives at lane q ----
    #pragma unroll
    for (int f = 0; f < NFRG; f++) {
        int fi = f * 16 + z * 4 + w;
        if (fi * 16 >= Nq) continue;
        #pragma unroll
        for (int r = 0; r < 4; r++) {
            float lr = __shfl(l_i[f], 4 * g + r);
            int qrow = fi * 16 + 4 * g + r;
            if (qrow < Nq)
                O[((size_t)(b * Nq + qrow)) * EE + h * 16 + r16] = o_acc[f][r] / lr;
        }
    }
}

// ---------------- InstanceNorm over node axis (coalesced; r8: -276us vs e-fixed) ----------------
__global__ __launch_bounds__(256) void inorm_k(
    const float* __restrict__ X, const float* __restrict__ Y,
    const float* __restrict__ g, const float* __restrict__ bb,
    float* __restrict__ Out)
{
    int b = blockIdx.x, eg = blockIdx.y;
    int t = threadIdx.x;
    int tx = t & 15, tn = t >> 4;
    int e = eg * 16 + tx;
    const float* Xb = X + ((size_t)b * NN) * EE + e;
    const float* Yb = Y + ((size_t)b * NN) * EE + e;
    float s = 0.0f, s2 = 0.0f;
    for (int n = tn; n < NN; n += 16) {
        float v = Xb[(size_t)n * EE] + Yb[(size_t)n * EE];
        s += v; s2 += v * v;
    }
    __shared__ float rs[16][17], rs2[16][17];
    rs[tn][tx] = s; rs2[tn][tx] = s2;
    __syncthreads();
    float st = 0.0f, st2 = 0.0f;
    #pragma unroll
    for (int j = 0; j < 16; j++) { st += rs[j][tx]; st2 += rs2[j][tx]; }
    float mu = st * (1.0f / NN);
    float var = st2 * (1.0f / NN) - mu * mu;
    float inv = rsqrtf(var + 1e-5f);
    float gg = g[e], bv = bb[e];
    float* Ob = Out + ((size_t)b * NN) * EE + e;
    for (int n = tn; n < NN; n += 16) {
        float v = Xb[(size_t)n * EE] + Yb[(size_t)n * EE];
        Ob[(size_t)n * EE] = (v - mu) * inv * gg + bv;
    }
}

__global__ void zero_k(float* p, int n) {
    int i = blockIdx.x * 256 + threadIdx.x;
    if (i < n) p[i] = 0.0f;
}

__global__ __launch_bounds__(128) void encsum_k(const float* __restrict__ enc, float* __restrict__ esum) {
    int b = blockIdx.x, ch = blockIdx.y, t = threadIdx.x;
    float a = 0.0f;
    for (int i = 0; i < 65; i++) {
        int n = ch * 65 + i;
        a += enc[((size_t)(b * NN + n)) * EE + t];
    }
    atomicAdd(&esum[b * EE + t], a);
}

// mt[b,e] = sum_f (esum[b,f]/N) * Wr[e, 128+f]
__global__ __launch_bounds__(128) void meanterm_k(
    const float* __restrict__ esum, const float* __restrict__ Wr, float* __restrict__ mt)
{
    int b = blockIdx.x, t = threadIdx.x;
    __shared__ float em[128];
    em[t] = esum[b * EE + t] * (1.0f / NN);
    __syncthreads();
    const float* w = Wr + (size_t)t * 257 + 128;
    float a = 0.0f;
    for (int f = 0; f < 128; f++) a += em[f] * w[f];
    mt[b * EE + t] = a;
}

__global__ __launch_bounds__(128) void subtour_k(
    const float* __restrict__ enc, const int* __restrict__ subn,
    const int* __restrict__ subl, float* __restrict__ subm)
{
    int bm = blockIdx.x;
    int b = bm / MM;
    int t = threadIdx.x;
    int len = subl[bm];
    float acc = 0.0f; int cnt = 0;
    for (int l = 0; l < LL; l++) {
        int node = subn[(size_t)bm * LL + l];
        if (l < len && node >= DEPOT_) {
            acc += enc[((size_t)(b * NN + node)) * EE + t];
            cnt++;
        }
    }
    float cf = (float)(cnt < 1 ? 1 : cnt);
    subm[(size_t)bm * EE + t] = acc / cf;
}

// ---------------- decoder q: gather/blend, writes head-packed final_q ----------------
__global__ __launch_bounds__(128) void decq_gather_k(
    const float* __restrict__ R, const float* __restrict__ L1, const float* __restrict__ SM2,
    const float* __restrict__ mterm, const int* __restrict__ cur,
    const float* __restrict__ loadv, const int* __restrict__ sel,
    const float* __restrict__ Wqr, float* __restrict__ out)
{
    int bm = blockIdx.x;
    int b = bm / MM;
    int m = bm - b * MM;
    int t = threadIdx.x;
    int cn = cur[bm];
    int s2v = sel[(size_t)bm * 4 + 2];
    bool flag = (s2v >= DEPOT_) && (cn < DEPOT_);
    size_t eo = ((size_t)(b * NN + cn)) * EE + t;
    float q;
    if (flag) q = L1[eo] + SM2[(size_t)bm * EE + t];
    else      q = R[eo] + mterm[b * EE + t] + loadv[bm] * Wqr[(size_t)t * 257 + 256];
    out[((size_t)(b * HH + (t >> 4)) * MM + m) * 16 + (t & 15)] = q;
}

extern "C" void kernel_launch(void* const* d_in, const int* in_sizes, int n_in,
                              void* d_out, int out_size, void* d_ws, size_t ws_size,
                              hipStream_t stream)
{
    const float* depot = (const float*)d_in[0];
    const float* cust  = (const float*)d_in[1];
    const float* mask  = (const float*)d_in[2];
    const float* loadv = (const float*)d_in[3];
    const int*  cur   = (const int*)d_in[4];
    const int*  subn  = (const int*)d_in[5];
    const int*  subl  = (const int*)d_in[6];
    const int*  sel   = (const int*)d_in[7];
    const float* Wdep  = (const float*)d_in[8];
    const float* bdep  = (const float*)d_in[9];
    const float* Wcus  = (const float*)d_in[10];
    const float* bcus  = (const float*)d_in[11];
    const float* Wq    = (const float*)d_in[12];
    const float* Wk    = (const float*)d_in[13];
    const float* Wv    = (const float*)d_in[14];
    const float* Wc    = (const float*)d_in[15];
    const float* Wcb   = (const float*)d_in[16];
    const float* n1g   = (const float*)d_in[17];
    const float* n1b   = (const float*)d_in[18];
    const float* fW1   = (const float*)d_in[19];
    const float* fb1   = (const float*)d_in[20];
    const float* fW2   = (const float*)d_in[21];
    const float* fb2   = (const float*)d_in[22];
    const float* n2g   = (const float*)d_in[23];
    const float* n2b   = (const float*)d_in[24];
    const float* Wql   = (const float*)d_in[25];
    const float* Wqr   = (const float*)d_in[26];
    const float* dWk   = (const float*)d_in[27];
    const float* dWv   = (const float*)d_in[28];
    const float* dWc   = (const float*)d_in[29];
    const float* dWcb  = (const float*)d_in[30];

    const size_t SZ = (size_t)BB * NN * EE;           // 2,129,920
    float* f0 = (float*)d_ws;       // x / encoded
    float* f1 = f0 + SZ;            // q / k_d (packed) / logits (spans f1..f5)
    float* f2 = f1 + SZ;            // k / v_d (packed)
    float* f3 = f2 + SZ;            // v (packed) / encsum + meanterm
    float* f4 = f3 + SZ;            // mh,ff2 out / sub_mean, dec attn
    float* f5 = f4 + SZ;            // x1 / final_q (packed)
    float* big = f5 + SZ;           // ffh (B*N*FFH) / R,L1,SM2 / dec score
    unsigned short* WHp = (unsigned short*)(big + (size_t)BB * NN * FFH_);
    unsigned short* WLp = WHp + WTOT;

    dim3 g4(EE / 64, (BB * NN) / 128);     // (2, 130)
    dim3 g16(FFH_ / 64, (BB * NN) / 128);  // (8, 130)
    dim3 gq3(6, (BB * NN) / 128);          // fused QKV
    dim3 gq2(4, (BB * NN) / 128);          // fused 2-way
    dim3 gmha(BB, HH, 4);                  // (32, 8, 4): id%8==b%8 -> per-batch L2 on one XCD
    dim3 gin(BB, 8);                       // coalesced inorm: (b, e-group)
    dim3 gsc((NN + GT - 1) / GT, (NN + GT - 1) / GT, BB);  // (9, 9, 32)

    wconv_k<<<(WTOT + 255) / 256, 256, 0, stream>>>(Wq, Wk, Wv, Wc, fW1, fW2,
                                                    dWk, dWv, dWc, Wql, Wqr, WHp, WLp);
    embed_k<<<(BB * NN * EE) / 256, 256, 0, stream>>>(depot, cust, Wdep, bdep, Wcus, bcus, f0);

    for (int i = 0; i < NL_; i++) {
        const unsigned short* lH = WHp + (size_t)i * WLS;
        const unsigned short* lL = WLp + (size_t)i * WLS;
        gemm_qkv3_k<<<gq3, 256, 0, stream>>>(f0, EE, lH, lL, EE, f1, f2, f3, EE, EE, 1);
        fmha_pers_k<<<gmha, 256, 0, stream>>>(f1, f2, f3, nullptr, f4, NN, NN);
        gemm_pc_k<<<g4, 256, 0, stream>>>(f4, EE, lH + 49152, lL + 49152, EE, Wcb + i * EE, f1, EE, EE, 0);
        inorm_k<<<gin, 256, 0, stream>>>(f0, f1, n1g + i * EE, n1b + i * EE, f5);
        gemm_pc_k<<<g16, 256, 0, stream>>>(f5, EE, lH + 65536, lL + 65536, EE, fb1 + i * FFH_, big, FFH_, EE, 1);
        gemm_pc_k<<<g4, 256, 0, stream>>>(big, FFH_, lH + 131072, lL + 131072, FFH_, fb2 + i * EE, f1, EE, FFH_, 0);
        inorm_k<<<gin, 256, 0, stream>>>(f5, f1, n2g + i * EE, n2b + i * EE, f0);
    }

    // ---- decoder ----
    const unsigned short* dH = WHp + WDEC;
    const unsigned short* dL = WLp + WDEC;
    gemm_qkv3_k<<<gq2, 256, 0, stream>>>(f0, EE, dH, dL, EE, f1, f2, f2, EE, EE, 1);  // k_d, v_d packed

    zero_k<<<(BB * EE + 255) / 256, 256, 0, stream>>>(f3, BB * EE);
    encsum_k<<<dim3(BB, 8), 128, 0, stream>>>(f0, f3);
    meanterm_k<<<BB, 128, 0, stream>>>(f3, Wqr, f3 + BB * EE);
    subtour_k<<<BB * MM, 128, 0, stream>>>(f0, subn, subl, f4);

    // R (big), L1 (big+SZ) from encoded; SM2 (big+2SZ) from subm  (standard layout)
    gemm_qkv3_k<<<gq2, 256, 0, stream>>>(f0, EE, dH + 49152, dL + 49152, EE, big, big + SZ, big + SZ, EE, EE, 0);
    gemm_pc_k<<<g4, 256, 0, stream>>>(f4, EE, dH + 49152 + 32768, dL + 49152 + 32768, EE, nullptr, big + 2 * SZ, EE, EE, 0);
    decq_gather_k<<<BB * MM, 128, 0, stream>>>(big, big + SZ, big + 2 * SZ, f3 + BB * EE, cur, loadv, sel, Wqr, f5);

    fmha_pers_k<<<gmha, 256, 0, stream>>>(f5, f1, f2, mask, f4, MM, NN);
    gemm_pc_k<<<g4, 256, 0, stream>>>(f4, EE, dH + 32768, dL + 32768, EE, dWcb, big, EE, EE, 0);

    // logits (B x 520 x 520) at f1 (spans f1..f5; all dead now)
    sgemm_k<<<gsc, 256, 0, stream>>>(big, f0, f1);
    smax_k<<<BB * MM, 64, 0, stream>>>(f1, mask, (float*)d_out);
}

// Round 10
// 1474.495 us; speedup vs baseline: 1.2679x; 1.0070x over previous
//
#include <hip/hip_runtime.h>
#include <hip/hip_bf16.h>

#define BB 32
#define NN 520
#define MM 520
#define EE 128
#define HH 8
#define DKK 16
#define FFH_ 512
#define NL_ 6
#define DEPOT_ 20
#define LL 40

typedef short short8 __attribute__((ext_vector_type(8)));
typedef short bshort4 __attribute__((ext_vector_type(4)));
typedef float floatx4 __attribute__((ext_vector_type(4)));

// Manual RTNE float->bf16 (4 VALU ops) -- used where a value is converted once.
__device__ __forceinline__ unsigned short f2b(float x) {
    unsigned int u = __float_as_uint(x);
    return (unsigned short)((u + 0x7fffu + ((u >> 16) & 1u)) >> 16);
}
// Truncating float->bf16 (1 VALU op) -- ONLY for hi/lo SPLIT PAIRS (lo captures
// the hi residual exactly; r8/r9: saved ~8us/dispatch in fmha vs RTNE).
__device__ __forceinline__ unsigned short f2b_t(float x) {
    return (unsigned short)(__float_as_uint(x) >> 16);
}
__device__ __forceinline__ float b2f_(unsigned short h) {
    return __uint_as_float(((unsigned int)h) << 16);
}

// ---------------- embedding: depot/customer linear ----------------
__global__ __launch_bounds__(256) void embed_k(
    const float* __restrict__ dep, const float* __restrict__ cus,
    const float* __restrict__ Wd, const float* __restrict__ bd,
    const float* __restrict__ Wc3, const float* __restrict__ bc,
    float* __restrict__ x)
{
    int idx = blockIdx.x * 256 + threadIdx.x;   // < B*N*E = 2129920
    int e = idx & 127;
    int bn = idx >> 7;
    int n = bn % NN;
    int b = bn / NN;
    float a;
    if (n < DEPOT_) {
        a = bd[e];
        const float* f = dep + ((size_t)(b * DEPOT_ + n)) * 4;
        #pragma unroll
        for (int j = 0; j < 4; j++) a += f[j] * Wd[e * 4 + j];
    } else {
        a = bc[e];
        const float* f = cus + ((size_t)(b * 500 + (n - DEPOT_))) * 3;
        #pragma unroll
        for (int j = 0; j < 3; j++) a += f[j] * Wc3[e * 3 + j];
    }
    x[idx] = a;
}

// ---------------- weight pre-conversion: fp32 -> hi/lo bf16 planes ----------------
#define WLS 196608
#define WDEC 1179648
#define WTOT 1277952
__global__ __launch_bounds__(256) void wconv_k(
    const float* __restrict__ Wq, const float* __restrict__ Wk, const float* __restrict__ Wv,
    const float* __restrict__ Wc, const float* __restrict__ fW1, const float* __restrict__ fW2,
    const float* __restrict__ dWk, const float* __restrict__ dWv, const float* __restrict__ dWc,
    const float* __restrict__ Wql, const float* __restrict__ Wqr,
    unsigned short* __restrict__ WH, unsigned short* __restrict__ WL)
{
    int idx = blockIdx.x * 256 + threadIdx.x;
    if (idx >= WTOT) return;
    const float* src;
    if (idx < WDEC) {
        int i = idx / WLS, r = idx % WLS;
        if (r < 49152) {
            int row = r >> 7, col = r & 127;
            const float* w = row < 128 ? Wq : (row < 256 ? Wk : Wv);
            src = w + (size_t)i * 16384 + (size_t)(row & 127) * 128 + col;
        } else if (r < 65536) {
            src = Wc + (size_t)i * 16384 + (r - 49152);
        } else if (r < 131072) {
            src = fW1 + (size_t)i * 65536 + (r - 65536);
        } else {
            src = fW2 + (size_t)i * 65536 + (r - 131072);
        }
    } else {
        int r = idx - WDEC;
        if (r < 32768) {
            int row = r >> 7, col = r & 127;
            src = (row < 128 ? dWk : dWv) + (size_t)(row & 127) * 128 + col;
        } else if (r < 49152) {
            src = dWc + (r - 32768);
        } else {
            int rr = r - 49152;
            int row = rr >> 7, col = rr & 127;
            if (row < 128)      src = Wqr + (size_t)row * 257 + col;
            else if (row < 256) src = Wql + (size_t)(row - 128) * 256 + col;
            else                src = Wql + (size_t)(row - 256) * 256 + 128 + col;
        }
    }
    float v = *src;
    unsigned short h = f2b(v);
    WH[idx] = h;
    WL[idx] = f2b(v - b2f_(h));
}

// ---------------- bf16x3 MFMA GEMM, BM=64, double-buffered LDS ----------------
// r9 post-mortem: at BM=128 the g4 grids were 260 blocks = 1 block/CU = 1
// wave/SIMD -- any vmcnt stall idles the CU (barrier-synced waves). BM=64
// doubles the grid (2+ blocks/CU): independent barrier groups cover each
// other's stalls. Same bf16x3 math; acc 2x4 -> 1x4.
#define AP 40
__global__ __launch_bounds__(256) void gemm_pc_k(
    const float* __restrict__ A, int lda,
    const unsigned short* __restrict__ WH, const unsigned short* __restrict__ WL, int ldw,
    const float* __restrict__ bias,
    float* __restrict__ C, int ldc,
    int K, int relu)
{
    __shared__ __align__(16) unsigned short Ah[2][64][AP];
    __shared__ __align__(16) unsigned short Al[2][64][AP];
    __shared__ __align__(16) unsigned short Bh[2][64][AP];
    __shared__ __align__(16) unsigned short Bl[2][64][AP];

    int t = threadIdx.x;
    int w = t >> 6, lane = t & 63;
    int frow = lane & 15, fq = lane >> 4;
    int n0 = blockIdx.x * 64, m0 = blockIdx.y * 64;

    int arow = t & 63, acol = (t >> 6) * 8;   // A: 64 rows x 32 cols, 8 floats/thread

    const float* Abase = A + (size_t)(m0 + arow) * lda + acol;
    const unsigned short* WHb = WH + (size_t)(n0 + arow) * ldw + acol;
    const unsigned short* WLb = WL + (size_t)(n0 + arow) * ldw + acol;

    floatx4 acc[4];
    #pragma unroll
    for (int j = 0; j < 4; j++) acc[j] = (floatx4){0.0f, 0.0f, 0.0f, 0.0f};

    // ---- prologue: stage chunk 0 into buffer 0 ----
    {
        float4 v0 = ((const float4*)Abase)[0];
        float4 v1 = ((const float4*)Abase)[1];
        float vr[8] = {v0.x, v0.y, v0.z, v0.w, v1.x, v1.y, v1.z, v1.w};
        short8 hv, lv;
        #pragma unroll
        for (int j = 0; j < 8; j++) {
            unsigned short h = f2b(vr[j]);
            hv[j] = (short)h;
            lv[j] = (short)f2b(vr[j] - b2f_(h));
        }
        *((short8*)&Ah[0][arow][acol]) = hv;
        *((short8*)&Al[0][arow][acol]) = lv;
        *((short8*)&Bh[0][arow][acol]) = *((const short8*)WHb);
        *((short8*)&Bl[0][arow][acol]) = *((const short8*)WLb);
    }
    __syncthreads();

    int nkt = K >> 5;
    for (int kt = 0; kt < nkt; kt++) {
        int cur = kt & 1;
        bool pf = (kt + 1 < nkt);

        // ---- issue next chunk's global loads (hide under MFMA) ----
        float4 av0, av1;
        short8 nbh, nbl;
        if (pf) {
            const float* Ap = Abase + (kt + 1) * 32;
            av0 = ((const float4*)Ap)[0];
            av1 = ((const float4*)Ap)[1];
            nbh = *((const short8*)(WHb + (kt + 1) * 32));
            nbl = *((const short8*)(WLb + (kt + 1) * 32));
        }

        short8 ah = *((const short8*)&Ah[cur][w * 16 + frow][fq * 8]);
        short8 al = *((const short8*)&Al[cur][w * 16 + frow][fq * 8]);
        #pragma unroll
        for (int nt = 0; nt < 4; nt++) {
            short8 bh = *((const short8*)&Bh[cur][nt * 16 + frow][fq * 8]);
            short8 bl = *((const short8*)&Bl[cur][nt * 16 + frow][fq * 8]);
            acc[nt] = __builtin_amdgcn_mfma_f32_16x16x32_bf16(ah, bh, acc[nt], 0, 0, 0);
            acc[nt] = __builtin_amdgcn_mfma_f32_16x16x32_bf16(ah, bl, acc[nt], 0, 0, 0);
            acc[nt] = __builtin_amdgcn_mfma_f32_16x16x32_bf16(al, bh, acc[nt], 0, 0, 0);
        }

        // ---- convert + write next chunk into the OTHER buffer ----
        if (pf) {
            int nb2 = cur ^ 1;
            float vr[8] = {av0.x, av0.y, av0.z, av0.w, av1.x, av1.y, av1.z, av1.w};
            short8 hv, lv;
            #pragma unroll
            for (int j = 0; j < 8; j++) {
                unsigned short h = f2b(vr[j]);
                hv[j] = (short)h;
                lv[j] = (short)f2b(vr[j] - b2f_(h));
            }
            *((short8*)&Ah[nb2][arow][acol]) = hv;
            *((short8*)&Al[nb2][arow][acol]) = lv;
            *((short8*)&Bh[nb2][arow][acol]) = nbh;
            *((short8*)&Bl[nb2][arow][acol]) = nbl;
        }
        __syncthreads();
    }

    #pragma unroll
    for (int nt = 0; nt < 4; nt++) {
        int col = n0 + nt * 16 + frow;
        float bv = bias ? bias[col] : 0.0f;
        int rbase = m0 + w * 16 + fq * 4;
        #pragma unroll
        for (int r = 0; r < 4; r++) {
            float v = acc[nt][r] + bv;
            if (relu) v = fmaxf(v, 0.0f);
            C[(size_t)(rbase + r) * ldc + col] = v;
        }
    }
}

// ---------------- fused 3-way GEMM (QKV / dec-KV / R+L1), BM=64, dbuf ----------------
// pack=1: outputs written head-major [B*H][N][16] (for fmha); pack=0: standard [B*N][E].
__global__ __launch_bounds__(256) void gemm_qkv3_k(
    const float* __restrict__ A, int lda,
    const unsigned short* __restrict__ WH, const unsigned short* __restrict__ WL, int ldw,
    float* __restrict__ C0, float* __restrict__ C1, float* __restrict__ C2,
    int ldc, int K, int pack)
{
    __shared__ __align__(16) unsigned short Ah[2][64][AP];
    __shared__ __align__(16) unsigned short Al[2][64][AP];
    __shared__ __align__(16) unsigned short Bh[2][64][AP];
    __shared__ __align__(16) unsigned short Bl[2][64][AP];

    int t = threadIdx.x;
    int w = t >> 6, lane = t & 63;
    int frow = lane & 15, fq = lane >> 4;
    int nb = blockIdx.x;
    int which = nb >> 1;
    float* C = which == 0 ? C0 : (which == 1 ? C1 : C2);
    int n0w = nb * 64;            // row in stacked weight plane
    int n0c = (nb & 1) * 64;      // col in the selected C
    int m0 = blockIdx.y * 64;

    int arow = t & 63, acol = (t >> 6) * 8;

    const float* Abase = A + (size_t)(m0 + arow) * lda + acol;
    const unsigned short* WHb = WH + (size_t)(n0w + arow) * ldw + acol;
    const unsigned short* WLb = WL + (size_t)(n0w + arow) * ldw + acol;

    floatx4 acc[4];
    #pragma unroll
    for (int j = 0; j < 4; j++) acc[j] = (floatx4){0.0f, 0.0f, 0.0f, 0.0f};

    {
        float4 v0 = ((const float4*)Abase)[0];
        float4 v1 = ((const float4*)Abase)[1];
        float vr[8] = {v0.x, v0.y, v0.z, v0.w, v1.x, v1.y, v1.z, v1.w};
        short8 hv, lv;
        #pragma unroll
        for (int j = 0; j < 8; j++) {
            unsigned short h = f2b(vr[j]);
            hv[j] = (short)h;
            lv[j] = (short)f2b(vr[j] - b2f_(h));
        }
        *((short8*)&Ah[0][arow][acol]) = hv;
        *((short8*)&Al[0][arow][acol]) = lv;
        *((short8*)&Bh[0][arow][acol]) = *((const short8*)WHb);
        *((short8*)&Bl[0][arow][acol]) = *((const short8*)WLb);
    }
    __syncthreads();

    int nkt = K >> 5;
    for (int kt = 0; kt < nkt; kt++) {
        int cur = kt & 1;
        bool pf = (kt + 1 < nkt);

        float4 av0, av1;
        short8 nbh, nbl;
        if (pf) {
            const float* Ap = Abase + (kt + 1) * 32;
            av0 = ((const float4*)Ap)[0];
            av1 = ((const float4*)Ap)[1];
            nbh = *((const short8*)(WHb + (kt + 1) * 32));
            nbl = *((const short8*)(WLb + (kt + 1) * 32));
        }

        short8 ah = *((const short8*)&Ah[cur][w * 16 + frow][fq * 8]);
        short8 al = *((const short8*)&Al[cur][w * 16 + frow][fq * 8]);
        #pragma unroll
        for (int nt = 0; nt < 4; nt++) {
            short8 bh = *((const short8*)&Bh[cur][nt * 16 + frow][fq * 8]);
            short8 bl = *((const short8*)&Bl[cur][nt * 16 + frow][fq * 8]);
            acc[nt] = __builtin_amdgcn_mfma_f32_16x16x32_bf16(ah, bh, acc[nt], 0, 0, 0);
            acc[nt] = __builtin_amdgcn_mfma_f32_16x16x32_bf16(ah, bl, acc[nt], 0, 0, 0);
            acc[nt] = __builtin_amdgcn_mfma_f32_16x16x32_bf16(al, bh, acc[nt], 0, 0, 0);
        }

        if (pf) {
            int nb2 = cur ^ 1;
            float vr[8] = {av0.x, av0.y, av0.z, av0.w, av1.x, av1.y, av1.z, av1.w};
            short8 hv, lv;
            #pragma unroll
            for (int j = 0; j < 8; j++) {
                unsigned short h = f2b(vr[j]);
                hv[j] = (short)h;
                lv[j] = (short)f2b(vr[j] - b2f_(h));
            }
            *((short8*)&Ah[nb2][arow][acol]) = hv;
            *((short8*)&Al[nb2][arow][acol]) = lv;
            *((short8*)&Bh[nb2][arow][acol]) = nbh;
            *((short8*)&Bl[nb2][arow][acol]) = nbl;
        }
        __syncthreads();
    }

    #pragma unroll
    for (int nt = 0; nt < 4; nt++) {
        int col = n0c + nt * 16 + frow;
        int hh = col >> 4, dd = col & 15;
        int rbase = m0 + w * 16 + fq * 4;
        #pragma unroll
        for (int r = 0; r < 4; r++) {
            int row = rbase + r;
            if (pack) {
                int b2 = row / NN, n2 = row - b2 * NN;
                C[((size_t)(b2 * HH + hh) * NN + n2) * 16 + dd] = acc[nt][r];
            } else {
                C[(size_t)row * ldc + col] = acc[nt][r];
            }
        }
    }
}

// ---------------- score GEMM (NT) with tanh epilogue (fp32) ----------------
#define GT 64
#define GK 32
#define GP 36
__global__ __launch_bounds__(256) void sgemm_k(
    const float* __restrict__ A,    // score [B*520][128]
    const float* __restrict__ Enc,  // [B*520][128]
    float* __restrict__ C)          // [B][520][520]
{
    __shared__ float As[GT][GP];
    __shared__ float Ws[GT][GP];
    int t = threadIdx.x;
    int tx = t & 15, ty = t >> 4;
    int b = blockIdx.z;
    int m0 = blockIdx.y * GT, n0 = blockIdx.x * GT;
    int lr = t >> 2, lc = (t & 3) * 8;
    int mr = m0 + lr; if (mr >= NN) mr = NN - 1;
    int nr = n0 + lr; if (nr >= NN) nr = NN - 1;
    float acc[4][4];
    #pragma unroll
    for (int i = 0; i < 4; i++)
        #pragma unroll
        for (int j = 0; j < 4; j++) acc[i][j] = 0.0f;

    for (int k0 = 0; k0 < EE; k0 += GK) {
        const float* Ap = A + ((size_t)(b * NN + mr)) * EE + k0 + lc;
        const float* Wp = Enc + ((size_t)(b * NN + nr)) * EE + k0 + lc;
        float4 av0 = *((const float4*)Ap), av1 = *((const float4*)(Ap + 4));
        float4 wv0 = *((const float4*)Wp), wv1 = *((const float4*)(Wp + 4));
        *((float4*)&As[lr][lc]) = av0; *((float4*)&As[lr][lc + 4]) = av1;
        *((float4*)&Ws[lr][lc]) = wv0; *((float4*)&Ws[lr][lc + 4]) = wv1;
        __syncthreads();
        #pragma unroll
        for (int kk = 0; kk < GK; kk += 2) {
            float2 a0 = *((const float2*)&As[ty][kk]);
            float2 a1 = *((const float2*)&As[ty + 16][kk]);
            float2 a2 = *((const float2*)&As[ty + 32][kk]);
            float2 a3 = *((const float2*)&As[ty + 48][kk]);
            float2 w0 = *((const float2*)&Ws[tx][kk]);
            float2 w1 = *((const float2*)&Ws[tx + 16][kk]);
            float2 w2 = *((const float2*)&Ws[tx + 32][kk]);
            float2 w3 = *((const float2*)&Ws[tx + 48][kk]);
            acc[0][0] += a0.x * w0.x + a0.y * w0.y;
            acc[0][1] += a0.x * w1.x + a0.y * w1.y;
            acc[0][2] += a0.x * w2.x + a0.y * w2.y;
            acc[0][3] += a0.x * w3.x + a0.y * w3.y;
            acc[1][0] += a1.x * w0.x + a1.y * w0.y;
            acc[1][1] += a1.x * w1.x + a1.y * w1.y;
            acc[1][2] += a1.x * w2.x + a1.y * w2.y;
            acc[1][3] += a1.x * w3.x + a1.y * w3.y;
            acc[2][0] += a2.x * w0.x + a2.y * w0.y;
            acc[2][1] += a2.x * w1.x + a2.y * w1.y;
            acc[2][2] += a2.x * w2.x + a2.y * w2.y;
            acc[2][3] += a2.x * w3.x + a2.y * w3.y;
            acc[3][0] += a3.x * w0.x + a3.y * w0.y;
            acc[3][1] += a3.x * w1.x + a3.y * w1.y;
            acc[3][2] += a3.x * w2.x + a3.y * w2.y;
            acc[3][3] += a3.x * w3.x + a3.y * w3.y;
        }
        __syncthreads();
    }
    #pragma unroll
    for (int i = 0; i < 4; i++) {
        int m = m0 + ty + 16 * i;
        if (m >= NN) continue;
        #pragma unroll
        for (int j = 0; j < 4; j++) {
            int n = n0 + tx + 16 * j;
            if (n >= NN) continue;
            float v = 10.0f * tanhf(acc[i][j] * 0.088388347648318447f);
            C[((size_t)(b * NN + m)) * NN + n] = v;
        }
    }
}

// ---------------- row softmax: out = softmax(logits + mask) ----------------
__global__ __launch_bounds__(64) void smax_k(
    const float* __restrict__ L, const float* __restrict__ mask,
    float* __restrict__ out)
{
    int bm = blockIdx.x;
    int t = threadIdx.x;
    const float* Lr = L + (size_t)bm * NN;
    const float* Mr = mask + (size_t)bm * NN;
    float v[9];
    float mx = -1e30f;
    #pragma unroll
    for (int i = 0; i < 9; i++) {
        int idx = t + i * 64;
        if (idx < NN) { v[i] = Lr[idx] + Mr[idx]; mx = fmaxf(mx, v[i]); }
        else v[i] = -1e30f;
    }
    #pragma unroll
    for (int o = 32; o > 0; o >>= 1) mx = fmaxf(mx, __shfl_xor(mx, o));
    float s = 0.0f;
    #pragma unroll
    for (int i = 0; i < 9; i++) {
        int idx = t + i * 64;
        float e = (idx < NN) ? expf(v[i] - mx) : 0.0f;
        v[i] = e; s += e;
    }
    #pragma unroll
    for (int o = 32; o > 0; o >>= 1) s += __shfl_xor(s, o);
    float inv = 1.0f / s;
    #pragma unroll
    for (int i = 0; i < 9; i++) {
        int idx = t + i * 64;
        if (idx < NN) out[(size_t)bm * NN + idx] = v[i] * inv;
    }
}

// ---------------- persistent-KV MFMA flash attention v3.4 (bf16x3, fp32-equivalent) ----------------
// Grid (b=32, h=8, z=4), 256 threads (4 waves). id%8 = b%8: all 32 blocks of a
// batch share one XCD -> mask + K/V L2-resident. QK^T: two mfma_16x16x32 with
// [Kh|Kl] x {[Qh|Ql],[Ql|Qh]} = exact 4-term product. Trunc hi/lo splits (r9).
// v3.4: mask loads moved INTO the per-frag loop -- 16 live VGPRs instead of the
// hoisted 48 (mvv[3][4][4]); still issued before that frag's MFMAs so the loads
// overlap. VGPR 108 -> ~84 => 6 waves/SIMD. Dbuf LDS, 1 barrier/iter.
#define ATK 64
#define NFRG 3
__global__ __launch_bounds__(256) void fmha_pers_k(
    const float* __restrict__ Qp, const float* __restrict__ Kp,
    const float* __restrict__ Vp, const float* __restrict__ mask,
    float* __restrict__ O, int Nq, int Nk)
{
    __shared__ __align__(16) unsigned short Khl[2][ATK][40];  // [kc][0:16 hi-dk | 16:32 lo-dk]
    __shared__ __align__(16) unsigned short Vhi[2][16][72];
    __shared__ __align__(16) unsigned short Vlo[2][16][72];

    int b = blockIdx.x, h = blockIdx.y, z = blockIdx.z;
    int bh = b * HH + h;
    int t = threadIdx.x;
    int w = t >> 6, lane = t & 63;
    int r16 = lane & 15, g = lane >> 4;

    // ---- per-wave q fragments: fi = f*16 + z*4 + w covers rows [fi*16, fi*16+16) ----
    short8 qf[NFRG], qs[NFRG];      // [Qh|Ql] and swapped [Ql|Qh] 32-k operands
    floatx4 o_acc[NFRG];
    float m_i[NFRG], l_i[NFRG];
    const float* mrowf[NFRG];
    const float* QpB = Qp + (size_t)bh * Nq * 16;
    #pragma unroll
    for (int f = 0; f < NFRG; f++) {
        int fi = f * 16 + z * 4 + w;
        int qg = fi * 16 + r16;
        int qc = qg < Nq ? qg : Nq - 1;
        const float* qp = QpB + (size_t)qc * 16 + 8 * (g & 1);
        float4 qv0 = *((const float4*)qp);
        float4 qv1 = *((const float4*)(qp + 4));
        float qa[8] = {qv0.x, qv0.y, qv0.z, qv0.w, qv1.x, qv1.y, qv1.z, qv1.w};
        #pragma unroll
        for (int j = 0; j < 8; j++) {
            unsigned short hh = f2b_t(qa[j]);
            unsigned short ll = f2b_t(qa[j] - b2f_(hh));
            qf[f][j] = (short)(g < 2 ? hh : ll);
            qs[f][j] = (short)(g < 2 ? ll : hh);
        }
        o_acc[f] = (floatx4){0.0f, 0.0f, 0.0f, 0.0f};
        m_i[f] = -1e30f; l_i[f] = 0.0f;
        mrowf[f] = mask ? (mask + ((size_t)(b * Nq + qc)) * Nk) : nullptr;
    }

    // ---- staging: 256 threads, float4/thread per array ----
    int srow = t >> 2, sc = (t & 3) * 4;
    const float* KpB = Kp + ((size_t)bh * Nk) * 16 + sc;
    const float* VpB = Vp + ((size_t)bh * Nk) * 16 + sc;

    {
        int krc = srow < Nk ? srow : Nk - 1;
        float4 kv = *((const float4*)(KpB + (size_t)krc * 16));
        float4 vv = *((const float4*)(VpB + (size_t)krc * 16));
        float ka[4] = {kv.x, kv.y, kv.z, kv.w};
        float va[4] = {vv.x, vv.y, vv.z, vv.w};
        bshort4 khv, klv;
        #pragma unroll
        for (int j = 0; j < 4; j++) {
            unsigned short hh = f2b_t(ka[j]);
            khv[j] = (short)hh;
            klv[j] = (short)f2b_t(ka[j] - b2f_(hh));
        }
        *((bshort4*)&Khl[0][srow][sc])      = khv;
        *((bshort4*)&Khl[0][srow][16 + sc]) = klv;
        #pragma unroll
        for (int j = 0; j < 4; j++) {
            unsigned short hh = f2b_t(va[j]);
            Vhi[0][sc + j][srow] = hh;
            Vlo[0][sc + j][srow] = f2b_t(va[j] - b2f_(hh));
        }
    }
    __syncthreads();

    int nkt = (Nk + ATK - 1) / ATK;
    for (int kt = 0; kt < nkt; kt++) {
        int cur = kt & 1;
        int k0 = kt * ATK;

        // ---- prefetch next K/V tile to regs (HBM/L2 latency hides under compute) ----
        float4 nkv, nvv;
        bool pf = (kt + 1 < nkt);
        if (pf) {
            int kr = k0 + ATK + srow;
            int krc = kr < Nk ? kr : Nk - 1;
            nkv = *((const float4*)(KpB + (size_t)krc * 16));
            nvv = *((const float4*)(VpB + (size_t)krc * 16));
        }

        // ---- K/V fragments for this tile (shared by all frags of the wave) ----
        short8 kfr[4];
        bshort4 vhf[4], vlf[4];
        #pragma unroll
        for (int s = 0; s < 4; s++) {
            kfr[s] = *((const short8*)&Khl[cur][s * 16 + r16][8 * g]);
            vhf[s] = *((const bshort4*)&Vhi[cur][r16][s * 16 + 4 * g]);
            vlf[s] = *((const bshort4*)&Vlo[cur][r16][s * 16 + 4 * g]);
        }

        #pragma unroll
        for (int f = 0; f < NFRG; f++) {
            int fi = f * 16 + z * 4 + w;
            if (fi * 16 >= Nq) continue;   // wave-uniform

            // ---- this frag's mask loads (issued before the MFMAs; independent) ----
            float mv[4][4];
            if (mask) {
                #pragma unroll
                for (int s = 0; s < 4; s++) {
                    int c0 = k0 + s * 16 + 4 * g;
                    if (c0 + 3 < Nk) {
                        float4 m4 = *((const float4*)(mrowf[f] + c0));
                        mv[s][0] = m4.x; mv[s][1] = m4.y;
                        mv[s][2] = m4.z; mv[s][3] = m4.w;
                    } else {
                        #pragma unroll
                        for (int r = 0; r < 4; r++)
                            mv[s][r] = (c0 + r < Nk) ? mrowf[f][c0 + r] : 0.0f;
                    }
                }
            }

            // ---- S^T: 4 sub-tiles x 2 passes of 16x16x32 (exact 4-term product) ----
            float p[4][4];
            #pragma unroll
            for (int s = 0; s < 4; s++) {
                floatx4 a = (floatx4){0.0f, 0.0f, 0.0f, 0.0f};
                a = __builtin_amdgcn_mfma_f32_16x16x32_bf16(kfr[s], qf[f], a, 0, 0, 0);
                a = __builtin_amdgcn_mfma_f32_16x16x32_bf16(kfr[s], qs[f], a, 0, 0, 0);
                #pragma unroll
                for (int r = 0; r < 4; r++) p[s][r] = a[r];
            }

            // ---- scale + mask + bounds ----
            #pragma unroll
            for (int s = 0; s < 4; s++) {
                int c0 = k0 + s * 16 + 4 * g;
                #pragma unroll
                for (int r = 0; r < 4; r++) {
                    float mvr = mask ? mv[s][r] : 0.0f;
                    p[s][r] = (c0 + r < Nk) ? (p[s][r] * 0.25f + mvr) : -1e30f;
                }
            }

            // ---- online softmax (per q = lane&15) ----
            float tmax = -1e30f;
            #pragma unroll
            for (int s = 0; s < 4; s++)
                #pragma unroll
                for (int r = 0; r < 4; r++) tmax = fmaxf(tmax, p[s][r]);
            tmax = fmaxf(tmax, __shfl_xor(tmax, 16));
            tmax = fmaxf(tmax, __shfl_xor(tmax, 32));
            float m_new = fmaxf(m_i[f], tmax);
            float alpha = __expf(m_i[f] - m_new);
            float lloc = 0.0f;
            #pragma unroll
            for (int s = 0; s < 4; s++) {
                #pragma unroll
                for (int r = 0; r < 4; r++) {
                    float e = __expf(p[s][r] - m_new);
                    p[s][r] = e; lloc += e;
                }
            }
            lloc += __shfl_xor(lloc, 16);
            lloc += __shfl_xor(lloc, 32);
            l_i[f] = l_i[f] * alpha + lloc;
            m_i[f] = m_new;
            #pragma unroll
            for (int r = 0; r < 4; r++) {
                float ar = __shfl(alpha, 4 * g + r);
                o_acc[f][r] *= ar;
            }

            // ---- PV: p is already the x16 A-frag (kc = 4g+r); trunc split ----
            #pragma unroll
            for (int s = 0; s < 4; s++) {
                bshort4 ph, pl;
                #pragma unroll
                for (int r = 0; r < 4; r++) {
                    unsigned short hh = f2b_t(p[s][r]);
                    ph[r] = (short)hh;
                    pl[r] = (short)f2b_t(p[s][r] - b2f_(hh));
                }
                o_acc[f] = __builtin_amdgcn_mfma_f32_16x16x16bf16_1k(ph, vhf[s], o_acc[f], 0, 0, 0);
                o_acc[f] = __builtin_amdgcn_mfma_f32_16x16x16bf16_1k(ph, vlf[s], o_acc[f], 0, 0, 0);
                o_acc[f] = __builtin_amdgcn_mfma_f32_16x16x16bf16_1k(pl, vhf[s], o_acc[f], 0, 0, 0);
            }
        }

        // ---- write next tile into the other buffer; one barrier per iteration ----
        if (pf) {
            int nb2 = cur ^ 1;
            float ka[4] = {nkv.x, nkv.y, nkv.z, nkv.w};
            float va[4] = {nvv.x, nvv.y, nvv.z, nvv.w};
            bshort4 khv, klv;
            #pragma unroll
            for (int j = 0; j < 4; j++) {
                unsigned short hh = f2b_t(ka[j]);
                khv[j] = (short)hh;
                klv[j] = (short)f2b_t(ka[j] - b2f_(hh));
            }
            *((bshort4*)&Khl[nb2][srow][sc])      = khv;
            *((bshort4*)&Khl[nb2][srow][16 + sc]) = klv;
            #pragma unroll
            for (int j = 0; j < 4; j++) {
                unsigned short hh = f2b_t(va[j]);
                Vhi[nb2][sc + j][srow] = hh;
                Vlo[nb2][sc + j][srow] = f2b_t(va[j] - b2f_(hh));
            }
        }
        __syncthreads();
    }

    // ---- epilogue: O reg r is (q-row 4g+r, d = r16); l lives at lane q ----
    #pragma unroll
    for (int f = 0; f < NFRG; f++) {
        int fi = f * 16 + z * 4 + w;
        if (fi * 16 >= Nq) continue;
        #pragma unroll
        for (int r = 0; r < 4; r++) {
            float lr = __shfl(l_i[f], 4 * g + r);
            int qrow = fi * 16 + 4 * g + r;
            if (qrow < Nq)
                O[((size_t)(b * Nq + qrow)) * EE + h * 16 + r16] = o_acc[f][r] / lr;
        }
    }
}

// ---------------- InstanceNorm over node axis (coalesced; r8: -276us vs e-fixed) ----------------
__global__ __launch_bounds__(256) void inorm_k(
    const float* __restrict__ X, const float* __restrict__ Y,
    const float* __restrict__ g, const float* __restrict__ bb,
    float* __restrict__ Out)
{
    int b = blockIdx.x, eg = blockIdx.y;
    int t = threadIdx.x;
    int tx = t & 15, tn = t >> 4;
    int e = eg * 16 + tx;
    const float* Xb = X + ((size_t)b * NN) * EE + e;
    const float* Yb = Y + ((size_t)b * NN) * EE + e;
    float s = 0.0f, s2 = 0.0f;
    for (int n = tn; n < NN; n += 16) {
        float v = Xb[(size_t)n * EE] + Yb[(size_t)n * EE];
        s += v; s2 += v * v;
    }
    __shared__ float rs[16][17], rs2[16][17];
    rs[tn][tx] = s; rs2[tn][tx] = s2;
    __syncthreads();
    float st = 0.0f, st2 = 0.0f;
    #pragma unroll
    for (int j = 0; j < 16; j++) { st += rs[j][tx]; st2 += rs2[j][tx]; }
    float mu = st * (1.0f / NN);
    float var = st2 * (1.0f / NN) - mu * mu;
    float inv = rsqrtf(var + 1e-5f);
    float gg = g[e], bv = bb[e];
    float* Ob = Out + ((size_t)b * NN) * EE + e;
    for (int n = tn; n < NN; n += 16) {
        float v = Xb[(size_t)n * EE] + Yb[(size_t)n * EE];
        Ob[(size_t)n * EE] = (v - mu) * inv * gg + bv;
    }
}

__global__ void zero_k(float* p, int n) {
    int i = blockIdx.x * 256 + threadIdx.x;
    if (i < n) p[i] = 0.0f;
}

__global__ __launch_bounds__(128) void encsum_k(const float* __restrict__ enc, float* __restrict__ esum) {
    int b = blockIdx.x, ch = blockIdx.y, t = threadIdx.x;
    float a = 0.0f;
    for (int i = 0; i < 65; i++) {
        int n = ch * 65 + i;
        a += enc[((size_t)(b * NN + n)) * EE + t];
    }
    atomicAdd(&esum[b * EE + t], a);
}

// mt[b,e] = sum_f (esum[b,f]/N) * Wr[e, 128+f]
__global__ __launch_bounds__(128) void meanterm_k(
    const float* __restrict__ esum, const float* __restrict__ Wr, float* __restrict__ mt)
{
    int b = blockIdx.x, t = threadIdx.x;
    __shared__ float em[128];
    em[t] = esum[b * EE + t] * (1.0f / NN);
    __syncthreads();
    const float* w = Wr + (size_t)t * 257 + 128;
    float a = 0.0f;
    for (int f = 0; f < 128; f++) a += em[f] * w[f];
    mt[b * EE + t] = a;
}

__global__ __launch_bounds__(128) void subtour_k(
    const float* __restrict__ enc, const int* __restrict__ subn,
    const int* __restrict__ subl, float* __restrict__ subm)
{
    int bm = blockIdx.x;
    int b = bm / MM;
    int t = threadIdx.x;
    int len = subl[bm];
    float acc = 0.0f; int cnt = 0;
    for (int l = 0; l < LL; l++) {
        int node = subn[(size_t)bm * LL + l];
        if (l < len && node >= DEPOT_) {
            acc += enc[((size_t)(b * NN + node)) * EE + t];
            cnt++;
        }
    }
    float cf = (float)(cnt < 1 ? 1 : cnt);
    subm[(size_t)bm * EE + t] = acc / cf;
}

// ---------------- decoder q: gather/blend, writes head-packed final_q ----------------
__global__ __launch_bounds__(128) void decq_gather_k(
    const float* __restrict__ R, const float* __restrict__ L1, const float* __restrict__ SM2,
    const float* __restrict__ mterm, const int* __restrict__ cur,
    const float* __restrict__ loadv, const int* __restrict__ sel,
    const float* __restrict__ Wqr, float* __restrict__ out)
{
    int bm = blockIdx.x;
    int b = bm / MM;
    int m = bm - b * MM;
    int t = threadIdx.x;
    int cn = cur[bm];
    int s2v = sel[(size_t)bm * 4 + 2];
    bool flag = (s2v >= DEPOT_) && (cn < DEPOT_);
    size_t eo = ((size_t)(b * NN + cn)) * EE + t;
    float q;
    if (flag) q = L1[eo] + SM2[(size_t)bm * EE + t];
    else      q = R[eo] + mterm[b * EE + t] + loadv[bm] * Wqr[(size_t)t * 257 + 256];
    out[((size_t)(b * HH + (t >> 4)) * MM + m) * 16 + (t & 15)] = q;
}

extern "C" void kernel_launch(void* const* d_in, const int* in_sizes, int n_in,
                              void* d_out, int out_size, void* d_ws, size_t ws_size,
                              hipStream_t stream)
{
    const float* depot = (const float*)d_in[0];
    const float* cust  = (const float*)d_in[1];
    const float* mask  = (const float*)d_in[2];
    const float* loadv = (const float*)d_in[3];
    const int*  cur   = (const int*)d_in[4];
    const int*  subn  = (const int*)d_in[5];
    const int*  subl  = (const int*)d_in[6];
    const int*  sel   = (const int*)d_in[7];
    const float* Wdep  = (const float*)d_in[8];
    const float* bdep  = (const float*)d_in[9];
    const float* Wcus  = (const float*)d_in[10];
    const float* bcus  = (const float*)d_in[11];
    const float* Wq    = (const float*)d_in[12];
    const float* Wk    = (const float*)d_in[13];
    const float* Wv    = (const float*)d_in[14];
    const float* Wc    = (const float*)d_in[15];
    const float* Wcb   = (const float*)d_in[16];
    const float* n1g   = (const float*)d_in[17];
    const float* n1b   = (const float*)d_in[18];
    const float* fW1   = (const float*)d_in[19];
    const float* fb1   = (const float*)d_in[20];
    const float* fW2   = (const float*)d_in[21];
    const float* fb2   = (const float*)d_in[22];
    const float* n2g   = (const float*)d_in[23];
    const float* n2b   = (const float*)d_in[24];
    const float* Wql   = (const float*)d_in[25];
    const float* Wqr   = (const float*)d_in[26];
    const float* dWk   = (const float*)d_in[27];
    const float* dWv   = (const float*)d_in[28];
    const float* dWc   = (const float*)d_in[29];
    const float* dWcb  = (const float*)d_in[30];

    const size_t SZ = (size_t)BB * NN * EE;           // 2,129,920
    float* f0 = (float*)d_ws;       // x / encoded
    float* f1 = f0 + SZ;            // q / k_d (packed) / logits (spans f1..f5)
    float* f2 = f1 + SZ;            // k / v_d (packed)
    float* f3 = f2 + SZ;            // v (packed) / encsum + meanterm
    float* f4 = f3 + SZ;            // mh,ff2 out / sub_mean, dec attn
    float* f5 = f4 + SZ;            // x1 / final_q (packed)
    float* big = f5 + SZ;           // ffh (B*N*FFH) / R,L1,SM2 / dec score
    unsigned short* WHp = (unsigned short*)(big + (size_t)BB * NN * FFH_);
    unsigned short* WLp = WHp + WTOT;

    dim3 g4(EE / 64, (BB * NN) / 64);      // (2, 260) = 520 blocks
    dim3 g16(FFH_ / 64, (BB * NN) / 64);   // (8, 260) = 2080 blocks
    dim3 gq3(6, (BB * NN) / 64);           // fused QKV, 1560 blocks
    dim3 gq2(4, (BB * NN) / 64);           // fused 2-way, 1040 blocks
    dim3 gmha(BB, HH, 4);                  // (32, 8, 4): id%8==b%8 -> per-batch L2 on one XCD
    dim3 gin(BB, 8);                       // coalesced inorm: (b, e-group)
    dim3 gsc((NN + GT - 1) / GT, (NN + GT - 1) / GT, BB);  // (9, 9, 32)

    wconv_k<<<(WTOT + 255) / 256, 256, 0, stream>>>(Wq, Wk, Wv, Wc, fW1, fW2,
                                                    dWk, dWv, dWc, Wql, Wqr, WHp, WLp);
    embed_k<<<(BB * NN * EE) / 256, 256, 0, stream>>>(depot, cust, Wdep, bdep, Wcus, bcus, f0);

    for (int i = 0; i < NL_; i++) {
        const unsigned short* lH = WHp + (size_t)i * WLS;
        const unsigned short* lL = WLp + (size_t)i * WLS;
        gemm_qkv3_k<<<gq3, 256, 0, stream>>>(f0, EE, lH, lL, EE, f1, f2, f3, EE, EE, 1);
        fmha_pers_k<<<gmha, 256, 0, stream>>>(f1, f2, f3, nullptr, f4, NN, NN);
        gemm_pc_k<<<g4, 256, 0, stream>>>(f4, EE, lH + 49152, lL + 49152, EE, Wcb + i * EE, f1, EE, EE, 0);
        inorm_k<<<gin, 256, 0, stream>>>(f0, f1, n1g + i * EE, n1b + i * EE, f5);
        gemm_pc_k<<<g16, 256, 0, stream>>>(f5, EE, lH + 65536, lL + 65536, EE, fb1 + i * FFH_, big, FFH_, EE, 1);
        gemm_pc_k<<<g4, 256, 0, stream>>>(big, FFH_, lH + 131072, lL + 131072, FFH_, fb2 + i * EE, f1, EE, FFH_, 0);
        inorm_k<<<gin, 256, 0, stream>>>(f5, f1, n2g + i * EE, n2b + i * EE, f0);
    }

    // ---- decoder ----
    const unsigned short* dH = WHp + WDEC;
    const unsigned short* dL = WLp + WDEC;
    gemm_qkv3_k<<<gq2, 256, 0, stream>>>(f0, EE, dH, dL, EE, f1, f2, f2, EE, EE, 1);  // k_d, v_d packed

    zero_k<<<(BB * EE + 255) / 256, 256, 0, stream>>>(f3, BB * EE);
    encsum_k<<<dim3(BB, 8), 128, 0, stream>>>(f0, f3);
    meanterm_k<<<BB, 128, 0, stream>>>(f3, Wqr, f3 + BB * EE);
    subtour_k<<<BB * MM, 128, 0, stream>>>(f0, subn, subl, f4);

    // R (big), L1 (big+SZ) from encoded; SM2 (big+2SZ) from subm  (standard layout)
    gemm_qkv3_k<<<gq2, 256, 0, stream>>>(f0, EE, dH + 49152, dL + 49152, EE, big, big + SZ, big + SZ, EE, EE, 0);
    gemm_pc_k<<<g4, 256, 0, stream>>>(f4, EE, dH + 49152 + 32768, dL + 49152 + 32768, EE, nullptr, big + 2 * SZ, EE, EE, 0);
    decq_gather_k<<<BB * MM, 128, 0, stream>>>(big, big + SZ, big + 2 * SZ, f3 + BB * EE, cur, loadv, sel, Wqr, f5);

    fmha_pers_k<<<gmha, 256, 0, stream>>>(f5, f1, f2, mask, f4, MM, NN);
    gemm_pc_k<<<g4, 256, 0, stream>>>(f4, EE, dH + 32768, dL + 32768, EE, dWcb, big, EE, EE, 0);

    // logits (B x 520 x 520) at f1 (spans f1..f5; all dead now)
    sgemm_k<<<gsc, 256, 0, stream>>>(big, f0, f1);
    smax_k<<<BB * MM, 64, 0, stream>>>(f1, mask, (float*)d_out);
}

// Round 11
// 1441.196 us; speedup vs baseline: 1.2972x; 1.0231x over previous
//
#include <hip/hip_runtime.h>
#include <hip/hip_bf16.h>

#define BB 32
#define NN 520
#define MM 520
#define EE 128
#define HH 8
#define DKK 16
#define FFH_ 512
#define NL_ 6
#define DEPOT_ 20
#define LL 40

typedef short short8 __attribute__((ext_vector_type(8)));
typedef short bshort4 __attribute__((ext_vector_type(4)));
typedef float floatx4 __attribute__((ext_vector_type(4)));

// Manual RTNE float->bf16 (4 VALU ops) -- used where a value is converted once.
__device__ __forceinline__ unsigned short f2b(float x) {
    unsigned int u = __float_as_uint(x);
    return (unsigned short)((u + 0x7fffu + ((u >> 16) & 1u)) >> 16);
}
// Truncating float->bf16 (1 VALU op) -- ONLY for hi/lo SPLIT PAIRS (lo captures
// the hi residual exactly; r8/r9: saved ~8us/dispatch in fmha vs RTNE).
__device__ __forceinline__ unsigned short f2b_t(float x) {
    return (unsigned short)(__float_as_uint(x) >> 16);
}
__device__ __forceinline__ float b2f_(unsigned short h) {
    return __uint_as_float(((unsigned int)h) << 16);
}

// ---------------- embedding: depot/customer linear ----------------
__global__ __launch_bounds__(256) void embed_k(
    const float* __restrict__ dep, const float* __restrict__ cus,
    const float* __restrict__ Wd, const float* __restrict__ bd,
    const float* __restrict__ Wc3, const float* __restrict__ bc,
    float* __restrict__ x)
{
    int idx = blockIdx.x * 256 + threadIdx.x;   // < B*N*E = 2129920
    int e = idx & 127;
    int bn = idx >> 7;
    int n = bn % NN;
    int b = bn / NN;
    float a;
    if (n < DEPOT_) {
        a = bd[e];
        const float* f = dep + ((size_t)(b * DEPOT_ + n)) * 4;
        #pragma unroll
        for (int j = 0; j < 4; j++) a += f[j] * Wd[e * 4 + j];
    } else {
        a = bc[e];
        const float* f = cus + ((size_t)(b * 500 + (n - DEPOT_))) * 3;
        #pragma unroll
        for (int j = 0; j < 3; j++) a += f[j] * Wc3[e * 3 + j];
    }
    x[idx] = a;
}

// ---------------- weight pre-conversion: fp32 -> hi/lo bf16 planes ----------------
#define WLS 196608
#define WDEC 1179648
#define WTOT 1277952
__global__ __launch_bounds__(256) void wconv_k(
    const float* __restrict__ Wq, const float* __restrict__ Wk, const float* __restrict__ Wv,
    const float* __restrict__ Wc, const float* __restrict__ fW1, const float* __restrict__ fW2,
    const float* __restrict__ dWk, const float* __restrict__ dWv, const float* __restrict__ dWc,
    const float* __restrict__ Wql, const float* __restrict__ Wqr,
    unsigned short* __restrict__ WH, unsigned short* __restrict__ WL)
{
    int idx = blockIdx.x * 256 + threadIdx.x;
    if (idx >= WTOT) return;
    const float* src;
    if (idx < WDEC) {
        int i = idx / WLS, r = idx % WLS;
        if (r < 49152) {
            int row = r >> 7, col = r & 127;
            const float* w = row < 128 ? Wq : (row < 256 ? Wk : Wv);
            src = w + (size_t)i * 16384 + (size_t)(row & 127) * 128 + col;
        } else if (r < 65536) {
            src = Wc + (size_t)i * 16384 + (r - 49152);
        } else if (r < 131072) {
            src = fW1 + (size_t)i * 65536 + (r - 65536);
        } else {
            src = fW2 + (size_t)i * 65536 + (r - 131072);
        }
    } else {
        int r = idx - WDEC;
        if (r < 32768) {
            int row = r >> 7, col = r & 127;
            src = (row < 128 ? dWk : dWv) + (size_t)(row & 127) * 128 + col;
        } else if (r < 49152) {
            src = dWc + (r - 32768);
        } else {
            int rr = r - 49152;
            int row = rr >> 7, col = rr & 127;
            if (row < 128)      src = Wqr + (size_t)row * 257 + col;
            else if (row < 256) src = Wql + (size_t)(row - 128) * 256 + col;
            else                src = Wql + (size_t)(row - 256) * 256 + 128 + col;
        }
    }
    float v = *src;
    unsigned short h = f2b(v);
    WH[idx] = h;
    WL[idx] = f2b(v - b2f_(h));
}

// ---------------- bf16x3 MFMA GEMM, BM=64, double-buffered LDS (r10: kept) ----------------
#define AP 40
__global__ __launch_bounds__(256) void gemm_pc_k(
    const float* __restrict__ A, int lda,
    const unsigned short* __restrict__ WH, const unsigned short* __restrict__ WL, int ldw,
    const float* __restrict__ bias,
    float* __restrict__ C, int ldc,
    int K, int relu)
{
    __shared__ __align__(16) unsigned short Ah[2][64][AP];
    __shared__ __align__(16) unsigned short Al[2][64][AP];
    __shared__ __align__(16) unsigned short Bh[2][64][AP];
    __shared__ __align__(16) unsigned short Bl[2][64][AP];

    int t = threadIdx.x;
    int w = t >> 6, lane = t & 63;
    int frow = lane & 15, fq = lane >> 4;
    int n0 = blockIdx.x * 64, m0 = blockIdx.y * 64;

    int arow = t & 63, acol = (t >> 6) * 8;

    const float* Abase = A + (size_t)(m0 + arow) * lda + acol;
    const unsigned short* WHb = WH + (size_t)(n0 + arow) * ldw + acol;
    const unsigned short* WLb = WL + (size_t)(n0 + arow) * ldw + acol;

    floatx4 acc[4];
    #pragma unroll
    for (int j = 0; j < 4; j++) acc[j] = (floatx4){0.0f, 0.0f, 0.0f, 0.0f};

    {
        float4 v0 = ((const float4*)Abase)[0];
        float4 v1 = ((const float4*)Abase)[1];
        float vr[8] = {v0.x, v0.y, v0.z, v0.w, v1.x, v1.y, v1.z, v1.w};
        short8 hv, lv;
        #pragma unroll
        for (int j = 0; j < 8; j++) {
            unsigned short h = f2b(vr[j]);
            hv[j] = (short)h;
            lv[j] = (short)f2b(vr[j] - b2f_(h));
        }
        *((short8*)&Ah[0][arow][acol]) = hv;
        *((short8*)&Al[0][arow][acol]) = lv;
        *((short8*)&Bh[0][arow][acol]) = *((const short8*)WHb);
        *((short8*)&Bl[0][arow][acol]) = *((const short8*)WLb);
    }
    __syncthreads();

    int nkt = K >> 5;
    for (int kt = 0; kt < nkt; kt++) {
        int cur = kt & 1;
        bool pf = (kt + 1 < nkt);

        float4 av0, av1;
        short8 nbh, nbl;
        if (pf) {
            const float* Ap = Abase + (kt + 1) * 32;
            av0 = ((const float4*)Ap)[0];
            av1 = ((const float4*)Ap)[1];
            nbh = *((const short8*)(WHb + (kt + 1) * 32));
            nbl = *((const short8*)(WLb + (kt + 1) * 32));
        }

        short8 ah = *((const short8*)&Ah[cur][w * 16 + frow][fq * 8]);
        short8 al = *((const short8*)&Al[cur][w * 16 + frow][fq * 8]);
        #pragma unroll
        for (int nt = 0; nt < 4; nt++) {
            short8 bh = *((const short8*)&Bh[cur][nt * 16 + frow][fq * 8]);
            short8 bl = *((const short8*)&Bl[cur][nt * 16 + frow][fq * 8]);
            acc[nt] = __builtin_amdgcn_mfma_f32_16x16x32_bf16(ah, bh, acc[nt], 0, 0, 0);
            acc[nt] = __builtin_amdgcn_mfma_f32_16x16x32_bf16(ah, bl, acc[nt], 0, 0, 0);
            acc[nt] = __builtin_amdgcn_mfma_f32_16x16x32_bf16(al, bh, acc[nt], 0, 0, 0);
        }

        if (pf) {
            int nb2 = cur ^ 1;
            float vr[8] = {av0.x, av0.y, av0.z, av0.w, av1.x, av1.y, av1.z, av1.w};
            short8 hv, lv;
            #pragma unroll
            for (int j = 0; j < 8; j++) {
                unsigned short h = f2b(vr[j]);
                hv[j] = (short)h;
                lv[j] = (short)f2b(vr[j] - b2f_(h));
            }
            *((short8*)&Ah[nb2][arow][acol]) = hv;
            *((short8*)&Al[nb2][arow][acol]) = lv;
            *((short8*)&Bh[nb2][arow][acol]) = nbh;
            *((short8*)&Bl[nb2][arow][acol]) = nbl;
        }
        __syncthreads();
    }

    #pragma unroll
    for (int nt = 0; nt < 4; nt++) {
        int col = n0 + nt * 16 + frow;
        float bv = bias ? bias[col] : 0.0f;
        int rbase = m0 + w * 16 + fq * 4;
        #pragma unroll
        for (int r = 0; r < 4; r++) {
            float v = acc[nt][r] + bv;
            if (relu) v = fmaxf(v, 0.0f);
            C[(size_t)(rbase + r) * ldc + col] = v;
        }
    }
}

// ---------------- fused 3-way GEMM (QKV / dec-KV / R+L1), BM=64, dbuf ----------------
__global__ __launch_bounds__(256) void gemm_qkv3_k(
    const float* __restrict__ A, int lda,
    const unsigned short* __restrict__ WH, const unsigned short* __restrict__ WL, int ldw,
    float* __restrict__ C0, float* __restrict__ C1, float* __restrict__ C2,
    int ldc, int K, int pack)
{
    __shared__ __align__(16) unsigned short Ah[2][64][AP];
    __shared__ __align__(16) unsigned short Al[2][64][AP];
    __shared__ __align__(16) unsigned short Bh[2][64][AP];
    __shared__ __align__(16) unsigned short Bl[2][64][AP];

    int t = threadIdx.x;
    int w = t >> 6, lane = t & 63;
    int frow = lane & 15, fq = lane >> 4;
    int nb = blockIdx.x;
    int which = nb >> 1;
    float* C = which == 0 ? C0 : (which == 1 ? C1 : C2);
    int n0w = nb * 64;
    int n0c = (nb & 1) * 64;
    int m0 = blockIdx.y * 64;

    int arow = t & 63, acol = (t >> 6) * 8;

    const float* Abase = A + (size_t)(m0 + arow) * lda + acol;
    const unsigned short* WHb = WH + (size_t)(n0w + arow) * ldw + acol;
    const unsigned short* WLb = WL + (size_t)(n0w + arow) * ldw + acol;

    floatx4 acc[4];
    #pragma unroll
    for (int j = 0; j < 4; j++) acc[j] = (floatx4){0.0f, 0.0f, 0.0f, 0.0f};

    {
        float4 v0 = ((const float4*)Abase)[0];
        float4 v1 = ((const float4*)Abase)[1];
        float vr[8] = {v0.x, v0.y, v0.z, v0.w, v1.x, v1.y, v1.z, v1.w};
        short8 hv, lv;
        #pragma unroll
        for (int j = 0; j < 8; j++) {
            unsigned short h = f2b(vr[j]);
            hv[j] = (short)h;
            lv[j] = (short)f2b(vr[j] - b2f_(h));
        }
        *((short8*)&Ah[0][arow][acol]) = hv;
        *((short8*)&Al[0][arow][acol]) = lv;
        *((short8*)&Bh[0][arow][acol]) = *((const short8*)WHb);
        *((short8*)&Bl[0][arow][acol]) = *((const short8*)WLb);
    }
    __syncthreads();

    int nkt = K >> 5;
    for (int kt = 0; kt < nkt; kt++) {
        int cur = kt & 1;
        bool pf = (kt + 1 < nkt);

        float4 av0, av1;
        short8 nbh, nbl;
        if (pf) {
            const float* Ap = Abase + (kt + 1) * 32;
            av0 = ((const float4*)Ap)[0];
            av1 = ((const float4*)Ap)[1];
            nbh = *((const short8*)(WHb + (kt + 1) * 32));
            nbl = *((const short8*)(WLb + (kt + 1) * 32));
        }

        short8 ah = *((const short8*)&Ah[cur][w * 16 + frow][fq * 8]);
        short8 al = *((const short8*)&Al[cur][w * 16 + frow][fq * 8]);
        #pragma unroll
        for (int nt = 0; nt < 4; nt++) {
            short8 bh = *((const short8*)&Bh[cur][nt * 16 + frow][fq * 8]);
            short8 bl = *((const short8*)&Bl[cur][nt * 16 + frow][fq * 8]);
            acc[nt] = __builtin_amdgcn_mfma_f32_16x16x32_bf16(ah, bh, acc[nt], 0, 0, 0);
            acc[nt] = __builtin_amdgcn_mfma_f32_16x16x32_bf16(ah, bl, acc[nt], 0, 0, 0);
            acc[nt] = __builtin_amdgcn_mfma_f32_16x16x32_bf16(al, bh, acc[nt], 0, 0, 0);
        }

        if (pf) {
            int nb2 = cur ^ 1;
            float vr[8] = {av0.x, av0.y, av0.z, av0.w, av1.x, av1.y, av1.z, av1.w};
            short8 hv, lv;
            #pragma unroll
            for (int j = 0; j < 8; j++) {
                unsigned short h = f2b(vr[j]);
                hv[j] = (short)h;
                lv[j] = (short)f2b(vr[j] - b2f_(h));
            }
            *((short8*)&Ah[nb2][arow][acol]) = hv;
            *((short8*)&Al[nb2][arow][acol]) = lv;
            *((short8*)&Bh[nb2][arow][acol]) = nbh;
            *((short8*)&Bl[nb2][arow][acol]) = nbl;
        }
        __syncthreads();
    }

    #pragma unroll
    for (int nt = 0; nt < 4; nt++) {
        int col = n0c + nt * 16 + frow;
        int hh = col >> 4, dd = col & 15;
        int rbase = m0 + w * 16 + fq * 4;
        #pragma unroll
        for (int r = 0; r < 4; r++) {
            int row = rbase + r;
            if (pack) {
                int b2 = row / NN, n2 = row - b2 * NN;
                C[((size_t)(b2 * HH + hh) * NN + n2) * 16 + dd] = acc[nt][r];
            } else {
                C[(size_t)row * ldc + col] = acc[nt][r];
            }
        }
    }
}

// ---------------- score GEMM (NT) -> MFMA bf16x3 with tanh epilogue ----------------
// r10: was fp32 VALU (4.4 GFLOP, ~70-90us). Same BM=64 dbuf structure as
// gemm_pc_k; BOTH operands converted in-kernel (trunc splits -- hi/lo pair).
// Grid (9, 9, 32) = 2592 blocks. Rows clamped on load, stores guarded.
__global__ __launch_bounds__(256) void sgemm_k(
    const float* __restrict__ A,    // score [B*520][128]
    const float* __restrict__ Enc,  // [B*520][128]
    float* __restrict__ C)          // [B][520][520]
{
    __shared__ __align__(16) unsigned short Ah[2][64][AP];
    __shared__ __align__(16) unsigned short Al[2][64][AP];
    __shared__ __align__(16) unsigned short Bh[2][64][AP];
    __shared__ __align__(16) unsigned short Bl[2][64][AP];

    int t = threadIdx.x;
    int w = t >> 6, lane = t & 63;
    int frow = lane & 15, fq = lane >> 4;
    int b = blockIdx.z;
    int n0 = blockIdx.x * 64, m0 = blockIdx.y * 64;

    int arow = t & 63, acol = (t >> 6) * 8;
    int mr = m0 + arow; if (mr >= NN) mr = NN - 1;
    int nr = n0 + arow; if (nr >= NN) nr = NN - 1;

    const float* Abase = A + ((size_t)(b * NN + mr)) * EE + acol;
    const float* Bbase = Enc + ((size_t)(b * NN + nr)) * EE + acol;

    floatx4 acc[4];
    #pragma unroll
    for (int j = 0; j < 4; j++) acc[j] = (floatx4){0.0f, 0.0f, 0.0f, 0.0f};

    {
        float4 a0 = ((const float4*)Abase)[0];
        float4 a1 = ((const float4*)Abase)[1];
        float4 b0 = ((const float4*)Bbase)[0];
        float4 b1 = ((const float4*)Bbase)[1];
        float ar[8] = {a0.x, a0.y, a0.z, a0.w, a1.x, a1.y, a1.z, a1.w};
        float br[8] = {b0.x, b0.y, b0.z, b0.w, b1.x, b1.y, b1.z, b1.w};
        short8 ahv, alv, bhv, blv;
        #pragma unroll
        for (int j = 0; j < 8; j++) {
            unsigned short h = f2b_t(ar[j]);
            ahv[j] = (short)h;
            alv[j] = (short)f2b_t(ar[j] - b2f_(h));
            unsigned short g2 = f2b_t(br[j]);
            bhv[j] = (short)g2;
            blv[j] = (short)f2b_t(br[j] - b2f_(g2));
        }
        *((short8*)&Ah[0][arow][acol]) = ahv;
        *((short8*)&Al[0][arow][acol]) = alv;
        *((short8*)&Bh[0][arow][acol]) = bhv;
        *((short8*)&Bl[0][arow][acol]) = blv;
    }
    __syncthreads();

    int nkt = EE >> 5;   // 4
    for (int kt = 0; kt < nkt; kt++) {
        int cur = kt & 1;
        bool pf = (kt + 1 < nkt);

        float4 a0, a1, b0, b1;
        if (pf) {
            const float* Ap = Abase + (kt + 1) * 32;
            const float* Bp = Bbase + (kt + 1) * 32;
            a0 = ((const float4*)Ap)[0]; a1 = ((const float4*)Ap)[1];
            b0 = ((const float4*)Bp)[0]; b1 = ((const float4*)Bp)[1];
        }

        short8 ah = *((const short8*)&Ah[cur][w * 16 + frow][fq * 8]);
        short8 al = *((const short8*)&Al[cur][w * 16 + frow][fq * 8]);
        #pragma unroll
        for (int nt = 0; nt < 4; nt++) {
            short8 bh = *((const short8*)&Bh[cur][nt * 16 + frow][fq * 8]);
            short8 bl = *((const short8*)&Bl[cur][nt * 16 + frow][fq * 8]);
            acc[nt] = __builtin_amdgcn_mfma_f32_16x16x32_bf16(ah, bh, acc[nt], 0, 0, 0);
            acc[nt] = __builtin_amdgcn_mfma_f32_16x16x32_bf16(ah, bl, acc[nt], 0, 0, 0);
            acc[nt] = __builtin_amdgcn_mfma_f32_16x16x32_bf16(al, bh, acc[nt], 0, 0, 0);
        }

        if (pf) {
            int nb2 = cur ^ 1;
            float ar[8] = {a0.x, a0.y, a0.z, a0.w, a1.x, a1.y, a1.z, a1.w};
            float br[8] = {b0.x, b0.y, b0.z, b0.w, b1.x, b1.y, b1.z, b1.w};
            short8 ahv, alv, bhv, blv;
            #pragma unroll
            for (int j = 0; j < 8; j++) {
                unsigned short h = f2b_t(ar[j]);
                ahv[j] = (short)h;
                alv[j] = (short)f2b_t(ar[j] - b2f_(h));
                unsigned short g2 = f2b_t(br[j]);
                bhv[j] = (short)g2;
                blv[j] = (short)f2b_t(br[j] - b2f_(g2));
            }
            *((short8*)&Ah[nb2][arow][acol]) = ahv;
            *((short8*)&Al[nb2][arow][acol]) = alv;
            *((short8*)&Bh[nb2][arow][acol]) = bhv;
            *((short8*)&Bl[nb2][arow][acol]) = blv;
        }
        __syncthreads();
    }

    #pragma unroll
    for (int nt = 0; nt < 4; nt++) {
        int n = n0 + nt * 16 + frow;
        if (n >= NN) continue;
        int rbase = m0 + w * 16 + fq * 4;
        #pragma unroll
        for (int r = 0; r < 4; r++) {
            int m = rbase + r;
            if (m >= NN) continue;
            float v = 10.0f * tanhf(acc[nt][r] * 0.088388347648318447f);
            C[((size_t)(b * NN + m)) * NN + n] = v;
        }
    }
}

// ---------------- row softmax: out = softmax(logits + mask) ----------------
__global__ __launch_bounds__(64) void smax_k(
    const float* __restrict__ L, const float* __restrict__ mask,
    float* __restrict__ out)
{
    int bm = blockIdx.x;
    int t = threadIdx.x;
    const float* Lr = L + (size_t)bm * NN;
    const float* Mr = mask + (size_t)bm * NN;
    float v[9];
    float mx = -1e30f;
    #pragma unroll
    for (int i = 0; i < 9; i++) {
        int idx = t + i * 64;
        if (idx < NN) { v[i] = Lr[idx] + Mr[idx]; mx = fmaxf(mx, v[i]); }
        else v[i] = -1e30f;
    }
    #pragma unroll
    for (int o = 32; o > 0; o >>= 1) mx = fmaxf(mx, __shfl_xor(mx, o));
    float s = 0.0f;
    #pragma unroll
    for (int i = 0; i < 9; i++) {
        int idx = t + i * 64;
        float e = (idx < NN) ? expf(v[i] - mx) : 0.0f;
        v[i] = e; s += e;
    }
    #pragma unroll
    for (int o = 32; o > 0; o >>= 1) s += __shfl_xor(s, o);
    float inv = 1.0f / s;
    #pragma unroll
    for (int i = 0; i < 9; i++) {
        int idx = t + i * 64;
        if (idx < NN) out[(size_t)bm * NN + idx] = v[i] * inv;
    }
}

// ---------------- persistent-KV MFMA flash attention v3.3 (r9 version restored) ----------------
// r10 post-mortem: per-frag mask loads serialized with MFMAs (80->92us); the
// HOISTED mvv[3][4][4] issues all 12 loads at tile top so latency overlaps all
// 3 fragments' compute. VGPR 108 was NOT the limiter. Keep r9 exactly.
#define ATK 64
#define NFRG 3
__global__ __launch_bounds__(256) void fmha_pers_k(
    const float* __restrict__ Qp, const float* __restrict__ Kp,
    const float* __restrict__ Vp, const float* __restrict__ mask,
    float* __restrict__ O, int Nq, int Nk)
{
    __shared__ __align__(16) unsigned short Khl[2][ATK][40];  // [kc][0:16 hi-dk | 16:32 lo-dk]
    __shared__ __align__(16) unsigned short Vhi[2][16][72];
    __shared__ __align__(16) unsigned short Vlo[2][16][72];

    int b = blockIdx.x, h = blockIdx.y, z = blockIdx.z;
    int bh = b * HH + h;
    int t = threadIdx.x;
    int w = t >> 6, lane = t & 63;
    int r16 = lane & 15, g = lane >> 4;

    short8 qf[NFRG], qs[NFRG];
    floatx4 o_acc[NFRG];
    float m_i[NFRG], l_i[NFRG];
    const float* mrowf[NFRG];
    const float* QpB = Qp + (size_t)bh * Nq * 16;
    #pragma unroll
    for (int f = 0; f < NFRG; f++) {
        int fi = f * 16 + z * 4 + w;
        int qg = fi * 16 + r16;
        int qc = qg < Nq ? qg : Nq - 1;
        const float* qp = QpB + (size_t)qc * 16 + 8 * (g & 1);
        float4 qv0 = *((const float4*)qp);
        float4 qv1 = *((const float4*)(qp + 4));
        float qa[8] = {qv0.x, qv0.y, qv0.z, qv0.w, qv1.x, qv1.y, qv1.z, qv1.w};
        #pragma unroll
        for (int j = 0; j < 8; j++) {
            unsigned short hh = f2b_t(qa[j]);
            unsigned short ll = f2b_t(qa[j] - b2f_(hh));
            qf[f][j] = (short)(g < 2 ? hh : ll);
            qs[f][j] = (short)(g < 2 ? ll : hh);
        }
        o_acc[f] = (floatx4){0.0f, 0.0f, 0.0f, 0.0f};
        m_i[f] = -1e30f; l_i[f] = 0.0f;
        mrowf[f] = mask ? (mask + ((size_t)(b * Nq + qc)) * Nk) : nullptr;
    }

    int srow = t >> 2, sc = (t & 3) * 4;
    const float* KpB = Kp + ((size_t)bh * Nk) * 16 + sc;
    const float* VpB = Vp + ((size_t)bh * Nk) * 16 + sc;

    {
        int krc = srow < Nk ? srow : Nk - 1;
        float4 kv = *((const float4*)(KpB + (size_t)krc * 16));
        float4 vv = *((const float4*)(VpB + (size_t)krc * 16));
        float ka[4] = {kv.x, kv.y, kv.z, kv.w};
        float va[4] = {vv.x, vv.y, vv.z, vv.w};
        bshort4 khv, klv;
        #pragma unroll
        for (int j = 0; j < 4; j++) {
            unsigned short hh = f2b_t(ka[j]);
            khv[j] = (short)hh;
            klv[j] = (short)f2b_t(ka[j] - b2f_(hh));
        }
        *((bshort4*)&Khl[0][srow][sc])      = khv;
        *((bshort4*)&Khl[0][srow][16 + sc]) = klv;
        #pragma unroll
        for (int j = 0; j < 4; j++) {
            unsigned short hh = f2b_t(va[j]);
            Vhi[0][sc + j][srow] = hh;
            Vlo[0][sc + j][srow] = f2b_t(va[j] - b2f_(hh));
        }
    }
    __syncthreads();

    int nkt = (Nk + ATK - 1) / ATK;
    for (int kt = 0; kt < nkt; kt++) {
        int cur = kt & 1;
        int k0 = kt * ATK;

        float4 nkv, nvv;
        bool pf = (kt + 1 < nkt);
        if (pf) {
            int kr = k0 + ATK + srow;
            int krc = kr < Nk ? kr : Nk - 1;
            nkv = *((const float4*)(KpB + (size_t)krc * 16));
            nvv = *((const float4*)(VpB + (size_t)krc * 16));
        }

        // ---- hoisted mask loads for this tile (issue under the QK MFMAs) ----
        float mvv[NFRG][4][4];
        if (mask) {
            #pragma unroll
            for (int f = 0; f < NFRG; f++) {
                #pragma unroll
                for (int s = 0; s < 4; s++) {
                    int c0 = k0 + s * 16 + 4 * g;
                    if (c0 + 3 < Nk) {
                        float4 m4 = *((const float4*)(mrowf[f] + c0));
                        mvv[f][s][0] = m4.x; mvv[f][s][1] = m4.y;
                        mvv[f][s][2] = m4.z; mvv[f][s][3] = m4.w;
                    } else {
                        #pragma unroll
                        for (int r = 0; r < 4; r++)
                            mvv[f][s][r] = (c0 + r < Nk) ? mrowf[f][c0 + r] : 0.0f;
                    }
                }
            }
        }

        short8 kfr[4];
        bshort4 vhf[4], vlf[4];
        #pragma unroll
        for (int s = 0; s < 4; s++) {
            kfr[s] = *((const short8*)&Khl[cur][s * 16 + r16][8 * g]);
            vhf[s] = *((const bshort4*)&Vhi[cur][r16][s * 16 + 4 * g]);
            vlf[s] = *((const bshort4*)&Vlo[cur][r16][s * 16 + 4 * g]);
        }

        #pragma unroll
        for (int f = 0; f < NFRG; f++) {
            int fi = f * 16 + z * 4 + w;
            if (fi * 16 >= Nq) continue;   // wave-uniform

            float p[4][4];
            #pragma unroll
            for (int s = 0; s < 4; s++) {
                floatx4 a = (floatx4){0.0f, 0.0f, 0.0f, 0.0f};
                a = __builtin_amdgcn_mfma_f32_16x16x32_bf16(kfr[s], qf[f], a, 0, 0, 0);
                a = __builtin_amdgcn_mfma_f32_16x16x32_bf16(kfr[s], qs[f], a, 0, 0, 0);
                #pragma unroll
                for (int r = 0; r < 4; r++) p[s][r] = a[r];
            }

            #pragma unroll
            for (int s = 0; s < 4; s++) {
                int c0 = k0 + s * 16 + 4 * g;
                #pragma unroll
                for (int r = 0; r < 4; r++) {
                    float mv = mask ? mvv[f][s][r] : 0.0f;
                    p[s][r] = (c0 + r < Nk) ? (p[s][r] * 0.25f + mv) : -1e30f;
                }
            }

            float tmax = -1e30f;
            #pragma unroll
            for (int s = 0; s < 4; s++)
                #pragma unroll
                for (int r = 0; r < 4; r++) tmax = fmaxf(tmax, p[s][r]);
            tmax = fmaxf(tmax, __shfl_xor(tmax, 16));
            tmax = fmaxf(tmax, __shfl_xor(tmax, 32));
            float m_new = fmaxf(m_i[f], tmax);
            float alpha = __expf(m_i[f] - m_new);
            float lloc = 0.0f;
            #pragma unroll
            for (int s = 0; s < 4; s++) {
                #pragma unroll
                for (int r = 0; r < 4; r++) {
                    float e = __expf(p[s][r] - m_new);
                    p[s][r] = e; lloc += e;
                }
            }
            lloc += __shfl_xor(lloc, 16);
            lloc += __shfl_xor(lloc, 32);
            l_i[f] = l_i[f] * alpha + lloc;
            m_i[f] = m_new;
            #pragma unroll
            for (int r = 0; r < 4; r++) {
                float ar = __shfl(alpha, 4 * g + r);
                o_acc[f][r] *= ar;
            }

            #pragma unroll
            for (int s = 0; s < 4; s++) {
                bshort4 ph, pl;
                #pragma unroll
                for (int r = 0; r < 4; r++) {
                    unsigned short hh = f2b_t(p[s][r]);
                    ph[r] = (short)hh;
                    pl[r] = (short)f2b_t(p[s][r] - b2f_(hh));
                }
                o_acc[f] = __builtin_amdgcn_mfma_f32_16x16x16bf16_1k(ph, vhf[s], o_acc[f], 0, 0, 0);
                o_acc[f] = __builtin_amdgcn_mfma_f32_16x16x16bf16_1k(ph, vlf[s], o_acc[f], 0, 0, 0);
                o_acc[f] = __builtin_amdgcn_mfma_f32_16x16x16bf16_1k(pl, vhf[s], o_acc[f], 0, 0, 0);
            }
        }

        if (pf) {
            int nb2 = cur ^ 1;
            float ka[4] = {nkv.x, nkv.y, nkv.z, nkv.w};
            float va[4] = {nvv.x, nvv.y, nvv.z, nvv.w};
            bshort4 khv, klv;
            #pragma unroll
            for (int j = 0; j < 4; j++) {
                unsigned short hh = f2b_t(ka[j]);
                khv[j] = (short)hh;
                klv[j] = (short)f2b_t(ka[j] - b2f_(hh));
            }
            *((bshort4*)&Khl[nb2][srow][sc])      = khv;
            *((bshort4*)&Khl[nb2][srow][16 + sc]) = klv;
            #pragma unroll
            for (int j = 0; j < 4; j++) {
                unsigned short hh = f2b_t(va[j]);
                Vhi[nb2][sc + j][srow] = hh;
                Vlo[nb2][sc + j][srow] = f2b_t(va[j] - b2f_(hh));
            }
        }
        __syncthreads();
    }

    #pragma unroll
    for (int f = 0; f < NFRG; f++) {
        int fi = f * 16 + z * 4 + w;
        if (fi * 16 >= Nq) continue;
        #pragma unroll
        for (int r = 0; r < 4; r++) {
            float lr = __shfl(l_i[f], 4 * g + r);
            int qrow = fi * 16 + 4 * g + r;
            if (qrow < Nq)
                O[((size_t)(b * Nq + qrow)) * EE + h * 16 + r16] = o_acc[f][r] / lr;
        }
    }
}

// ---------------- InstanceNorm over node axis (coalesced; r8: -276us vs e-fixed) ----------------
__global__ __launch_bounds__(256) void inorm_k(
    const float* __restrict__ X, const float* __restrict__ Y,
    const float* __restrict__ g, const float* __restrict__ bb,
    float* __restrict__ Out)
{
    int b = blockIdx.x, eg = blockIdx.y;
    int t = threadIdx.x;
    int tx = t & 15, tn = t >> 4;
    int e = eg * 16 + tx;
    const float* Xb = X + ((size_t)b * NN) * EE + e;
    const float* Yb = Y + ((size_t)b * NN) * EE + e;
    float s = 0.0f, s2 = 0.0f;
    for (int n = tn; n < NN; n += 16) {
        float v = Xb[(size_t)n * EE] + Yb[(size_t)n * EE];
        s += v; s2 += v * v;
    }
    __shared__ float rs[16][17], rs2[16][17];
    rs[tn][tx] = s; rs2[tn][tx] = s2;
    __syncthreads();
    float st = 0.0f, st2 = 0.0f;
    #pragma unroll
    for (int j = 0; j < 16; j++) { st += rs[j][tx]; st2 += rs2[j][tx]; }
    float mu = st * (1.0f / NN);
    float var = st2 * (1.0f / NN) - mu * mu;
    float inv = rsqrtf(var + 1e-5f);
    float gg = g[e], bv = bb[e];
    float* Ob = Out + ((size_t)b * NN) * EE + e;
    for (int n = tn; n < NN; n += 16) {
        float v = Xb[(size_t)n * EE] + Yb[(size_t)n * EE];
        Ob[(size_t)n * EE] = (v - mu) * inv * gg + bv;
    }
}

__global__ void zero_k(float* p, int n) {
    int i = blockIdx.x * 256 + threadIdx.x;
    if (i < n) p[i] = 0.0f;
}

__global__ __launch_bounds__(128) void encsum_k(const float* __restrict__ enc, float* __restrict__ esum) {
    int b = blockIdx.x, ch = blockIdx.y, t = threadIdx.x;
    float a = 0.0f;
    for (int i = 0; i < 65; i++) {
        int n = ch * 65 + i;
        a += enc[((size_t)(b * NN + n)) * EE + t];
    }
    atomicAdd(&esum[b * EE + t], a);
}

// mt[b,e] = sum_f (esum[b,f]/N) * Wr[e, 128+f]
__global__ __launch_bounds__(128) void meanterm_k(
    const float* __restrict__ esum, const float* __restrict__ Wr, float* __restrict__ mt)
{
    int b = blockIdx.x, t = threadIdx.x;
    __shared__ float em[128];
    em[t] = esum[b * EE + t] * (1.0f / NN);
    __syncthreads();
    const float* w = Wr + (size_t)t * 257 + 128;
    float a = 0.0f;
    for (int f = 0; f < 128; f++) a += em[f] * w[f];
    mt[b * EE + t] = a;
}

__global__ __launch_bounds__(128) void subtour_k(
    const float* __restrict__ enc, const int* __restrict__ subn,
    const int* __restrict__ subl, float* __restrict__ subm)
{
    int bm = blockIdx.x;
    int b = bm / MM;
    int t = threadIdx.x;
    int len = subl[bm];
    float acc = 0.0f; int cnt = 0;
    for (int l = 0; l < LL; l++) {
        int node = subn[(size_t)bm * LL + l];
        if (l < len && node >= DEPOT_) {
            acc += enc[((size_t)(b * NN + node)) * EE + t];
            cnt++;
        }
    }
    float cf = (float)(cnt < 1 ? 1 : cnt);
    subm[(size_t)bm * EE + t] = acc / cf;
}

// ---------------- decoder q: gather/blend, writes head-packed final_q ----------------
__global__ __launch_bounds__(128) void decq_gather_k(
    const float* __restrict__ R, const float* __restrict__ L1, const float* __restrict__ SM2,
    const float* __restrict__ mterm, const int* __restrict__ cur,
    const float* __restrict__ loadv, const int* __restrict__ sel,
    const float* __restrict__ Wqr, float* __restrict__ out)
{
    int bm = blockIdx.x;
    int b = bm / MM;
    int m = bm - b * MM;
    int t = threadIdx.x;
    int cn = cur[bm];
    int s2v = sel[(size_t)bm * 4 + 2];
    bool flag = (s2v >= DEPOT_) && (cn < DEPOT_);
    size_t eo = ((size_t)(b * NN + cn)) * EE + t;
    float q;
    if (flag) q = L1[eo] + SM2[(size_t)bm * EE + t];
    else      q = R[eo] + mterm[b * EE + t] + loadv[bm] * Wqr[(size_t)t * 257 + 256];
    out[((size_t)(b * HH + (t >> 4)) * MM + m) * 16 + (t & 15)] = q;
}

extern "C" void kernel_launch(void* const* d_in, const int* in_sizes, int n_in,
                              void* d_out, int out_size, void* d_ws, size_t ws_size,
                              hipStream_t stream)
{
    const float* depot = (const float*)d_in[0];
    const float* cust  = (const float*)d_in[1];
    const float* mask  = (const float*)d_in[2];
    const float* loadv = (const float*)d_in[3];
    const int*  cur   = (const int*)d_in[4];
    const int*  subn  = (const int*)d_in[5];
    const int*  subl  = (const int*)d_in[6];
    const int*  sel   = (const int*)d_in[7];
    const float* Wdep  = (const float*)d_in[8];
    const float* bdep  = (const float*)d_in[9];
    const float* Wcus  = (const float*)d_in[10];
    const float* bcus  = (const float*)d_in[11];
    const float* Wq    = (const float*)d_in[12];
    const float* Wk    = (const float*)d_in[13];
    const float* Wv    = (const float*)d_in[14];
    const float* Wc    = (const float*)d_in[15];
    const float* Wcb   = (const float*)d_in[16];
    const float* n1g   = (const float*)d_in[17];
    const float* n1b   = (const float*)d_in[18];
    const float* fW1   = (const float*)d_in[19];
    const float* fb1   = (const float*)d_in[20];
    const float* fW2   = (const float*)d_in[21];
    const float* fb2   = (const float*)d_in[22];
    const float* n2g   = (const float*)d_in[23];
    const float* n2b   = (const float*)d_in[24];
    const float* Wql   = (const float*)d_in[25];
    const float* Wqr   = (const float*)d_in[26];
    const float* dWk   = (const float*)d_in[27];
    const float* dWv   = (const float*)d_in[28];
    const float* dWc   = (const float*)d_in[29];
    const float* dWcb  = (const float*)d_in[30];

    const size_t SZ = (size_t)BB * NN * EE;           // 2,129,920
    float* f0 = (float*)d_ws;       // x / encoded
    float* f1 = f0 + SZ;            // q / k_d (packed) / logits (spans f1..f5)
    float* f2 = f1 + SZ;            // k / v_d (packed)
    float* f3 = f2 + SZ;            // v (packed) / encsum + meanterm
    float* f4 = f3 + SZ;            // mh,ff2 out / sub_mean, dec attn
    float* f5 = f4 + SZ;            // x1 / final_q (packed)
    float* big = f5 + SZ;           // ffh (B*N*FFH) / R,L1,SM2 / dec score
    unsigned short* WHp = (unsigned short*)(big + (size_t)BB * NN * FFH_);
    unsigned short* WLp = WHp + WTOT;

    dim3 g4(EE / 64, (BB * NN) / 64);      // (2, 260) = 520 blocks
    dim3 g16(FFH_ / 64, (BB * NN) / 64);   // (8, 260) = 2080 blocks
    dim3 gq3(6, (BB * NN) / 64);           // fused QKV, 1560 blocks
    dim3 gq2(4, (BB * NN) / 64);           // fused 2-way, 1040 blocks
    dim3 gmha(BB, HH, 4);                  // (32, 8, 4): id%8==b%8 -> per-batch L2 on one XCD
    dim3 gin(BB, 8);                       // coalesced inorm: (b, e-group)
    dim3 gsc((NN + 63) / 64, (NN + 63) / 64, BB);  // (9, 9, 32) MFMA logits

    wconv_k<<<(WTOT + 255) / 256, 256, 0, stream>>>(Wq, Wk, Wv, Wc, fW1, fW2,
                                                    dWk, dWv, dWc, Wql, Wqr, WHp, WLp);
    embed_k<<<(BB * NN * EE) / 256, 256, 0, stream>>>(depot, cust, Wdep, bdep, Wcus, bcus, f0);

    for (int i = 0; i < NL_; i++) {
        const unsigned short* lH = WHp + (size_t)i * WLS;
        const unsigned short* lL = WLp + (size_t)i * WLS;
        gemm_qkv3_k<<<gq3, 256, 0, stream>>>(f0, EE, lH, lL, EE, f1, f2, f3, EE, EE, 1);
        fmha_pers_k<<<gmha, 256, 0, stream>>>(f1, f2, f3, nullptr, f4, NN, NN);
        gemm_pc_k<<<g4, 256, 0, stream>>>(f4, EE, lH + 49152, lL + 49152, EE, Wcb + i * EE, f1, EE, EE, 0);
        inorm_k<<<gin, 256, 0, stream>>>(f0, f1, n1g + i * EE, n1b + i * EE, f5);
        gemm_pc_k<<<g16, 256, 0, stream>>>(f5, EE, lH + 65536, lL + 65536, EE, fb1 + i * FFH_, big, FFH_, EE, 1);
        gemm_pc_k<<<g4, 256, 0, stream>>>(big, FFH_, lH + 131072, lL + 131072, FFH_, fb2 + i * EE, f1, EE, FFH_, 0);
        inorm_k<<<gin, 256, 0, stream>>>(f5, f1, n2g + i * EE, n2b + i * EE, f0);
    }

    // ---- decoder ----
    const unsigned short* dH = WHp + WDEC;
    const unsigned short* dL = WLp + WDEC;
    gemm_qkv3_k<<<gq2, 256, 0, stream>>>(f0, EE, dH, dL, EE, f1, f2, f2, EE, EE, 1);  // k_d, v_d packed

    zero_k<<<(BB * EE + 255) / 256, 256, 0, stream>>>(f3, BB * EE);
    encsum_k<<<dim3(BB, 8), 128, 0, stream>>>(f0, f3);
    meanterm_k<<<BB, 128, 0, stream>>>(f3, Wqr, f3 + BB * EE);
    subtour_k<<<BB * MM, 128, 0, stream>>>(f0, subn, subl, f4);

    // R (big), L1 (big+SZ) from encoded; SM2 (big+2SZ) from subm  (standard layout)
    gemm_qkv3_k<<<gq2, 256, 0, stream>>>(f0, EE, dH + 49152, dL + 49152, EE, big, big + SZ, big + SZ, EE, EE, 0);
    gemm_pc_k<<<g4, 256, 0, stream>>>(f4, EE, dH + 49152 + 32768, dL + 49152 + 32768, EE, nullptr, big + 2 * SZ, EE, EE, 0);
    decq_gather_k<<<BB * MM, 128, 0, stream>>>(big, big + SZ, big + 2 * SZ, f3 + BB * EE, cur, loadv, sel, Wqr, f5);

    fmha_pers_k<<<gmha, 256, 0, stream>>>(f5, f1, f2, mask, f4, MM, NN);
    gemm_pc_k<<<g4, 256, 0, stream>>>(f4, EE, dH + 32768, dL + 32768, EE, dWcb, big, EE, EE, 0);

    // logits (B x 520 x 520) at f1 (spans f1..f5; all dead now)
    sgemm_k<<<gsc, 256, 0, stream>>>(big, f0, f1);
    smax_k<<<BB * MM, 64, 0, stream>>>(f1, mask, (float*)d_out);
}

// Round 12
// 1384.771 us; speedup vs baseline: 1.3500x; 1.0407x over previous
//
#include <hip/hip_runtime.h>
#include <hip/hip_bf16.h>

#define BB 32
#define NN 520
#define MM 520
#define EE 128
#define HH 8
#define DKK 16
#define FFH_ 512
#define NL_ 6
#define DEPOT_ 20
#define LL 40

typedef short short8 __attribute__((ext_vector_type(8)));
typedef short bshort4 __attribute__((ext_vector_type(4)));
typedef float floatx4 __attribute__((ext_vector_type(4)));

// Manual RTNE float->bf16 (4 VALU ops) -- used where a value is converted once.
__device__ __forceinline__ unsigned short f2b(float x) {
    unsigned int u = __float_as_uint(x);
    return (unsigned short)((u + 0x7fffu + ((u >> 16) & 1u)) >> 16);
}
// Truncating float->bf16 (1 VALU op) -- ONLY for hi/lo SPLIT PAIRS (lo captures
// the hi residual exactly; r8/r9: saved ~8us/dispatch in fmha vs RTNE).
__device__ __forceinline__ unsigned short f2b_t(float x) {
    return (unsigned short)(__float_as_uint(x) >> 16);
}
__device__ __forceinline__ float b2f_(unsigned short h) {
    return __uint_as_float(((unsigned int)h) << 16);
}

// ---------------- embedding: depot/customer linear ----------------
__global__ __launch_bounds__(256) void embed_k(
    const float* __restrict__ dep, const float* __restrict__ cus,
    const float* __restrict__ Wd, const float* __restrict__ bd,
    const float* __restrict__ Wc3, const float* __restrict__ bc,
    float* __restrict__ x)
{
    int idx = blockIdx.x * 256 + threadIdx.x;   // < B*N*E = 2129920
    int e = idx & 127;
    int bn = idx >> 7;
    int n = bn % NN;
    int b = bn / NN;
    float a;
    if (n < DEPOT_) {
        a = bd[e];
        const float* f = dep + ((size_t)(b * DEPOT_ + n)) * 4;
        #pragma unroll
        for (int j = 0; j < 4; j++) a += f[j] * Wd[e * 4 + j];
    } else {
        a = bc[e];
        const float* f = cus + ((size_t)(b * 500 + (n - DEPOT_))) * 3;
        #pragma unroll
        for (int j = 0; j < 3; j++) a += f[j] * Wc3[e * 3 + j];
    }
    x[idx] = a;
}

// ---------------- weight pre-conversion: fp32 -> hi/lo bf16 planes ----------------
#define WLS 196608
#define WDEC 1179648
#define WTOT 1277952
__global__ __launch_bounds__(256) void wconv_k(
    const float* __restrict__ Wq, const float* __restrict__ Wk, const float* __restrict__ Wv,
    const float* __restrict__ Wc, const float* __restrict__ fW1, const float* __restrict__ fW2,
    const float* __restrict__ dWk, const float* __restrict__ dWv, const float* __restrict__ dWc,
    const float* __restrict__ Wql, const float* __restrict__ Wqr,
    unsigned short* __restrict__ WH, unsigned short* __restrict__ WL)
{
    int idx = blockIdx.x * 256 + threadIdx.x;
    if (idx >= WTOT) return;
    const float* src;
    if (idx < WDEC) {
        int i = idx / WLS, r = idx % WLS;
        if (r < 49152) {
            int row = r >> 7, col = r & 127;
            const float* w = row < 128 ? Wq : (row < 256 ? Wk : Wv);
            src = w + (size_t)i * 16384 + (size_t)(row & 127) * 128 + col;
        } else if (r < 65536) {
            src = Wc + (size_t)i * 16384 + (r - 49152);
        } else if (r < 131072) {
            src = fW1 + (size_t)i * 65536 + (r - 65536);
        } else {
            src = fW2 + (size_t)i * 65536 + (r - 131072);
        }
    } else {
        int r = idx - WDEC;
        if (r < 32768) {
            int row = r >> 7, col = r & 127;
            src = (row < 128 ? dWk : dWv) + (size_t)(row & 127) * 128 + col;
        } else if (r < 49152) {
            src = dWc + (r - 32768);
        } else {
            int rr = r - 49152;
            int row = rr >> 7, col = rr & 127;
            if (row < 128)      src = Wqr + (size_t)row * 257 + col;
            else if (row < 256) src = Wql + (size_t)(row - 128) * 256 + col;
            else                src = Wql + (size_t)(row - 256) * 256 + 128 + col;
        }
    }
    float v = *src;
    unsigned short h = f2b(v);
    WH[idx] = h;
    WL[idx] = f2b(v - b2f_(h));
}

// ---------------- bf16x3 MFMA GEMM, BM=64, double-buffered LDS ----------------
#define AP 40
__global__ __launch_bounds__(256) void gemm_pc_k(
    const float* __restrict__ A, int lda,
    const unsigned short* __restrict__ WH, const unsigned short* __restrict__ WL, int ldw,
    const float* __restrict__ bias,
    float* __restrict__ C, int ldc,
    int K, int relu)
{
    __shared__ __align__(16) unsigned short Ah[2][64][AP];
    __shared__ __align__(16) unsigned short Al[2][64][AP];
    __shared__ __align__(16) unsigned short Bh[2][64][AP];
    __shared__ __align__(16) unsigned short Bl[2][64][AP];

    int t = threadIdx.x;
    int w = t >> 6, lane = t & 63;
    int frow = lane & 15, fq = lane >> 4;
    int n0 = blockIdx.x * 64, m0 = blockIdx.y * 64;

    int arow = t & 63, acol = (t >> 6) * 8;

    const float* Abase = A + (size_t)(m0 + arow) * lda + acol;
    const unsigned short* WHb = WH + (size_t)(n0 + arow) * ldw + acol;
    const unsigned short* WLb = WL + (size_t)(n0 + arow) * ldw + acol;

    floatx4 acc[4];
    #pragma unroll
    for (int j = 0; j < 4; j++) acc[j] = (floatx4){0.0f, 0.0f, 0.0f, 0.0f};

    {
        float4 v0 = ((const float4*)Abase)[0];
        float4 v1 = ((const float4*)Abase)[1];
        float vr[8] = {v0.x, v0.y, v0.z, v0.w, v1.x, v1.y, v1.z, v1.w};
        short8 hv, lv;
        #pragma unroll
        for (int j = 0; j < 8; j++) {
            unsigned short h = f2b(vr[j]);
            hv[j] = (short)h;
            lv[j] = (short)f2b(vr[j] - b2f_(h));
        }
        *((short8*)&Ah[0][arow][acol]) = hv;
        *((short8*)&Al[0][arow][acol]) = lv;
        *((short8*)&Bh[0][arow][acol]) = *((const short8*)WHb);
        *((short8*)&Bl[0][arow][acol]) = *((const short8*)WLb);
    }
    __syncthreads();

    int nkt = K >> 5;
    for (int kt = 0; kt < nkt; kt++) {
        int cur = kt & 1;
        bool pf = (kt + 1 < nkt);

        float4 av0, av1;
        short8 nbh, nbl;
        if (pf) {
            const float* Ap = Abase + (kt + 1) * 32;
            av0 = ((const float4*)Ap)[0];
            av1 = ((const float4*)Ap)[1];
            nbh = *((const short8*)(WHb + (kt + 1) * 32));
            nbl = *((const short8*)(WLb + (kt + 1) * 32));
        }

        short8 ah = *((const short8*)&Ah[cur][w * 16 + frow][fq * 8]);
        short8 al = *((const short8*)&Al[cur][w * 16 + frow][fq * 8]);
        #pragma unroll
        for (int nt = 0; nt < 4; nt++) {
            short8 bh = *((const short8*)&Bh[cur][nt * 16 + frow][fq * 8]);
            short8 bl = *((const short8*)&Bl[cur][nt * 16 + frow][fq * 8]);
            acc[nt] = __builtin_amdgcn_mfma_f32_16x16x32_bf16(ah, bh, acc[nt], 0, 0, 0);
            acc[nt] = __builtin_amdgcn_mfma_f32_16x16x32_bf16(ah, bl, acc[nt], 0, 0, 0);
            acc[nt] = __builtin_amdgcn_mfma_f32_16x16x32_bf16(al, bh, acc[nt], 0, 0, 0);
        }

        if (pf) {
            int nb2 = cur ^ 1;
            float vr[8] = {av0.x, av0.y, av0.z, av0.w, av1.x, av1.y, av1.z, av1.w};
            short8 hv, lv;
            #pragma unroll
            for (int j = 0; j < 8; j++) {
                unsigned short h = f2b(vr[j]);
                hv[j] = (short)h;
                lv[j] = (short)f2b(vr[j] - b2f_(h));
            }
            *((short8*)&Ah[nb2][arow][acol]) = hv;
            *((short8*)&Al[nb2][arow][acol]) = lv;
            *((short8*)&Bh[nb2][arow][acol]) = nbh;
            *((short8*)&Bl[nb2][arow][acol]) = nbl;
        }
        __syncthreads();
    }

    #pragma unroll
    for (int nt = 0; nt < 4; nt++) {
        int col = n0 + nt * 16 + frow;
        float bv = bias ? bias[col] : 0.0f;
        int rbase = m0 + w * 16 + fq * 4;
        #pragma unroll
        for (int r = 0; r < 4; r++) {
            float v = acc[nt][r] + bv;
            if (relu) v = fmaxf(v, 0.0f);
            C[(size_t)(rbase + r) * ldc + col] = v;
        }
    }
}

// ---------------- fused 3-way GEMM (QKV / dec-KV / R+L1), BM=64, dbuf ----------------
__global__ __launch_bounds__(256) void gemm_qkv3_k(
    const float* __restrict__ A, int lda,
    const unsigned short* __restrict__ WH, const unsigned short* __restrict__ WL, int ldw,
    float* __restrict__ C0, float* __restrict__ C1, float* __restrict__ C2,
    int ldc, int K, int pack)
{
    __shared__ __align__(16) unsigned short Ah[2][64][AP];
    __shared__ __align__(16) unsigned short Al[2][64][AP];
    __shared__ __align__(16) unsigned short Bh[2][64][AP];
    __shared__ __align__(16) unsigned short Bl[2][64][AP];

    int t = threadIdx.x;
    int w = t >> 6, lane = t & 63;
    int frow = lane & 15, fq = lane >> 4;
    int nb = blockIdx.x;
    int which = nb >> 1;
    float* C = which == 0 ? C0 : (which == 1 ? C1 : C2);
    int n0w = nb * 64;
    int n0c = (nb & 1) * 64;
    int m0 = blockIdx.y * 64;

    int arow = t & 63, acol = (t >> 6) * 8;

    const float* Abase = A + (size_t)(m0 + arow) * lda + acol;
    const unsigned short* WHb = WH + (size_t)(n0w + arow) * ldw + acol;
    const unsigned short* WLb = WL + (size_t)(n0w + arow) * ldw + acol;

    floatx4 acc[4];
    #pragma unroll
    for (int j = 0; j < 4; j++) acc[j] = (floatx4){0.0f, 0.0f, 0.0f, 0.0f};

    {
        float4 v0 = ((const float4*)Abase)[0];
        float4 v1 = ((const float4*)Abase)[1];
        float vr[8] = {v0.x, v0.y, v0.z, v0.w, v1.x, v1.y, v1.z, v1.w};
        short8 hv, lv;
        #pragma unroll
        for (int j = 0; j < 8; j++) {
            unsigned short h = f2b(vr[j]);
            hv[j] = (short)h;
            lv[j] = (short)f2b(vr[j] - b2f_(h));
        }
        *((short8*)&Ah[0][arow][acol]) = hv;
        *((short8*)&Al[0][arow][acol]) = lv;
        *((short8*)&Bh[0][arow][acol]) = *((const short8*)WHb);
        *((short8*)&Bl[0][arow][acol]) = *((const short8*)WLb);
    }
    __syncthreads();

    int nkt = K >> 5;
    for (int kt = 0; kt < nkt; kt++) {
        int cur = kt & 1;
        bool pf = (kt + 1 < nkt);

        float4 av0, av1;
        short8 nbh, nbl;
        if (pf) {
            const float* Ap = Abase + (kt + 1) * 32;
            av0 = ((const float4*)Ap)[0];
            av1 = ((const float4*)Ap)[1];
            nbh = *((const short8*)(WHb + (kt + 1) * 32));
            nbl = *((const short8*)(WLb + (kt + 1) * 32));
        }

        short8 ah = *((const short8*)&Ah[cur][w * 16 + frow][fq * 8]);
        short8 al = *((const short8*)&Al[cur][w * 16 + frow][fq * 8]);
        #pragma unroll
        for (int nt = 0; nt < 4; nt++) {
            short8 bh = *((const short8*)&Bh[cur][nt * 16 + frow][fq * 8]);
            short8 bl = *((const short8*)&Bl[cur][nt * 16 + frow][fq * 8]);
            acc[nt] = __builtin_amdgcn_mfma_f32_16x16x32_bf16(ah, bh, acc[nt], 0, 0, 0);
            acc[nt] = __builtin_amdgcn_mfma_f32_16x16x32_bf16(ah, bl, acc[nt], 0, 0, 0);
            acc[nt] = __builtin_amdgcn_mfma_f32_16x16x32_bf16(al, bh, acc[nt], 0, 0, 0);
        }

        if (pf) {
            int nb2 = cur ^ 1;
            float vr[8] = {av0.x, av0.y, av0.z, av0.w, av1.x, av1.y, av1.z, av1.w};
            short8 hv, lv;
            #pragma unroll
            for (int j = 0; j < 8; j++) {
                unsigned short h = f2b(vr[j]);
                hv[j] = (short)h;
                lv[j] = (short)f2b(vr[j] - b2f_(h));
            }
            *((short8*)&Ah[nb2][arow][acol]) = hv;
            *((short8*)&Al[nb2][arow][acol]) = lv;
            *((short8*)&Bh[nb2][arow][acol]) = nbh;
            *((short8*)&Bl[nb2][arow][acol]) = nbl;
        }
        __syncthreads();
    }

    #pragma unroll
    for (int nt = 0; nt < 4; nt++) {
        int col = n0c + nt * 16 + frow;
        int hh = col >> 4, dd = col & 15;
        int rbase = m0 + w * 16 + fq * 4;
        #pragma unroll
        for (int r = 0; r < 4; r++) {
            int row = rbase + r;
            if (pack) {
                int b2 = row / NN, n2 = row - b2 * NN;
                C[((size_t)(b2 * HH + hh) * NN + n2) * 16 + dd] = acc[nt][r];
            } else {
                C[(size_t)row * ldc + col] = acc[nt][r];
            }
        }
    }
}

// ---------------- score GEMM (NT) MFMA bf16x3 with tanh epilogue (r11: kept) ----------------
__global__ __launch_bounds__(256) void sgemm_k(
    const float* __restrict__ A,    // score [B*520][128]
    const float* __restrict__ Enc,  // [B*520][128]
    float* __restrict__ C)          // [B][520][520]
{
    __shared__ __align__(16) unsigned short Ah[2][64][AP];
    __shared__ __align__(16) unsigned short Al[2][64][AP];
    __shared__ __align__(16) unsigned short Bh[2][64][AP];
    __shared__ __align__(16) unsigned short Bl[2][64][AP];

    int t = threadIdx.x;
    int w = t >> 6, lane = t & 63;
    int frow = lane & 15, fq = lane >> 4;
    int b = blockIdx.z;
    int n0 = blockIdx.x * 64, m0 = blockIdx.y * 64;

    int arow = t & 63, acol = (t >> 6) * 8;
    int mr = m0 + arow; if (mr >= NN) mr = NN - 1;
    int nr = n0 + arow; if (nr >= NN) nr = NN - 1;

    const float* Abase = A + ((size_t)(b * NN + mr)) * EE + acol;
    const float* Bbase = Enc + ((size_t)(b * NN + nr)) * EE + acol;

    floatx4 acc[4];
    #pragma unroll
    for (int j = 0; j < 4; j++) acc[j] = (floatx4){0.0f, 0.0f, 0.0f, 0.0f};

    {
        float4 a0 = ((const float4*)Abase)[0];
        float4 a1 = ((const float4*)Abase)[1];
        float4 b0 = ((const float4*)Bbase)[0];
        float4 b1 = ((const float4*)Bbase)[1];
        float ar[8] = {a0.x, a0.y, a0.z, a0.w, a1.x, a1.y, a1.z, a1.w};
        float br[8] = {b0.x, b0.y, b0.z, b0.w, b1.x, b1.y, b1.z, b1.w};
        short8 ahv, alv, bhv, blv;
        #pragma unroll
        for (int j = 0; j < 8; j++) {
            unsigned short h = f2b_t(ar[j]);
            ahv[j] = (short)h;
            alv[j] = (short)f2b_t(ar[j] - b2f_(h));
            unsigned short g2 = f2b_t(br[j]);
            bhv[j] = (short)g2;
            blv[j] = (short)f2b_t(br[j] - b2f_(g2));
        }
        *((short8*)&Ah[0][arow][acol]) = ahv;
        *((short8*)&Al[0][arow][acol]) = alv;
        *((short8*)&Bh[0][arow][acol]) = bhv;
        *((short8*)&Bl[0][arow][acol]) = blv;
    }
    __syncthreads();

    int nkt = EE >> 5;   // 4
    for (int kt = 0; kt < nkt; kt++) {
        int cur = kt & 1;
        bool pf = (kt + 1 < nkt);

        float4 a0, a1, b0, b1;
        if (pf) {
            const float* Ap = Abase + (kt + 1) * 32;
            const float* Bp = Bbase + (kt + 1) * 32;
            a0 = ((const float4*)Ap)[0]; a1 = ((const float4*)Ap)[1];
            b0 = ((const float4*)Bp)[0]; b1 = ((const float4*)Bp)[1];
        }

        short8 ah = *((const short8*)&Ah[cur][w * 16 + frow][fq * 8]);
        short8 al = *((const short8*)&Al[cur][w * 16 + frow][fq * 8]);
        #pragma unroll
        for (int nt = 0; nt < 4; nt++) {
            short8 bh = *((const short8*)&Bh[cur][nt * 16 + frow][fq * 8]);
            short8 bl = *((const short8*)&Bl[cur][nt * 16 + frow][fq * 8]);
            acc[nt] = __builtin_amdgcn_mfma_f32_16x16x32_bf16(ah, bh, acc[nt], 0, 0, 0);
            acc[nt] = __builtin_amdgcn_mfma_f32_16x16x32_bf16(ah, bl, acc[nt], 0, 0, 0);
            acc[nt] = __builtin_amdgcn_mfma_f32_16x16x32_bf16(al, bh, acc[nt], 0, 0, 0);
        }

        if (pf) {
            int nb2 = cur ^ 1;
            float ar[8] = {a0.x, a0.y, a0.z, a0.w, a1.x, a1.y, a1.z, a1.w};
            float br[8] = {b0.x, b0.y, b0.z, b0.w, b1.x, b1.y, b1.z, b1.w};
            short8 ahv, alv, bhv, blv;
            #pragma unroll
            for (int j = 0; j < 8; j++) {
                unsigned short h = f2b_t(ar[j]);
                ahv[j] = (short)h;
                alv[j] = (short)f2b_t(ar[j] - b2f_(h));
                unsigned short g2 = f2b_t(br[j]);
                bhv[j] = (short)g2;
                blv[j] = (short)f2b_t(br[j] - b2f_(g2));
            }
            *((short8*)&Ah[nb2][arow][acol]) = ahv;
            *((short8*)&Al[nb2][arow][acol]) = alv;
            *((short8*)&Bh[nb2][arow][acol]) = bhv;
            *((short8*)&Bl[nb2][arow][acol]) = blv;
        }
        __syncthreads();
    }

    #pragma unroll
    for (int nt = 0; nt < 4; nt++) {
        int n = n0 + nt * 16 + frow;
        if (n >= NN) continue;
        int rbase = m0 + w * 16 + fq * 4;
        #pragma unroll
        for (int r = 0; r < 4; r++) {
            int m = rbase + r;
            if (m >= NN) continue;
            float v = 10.0f * tanhf(acc[nt][r] * 0.088388347648318447f);
            C[((size_t)(b * NN + m)) * NN + n] = v;
        }
    }
}

// ---------------- row softmax: out = softmax(logits + mask) ----------------
__global__ __launch_bounds__(64) void smax_k(
    const float* __restrict__ L, const float* __restrict__ mask,
    float* __restrict__ out)
{
    int bm = blockIdx.x;
    int t = threadIdx.x;
    const float* Lr = L + (size_t)bm * NN;
    const float* Mr = mask + (size_t)bm * NN;
    float v[9];
    float mx = -1e30f;
    #pragma unroll
    for (int i = 0; i < 9; i++) {
        int idx = t + i * 64;
        if (idx < NN) { v[i] = Lr[idx] + Mr[idx]; mx = fmaxf(mx, v[i]); }
        else v[i] = -1e30f;
    }
    #pragma unroll
    for (int o = 32; o > 0; o >>= 1) mx = fmaxf(mx, __shfl_xor(mx, o));
    float s = 0.0f;
    #pragma unroll
    for (int i = 0; i < 9; i++) {
        int idx = t + i * 64;
        float e = (idx < NN) ? expf(v[i] - mx) : 0.0f;
        v[i] = e; s += e;
    }
    #pragma unroll
    for (int o = 32; o > 0; o >>= 1) s += __shfl_xor(s, o);
    float inv = 1.0f / s;
    #pragma unroll
    for (int i = 0; i < 9; i++) {
        int idx = t + i * 64;
        if (idx < NN) out[(size_t)bm * NN + idx] = v[i] * inv;
    }
}

// ---------------- persistent-KV MFMA flash attention v4 (bf16x3, fp32-equivalent) ----------------
// Grid (b=32, h=8, z=4), 256 threads (4 waves). id%8 = b%8: per-batch L2 on one XCD.
// QK^T: two mfma_16x16x32 with [Kh|Kl] x {[Qh|Ql],[Ql|Qh]} = exact 4-term product.
// r12: template<HASM> -- encoder (mask==nullptr) instantiation drops the whole
// mask path (48 VGPR mvv + selects/adds) at COMPILE time -> VGPR ~70, more
// waves/SIMD. Full/partial tile split: 8 of 9 K-tiles are full (520=8*64+8);
// wave-uniform `full` branch removes 48 cmp+cndmask per tile per frag.
#define ATK 64
#define NFRG 3
template<bool HASM>
__global__ __launch_bounds__(256) void fmha_t_k(
    const float* __restrict__ Qp, const float* __restrict__ Kp,
    const float* __restrict__ Vp, const float* __restrict__ mask,
    float* __restrict__ O, int Nq, int Nk)
{
    __shared__ __align__(16) unsigned short Khl[2][ATK][40];  // [kc][0:16 hi-dk | 16:32 lo-dk]
    __shared__ __align__(16) unsigned short Vhi[2][16][72];
    __shared__ __align__(16) unsigned short Vlo[2][16][72];

    int b = blockIdx.x, h = blockIdx.y, z = blockIdx.z;
    int bh = b * HH + h;
    int t = threadIdx.x;
    int w = t >> 6, lane = t & 63;
    int r16 = lane & 15, g = lane >> 4;

    short8 qf[NFRG], qs[NFRG];
    floatx4 o_acc[NFRG];
    float m_i[NFRG], l_i[NFRG];
    const float* mrowf[NFRG];
    const float* QpB = Qp + (size_t)bh * Nq * 16;
    #pragma unroll
    for (int f = 0; f < NFRG; f++) {
        int fi = f * 16 + z * 4 + w;
        int qg = fi * 16 + r16;
        int qc = qg < Nq ? qg : Nq - 1;
        const float* qp = QpB + (size_t)qc * 16 + 8 * (g & 1);
        float4 qv0 = *((const float4*)qp);
        float4 qv1 = *((const float4*)(qp + 4));
        float qa[8] = {qv0.x, qv0.y, qv0.z, qv0.w, qv1.x, qv1.y, qv1.z, qv1.w};
        #pragma unroll
        for (int j = 0; j < 8; j++) {
            unsigned short hh = f2b_t(qa[j]);
            unsigned short ll = f2b_t(qa[j] - b2f_(hh));
            qf[f][j] = (short)(g < 2 ? hh : ll);
            qs[f][j] = (short)(g < 2 ? ll : hh);
        }
        o_acc[f] = (floatx4){0.0f, 0.0f, 0.0f, 0.0f};
        m_i[f] = -1e30f; l_i[f] = 0.0f;
        mrowf[f] = HASM ? (mask + ((size_t)(b * Nq + qc)) * Nk) : nullptr;
    }

    int srow = t >> 2, sc = (t & 3) * 4;
    const float* KpB = Kp + ((size_t)bh * Nk) * 16 + sc;
    const float* VpB = Vp + ((size_t)bh * Nk) * 16 + sc;

    {
        int krc = srow < Nk ? srow : Nk - 1;
        float4 kv = *((const float4*)(KpB + (size_t)krc * 16));
        float4 vv = *((const float4*)(VpB + (size_t)krc * 16));
        float ka[4] = {kv.x, kv.y, kv.z, kv.w};
        float va[4] = {vv.x, vv.y, vv.z, vv.w};
        bshort4 khv, klv;
        #pragma unroll
        for (int j = 0; j < 4; j++) {
            unsigned short hh = f2b_t(ka[j]);
            khv[j] = (short)hh;
            klv[j] = (short)f2b_t(ka[j] - b2f_(hh));
        }
        *((bshort4*)&Khl[0][srow][sc])      = khv;
        *((bshort4*)&Khl[0][srow][16 + sc]) = klv;
        #pragma unroll
        for (int j = 0; j < 4; j++) {
            unsigned short hh = f2b_t(va[j]);
            Vhi[0][sc + j][srow] = hh;
            Vlo[0][sc + j][srow] = f2b_t(va[j] - b2f_(hh));
        }
    }
    __syncthreads();

    int nkt = (Nk + ATK - 1) / ATK;
    for (int kt = 0; kt < nkt; kt++) {
        int cur = kt & 1;
        int k0 = kt * ATK;
        bool full = (k0 + ATK <= Nk);   // wave-uniform

        float4 nkv, nvv;
        bool pf = (kt + 1 < nkt);
        if (pf) {
            int kr = k0 + ATK + srow;
            int krc = kr < Nk ? kr : Nk - 1;
            nkv = *((const float4*)(KpB + (size_t)krc * 16));
            nvv = *((const float4*)(VpB + (size_t)krc * 16));
        }

        // ---- hoisted mask loads for this tile (issue under the QK MFMAs) ----
        float mvv[HASM ? NFRG : 1][4][4];
        if (HASM) {
            #pragma unroll
            for (int f = 0; f < NFRG; f++) {
                #pragma unroll
                for (int s = 0; s < 4; s++) {
                    int c0 = k0 + s * 16 + 4 * g;
                    if (full || c0 + 3 < Nk) {
                        float4 m4 = *((const float4*)(mrowf[f] + c0));
                        mvv[f][s][0] = m4.x; mvv[f][s][1] = m4.y;
                        mvv[f][s][2] = m4.z; mvv[f][s][3] = m4.w;
                    } else {
                        #pragma unroll
                        for (int r = 0; r < 4; r++)
                            mvv[f][s][r] = (c0 + r < Nk) ? mrowf[f][c0 + r] : 0.0f;
                    }
                }
            }
        }

        short8 kfr[4];
        bshort4 vhf[4], vlf[4];
        #pragma unroll
        for (int s = 0; s < 4; s++) {
            kfr[s] = *((const short8*)&Khl[cur][s * 16 + r16][8 * g]);
            vhf[s] = *((const bshort4*)&Vhi[cur][r16][s * 16 + 4 * g]);
            vlf[s] = *((const bshort4*)&Vlo[cur][r16][s * 16 + 4 * g]);
        }

        #pragma unroll
        for (int f = 0; f < NFRG; f++) {
            int fi = f * 16 + z * 4 + w;
            if (fi * 16 >= Nq) continue;   // wave-uniform

            float p[4][4];
            #pragma unroll
            for (int s = 0; s < 4; s++) {
                floatx4 a = (floatx4){0.0f, 0.0f, 0.0f, 0.0f};
                a = __builtin_amdgcn_mfma_f32_16x16x32_bf16(kfr[s], qf[f], a, 0, 0, 0);
                a = __builtin_amdgcn_mfma_f32_16x16x32_bf16(kfr[s], qs[f], a, 0, 0, 0);
                #pragma unroll
                for (int r = 0; r < 4; r++) p[s][r] = a[r];
            }

            // ---- scale + mask (+ bounds only on the partial tile) ----
            if (full) {
                #pragma unroll
                for (int s = 0; s < 4; s++)
                    #pragma unroll
                    for (int r = 0; r < 4; r++) {
                        if (HASM) p[s][r] = p[s][r] * 0.25f + mvv[f][s][r];
                        else      p[s][r] = p[s][r] * 0.25f;
                    }
            } else {
                #pragma unroll
                for (int s = 0; s < 4; s++) {
                    int c0 = k0 + s * 16 + 4 * g;
                    #pragma unroll
                    for (int r = 0; r < 4; r++) {
                        float mv = HASM ? mvv[f][s][r] : 0.0f;
                        p[s][r] = (c0 + r < Nk) ? (p[s][r] * 0.25f + mv) : -1e30f;
                    }
                }
            }

            float tmax = -1e30f;
            #pragma unroll
            for (int s = 0; s < 4; s++)
                #pragma unroll
                for (int r = 0; r < 4; r++) tmax = fmaxf(tmax, p[s][r]);
            tmax = fmaxf(tmax, __shfl_xor(tmax, 16));
            tmax = fmaxf(tmax, __shfl_xor(tmax, 32));
            float m_new = fmaxf(m_i[f], tmax);
            float alpha = __expf(m_i[f] - m_new);
            float lloc = 0.0f;
            #pragma unroll
            for (int s = 0; s < 4; s++) {
                #pragma unroll
                for (int r = 0; r < 4; r++) {
                    float e = __expf(p[s][r] - m_new);
                    p[s][r] = e; lloc += e;
                }
            }
            lloc += __shfl_xor(lloc, 16);
            lloc += __shfl_xor(lloc, 32);
            l_i[f] = l_i[f] * alpha + lloc;
            m_i[f] = m_new;
            #pragma unroll
            for (int r = 0; r < 4; r++) {
                float ar = __shfl(alpha, 4 * g + r);
                o_acc[f][r] *= ar;
            }

            #pragma unroll
            for (int s = 0; s < 4; s++) {
                bshort4 ph, pl;
                #pragma unroll
                for (int r = 0; r < 4; r++) {
                    unsigned short hh = f2b_t(p[s][r]);
                    ph[r] = (short)hh;
                    pl[r] = (short)f2b_t(p[s][r] - b2f_(hh));
                }
                o_acc[f] = __builtin_amdgcn_mfma_f32_16x16x16bf16_1k(ph, vhf[s], o_acc[f], 0, 0, 0);
                o_acc[f] = __builtin_amdgcn_mfma_f32_16x16x16bf16_1k(ph, vlf[s], o_acc[f], 0, 0, 0);
                o_acc[f] = __builtin_amdgcn_mfma_f32_16x16x16bf16_1k(pl, vhf[s], o_acc[f], 0, 0, 0);
            }
        }

        if (pf) {
            int nb2 = cur ^ 1;
            float ka[4] = {nkv.x, nkv.y, nkv.z, nkv.w};
            float va[4] = {nvv.x, nvv.y, nvv.z, nvv.w};
            bshort4 khv, klv;
            #pragma unroll
            for (int j = 0; j < 4; j++) {
                unsigned short hh = f2b_t(ka[j]);
                khv[j] = (short)hh;
                klv[j] = (short)f2b_t(ka[j] - b2f_(hh));
            }
            *((bshort4*)&Khl[nb2][srow][sc])      = khv;
            *((bshort4*)&Khl[nb2][srow][16 + sc]) = klv;
            #pragma unroll
            for (int j = 0; j < 4; j++) {
                unsigned short hh = f2b_t(va[j]);
                Vhi[nb2][sc + j][srow] = hh;
                Vlo[nb2][sc + j][srow] = f2b_t(va[j] - b2f_(hh));
            }
        }
        __syncthreads();
    }

    #pragma unroll
    for (int f = 0; f < NFRG; f++) {
        int fi = f * 16 + z * 4 + w;
        if (fi * 16 >= Nq) continue;
        #pragma unroll
        for (int r = 0; r < 4; r++) {
            float lr = __shfl(l_i[f], 4 * g + r);
            int qrow = fi * 16 + 4 * g + r;
            if (qrow < Nq)
                O[((size_t)(b * Nq + qrow)) * EE + h * 16 + r16] = o_acc[f][r] / lr;
        }
    }
}

// ---------------- InstanceNorm over node axis (coalesced; r8: -276us vs e-fixed) ----------------
__global__ __launch_bounds__(256) void inorm_k(
    const float* __restrict__ X, const float* __restrict__ Y,
    const float* __restrict__ g, const float* __restrict__ bb,
    float* __restrict__ Out)
{
    int b = blockIdx.x, eg = blockIdx.y;
    int t = threadIdx.x;
    int tx = t & 15, tn = t >> 4;
    int e = eg * 16 + tx;
    const float* Xb = X + ((size_t)b * NN) * EE + e;
    const float* Yb = Y + ((size_t)b * NN) * EE + e;
    float s = 0.0f, s2 = 0.0f;
    for (int n = tn; n < NN; n += 16) {
        float v = Xb[(size_t)n * EE] + Yb[(size_t)n * EE];
        s += v; s2 += v * v;
    }
    __shared__ float rs[16][17], rs2[16][17];
    rs[tn][tx] = s; rs2[tn][tx] = s2;
    __syncthreads();
    float st = 0.0f, st2 = 0.0f;
    #pragma unroll
    for (int j = 0; j < 16; j++) { st += rs[j][tx]; st2 += rs2[j][tx]; }
    float mu = st * (1.0f / NN);
    float var = st2 * (1.0f / NN) - mu * mu;
    float inv = rsqrtf(var + 1e-5f);
    float gg = g[e], bv = bb[e];
    float* Ob = Out + ((size_t)b * NN) * EE + e;
    for (int n = tn; n < NN; n += 16) {
        float v = Xb[(size_t)n * EE] + Yb[(size_t)n * EE];
        Ob[(size_t)n * EE] = (v - mu) * inv * gg + bv;
    }
}

__global__ void zero_k(float* p, int n) {
    int i = blockIdx.x * 256 + threadIdx.x;
    if (i < n) p[i] = 0.0f;
}

__global__ __launch_bounds__(128) void encsum_k(const float* __restrict__ enc, float* __restrict__ esum) {
    int b = blockIdx.x, ch = blockIdx.y, t = threadIdx.x;
    float a = 0.0f;
    for (int i = 0; i < 65; i++) {
        int n = ch * 65 + i;
        a += enc[((size_t)(b * NN + n)) * EE + t];
    }
    atomicAdd(&esum[b * EE + t], a);
}

// mt[b,e] = sum_f (esum[b,f]/N) * Wr[e, 128+f]
__global__ __launch_bounds__(128) void meanterm_k(
    const float* __restrict__ esum, const float* __restrict__ Wr, float* __restrict__ mt)
{
    int b = blockIdx.x, t = threadIdx.x;
    __shared__ float em[128];
    em[t] = esum[b * EE + t] * (1.0f / NN);
    __syncthreads();
    const float* w = Wr + (size_t)t * 257 + 128;
    float a = 0.0f;
    for (int f = 0; f < 128; f++) a += em[f] * w[f];
    mt[b * EE + t] = a;
}

__global__ __launch_bounds__(128) void subtour_k(
    const float* __restrict__ enc, const int* __restrict__ subn,
    const int* __restrict__ subl, float* __restrict__ subm)
{
    int bm = blockIdx.x;
    int b = bm / MM;
    int t = threadIdx.x;
    int len = subl[bm];
    float acc = 0.0f; int cnt = 0;
    for (int l = 0; l < LL; l++) {
        int node = subn[(size_t)bm * LL + l];
        if (l < len && node >= DEPOT_) {
            acc += enc[((size_t)(b * NN + node)) * EE + t];
            cnt++;
        }
    }
    float cf = (float)(cnt < 1 ? 1 : cnt);
    subm[(size_t)bm * EE + t] = acc / cf;
}

// ---------------- decoder q: gather/blend, writes head-packed final_q ----------------
__global__ __launch_bounds__(128) void decq_gather_k(
    const float* __restrict__ R, const float* __restrict__ L1, const float* __restrict__ SM2,
    const float* __restrict__ mterm, const int* __restrict__ cur,
    const float* __restrict__ loadv, const int* __restrict__ sel,
    const float* __restrict__ Wqr, float* __restrict__ out)
{
    int bm = blockIdx.x;
    int b = bm / MM;
    int m = bm - b * MM;
    int t = threadIdx.x;
    int cn = cur[bm];
    int s2v = sel[(size_t)bm * 4 + 2];
    bool flag = (s2v >= DEPOT_) && (cn < DEPOT_);
    size_t eo = ((size_t)(b * NN + cn)) * EE + t;
    float q;
    if (flag) q = L1[eo] + SM2[(size_t)bm * EE + t];
    else      q = R[eo] + mterm[b * EE + t] + loadv[bm] * Wqr[(size_t)t * 257 + 256];
    out[((size_t)(b * HH + (t >> 4)) * MM + m) * 16 + (t & 15)] = q;
}

extern "C" void kernel_launch(void* const* d_in, const int* in_sizes, int n_in,
                              void* d_out, int out_size, void* d_ws, size_t ws_size,
                              hipStream_t stream)
{
    const float* depot = (const float*)d_in[0];
    const float* cust  = (const float*)d_in[1];
    const float* mask  = (const float*)d_in[2];
    const float* loadv = (const float*)d_in[3];
    const int*  cur   = (const int*)d_in[4];
    const int*  subn  = (const int*)d_in[5];
    const int*  subl  = (const int*)d_in[6];
    const int*  sel   = (const int*)d_in[7];
    const float* Wdep  = (const float*)d_in[8];
    const float* bdep  = (const float*)d_in[9];
    const float* Wcus  = (const float*)d_in[10];
    const float* bcus  = (const float*)d_in[11];
    const float* Wq    = (const float*)d_in[12];
    const float* Wk    = (const float*)d_in[13];
    const float* Wv    = (const float*)d_in[14];
    const float* Wc    = (const float*)d_in[15];
    const float* Wcb   = (const float*)d_in[16];
    const float* n1g   = (const float*)d_in[17];
    const float* n1b   = (const float*)d_in[18];
    const float* fW1   = (const float*)d_in[19];
    const float* fb1   = (const float*)d_in[20];
    const float* fW2   = (const float*)d_in[21];
    const float* fb2   = (const float*)d_in[22];
    const float* n2g   = (const float*)d_in[23];
    const float* n2b   = (const float*)d_in[24];
    const float* Wql   = (const float*)d_in[25];
    const float* Wqr   = (const float*)d_in[26];
    const float* dWk   = (const float*)d_in[27];
    const float* dWv   = (const float*)d_in[28];
    const float* dWc   = (const float*)d_in[29];
    const float* dWcb  = (const float*)d_in[30];

    const size_t SZ = (size_t)BB * NN * EE;           // 2,129,920
    float* f0 = (float*)d_ws;       // x / encoded
    float* f1 = f0 + SZ;            // q / k_d (packed) / logits (spans f1..f5)
    float* f2 = f1 + SZ;            // k / v_d (packed)
    float* f3 = f2 + SZ;            // v (packed) / encsum + meanterm
    float* f4 = f3 + SZ;            // mh,ff2 out / sub_mean, dec attn
    float* f5 = f4 + SZ;            // x1 / final_q (packed)
    float* big = f5 + SZ;           // ffh (B*N*FFH) / R,L1,SM2 / dec score
    unsigned short* WHp = (unsigned short*)(big + (size_t)BB * NN * FFH_);
    unsigned short* WLp = WHp + WTOT;

    dim3 g4(EE / 64, (BB * NN) / 64);      // (2, 260) = 520 blocks
    dim3 g16(FFH_ / 64, (BB * NN) / 64);   // (8, 260) = 2080 blocks
    dim3 gq3(6, (BB * NN) / 64);           // fused QKV, 1560 blocks
    dim3 gq2(4, (BB * NN) / 64);           // fused 2-way, 1040 blocks
    dim3 gmha(BB, HH, 4);                  // (32, 8, 4): id%8==b%8 -> per-batch L2 on one XCD
    dim3 gin(BB, 8);                       // coalesced inorm: (b, e-group)
    dim3 gsc((NN + 63) / 64, (NN + 63) / 64, BB);  // (9, 9, 32) MFMA logits

    wconv_k<<<(WTOT + 255) / 256, 256, 0, stream>>>(Wq, Wk, Wv, Wc, fW1, fW2,
                                                    dWk, dWv, dWc, Wql, Wqr, WHp, WLp);
    embed_k<<<(BB * NN * EE) / 256, 256, 0, stream>>>(depot, cust, Wdep, bdep, Wcus, bcus, f0);

    for (int i = 0; i < NL_; i++) {
        const unsigned short* lH = WHp + (size_t)i * WLS;
        const unsigned short* lL = WLp + (size_t)i * WLS;
        gemm_qkv3_k<<<gq3, 256, 0, stream>>>(f0, EE, lH, lL, EE, f1, f2, f3, EE, EE, 1);
        fmha_t_k<false><<<gmha, 256, 0, stream>>>(f1, f2, f3, nullptr, f4, NN, NN);
        gemm_pc_k<<<g4, 256, 0, stream>>>(f4, EE, lH + 49152, lL + 49152, EE, Wcb + i * EE, f1, EE, EE, 0);
        inorm_k<<<gin, 256, 0, stream>>>(f0, f1, n1g + i * EE, n1b + i * EE, f5);
        gemm_pc_k<<<g16, 256, 0, stream>>>(f5, EE, lH + 65536, lL + 65536, EE, fb1 + i * FFH_, big, FFH_, EE, 1);
        gemm_pc_k<<<g4, 256, 0, stream>>>(big, FFH_, lH + 131072, lL + 131072, FFH_, fb2 + i * EE, f1, EE, FFH_, 0);
        inorm_k<<<gin, 256, 0, stream>>>(f5, f1, n2g + i * EE, n2b + i * EE, f0);
    }

    // ---- decoder ----
    const unsigned short* dH = WHp + WDEC;
    const unsigned short* dL = WLp + WDEC;
    gemm_qkv3_k<<<gq2, 256, 0, stream>>>(f0, EE, dH, dL, EE, f1, f2, f2, EE, EE, 1);  // k_d, v_d packed

    zero_k<<<(BB * EE + 255) / 256, 256, 0, stream>>>(f3, BB * EE);
    encsum_k<<<dim3(BB, 8), 128, 0, stream>>>(f0, f3);
    meanterm_k<<<BB, 128, 0, stream>>>(f3, Wqr, f3 + BB * EE);
    subtour_k<<<BB * MM, 128, 0, stream>>>(f0, subn, subl, f4);

    // R (big), L1 (big+SZ) from encoded; SM2 (big+2SZ) from subm  (standard layout)
    gemm_qkv3_k<<<gq2, 256, 0, stream>>>(f0, EE, dH + 49152, dL + 49152, EE, big, big + SZ, big + SZ, EE, EE, 0);
    gemm_pc_k<<<g4, 256, 0, stream>>>(f4, EE, dH + 49152 + 32768, dL + 49152 + 32768, EE, nullptr, big + 2 * SZ, EE, EE, 0);
    decq_gather_k<<<BB * MM, 128, 0, stream>>>(big, big + SZ, big + 2 * SZ, f3 + BB * EE, cur, loadv, sel, Wqr, f5);

    fmha_t_k<true><<<gmha, 256, 0, stream>>>(f5, f1, f2, mask, f4, MM, NN);
    gemm_pc_k<<<g4, 256, 0, stream>>>(f4, EE, dH + 32768, dL + 32768, EE, dWcb, big, EE, EE, 0);

    // logits (B x 520 x 520) at f1 (spans f1..f5; all dead now)
    sgemm_k<<<gsc, 256, 0, stream>>>(big, f0, f1);
    smax_k<<<BB * MM, 64, 0, stream>>>(f1, mask, (float*)d_out);
}